// Round 13
// baseline (723.101 us; speedup 1.0000x reference)
//
#include <hip/hip_runtime.h>
#include <math.h>

// ---------------------------------------------------------------------------
// Model dims (fixed): B=8 L=400 F=128 D=256 T=256 H=512 NH=8 HD=64 P=1200
// ---------------------------------------------------------------------------

typedef __attribute__((ext_vector_type(8))) short bf16x8;
typedef __attribute__((ext_vector_type(4))) float f32x4;
typedef __attribute__((ext_vector_type(4))) unsigned int u32x4;
typedef __attribute__((ext_vector_type(4))) unsigned short us4;

__device__ __forceinline__ float mishf(float x) {
    float sp = fmaxf(x, 0.f) + log1pf(expf(-fabsf(x)));   // stable softplus
    return x * tanhf(sp);
}

__device__ __forceinline__ unsigned short f2bf(float f) {
    unsigned int u = __float_as_uint(f);
    u = (u + 0x7fffu + ((u >> 16) & 1u)) >> 16;           // RNE
    return (unsigned short)u;
}
__device__ __forceinline__ float bf2f(unsigned short h) {
    return __uint_as_float(((unsigned int)h) << 16);
}

__device__ __forceinline__ bf16x8 load_bf8(const unsigned short* p, bool valid) {
    bf16x8 z = {0, 0, 0, 0, 0, 0, 0, 0};
    if (valid) z = *(const bf16x8*)p;
    return z;
}

// ---------------------------------------------------------------------------
// fp32 GEMM (front MLP, K=128): writes f1pad (padded conv layout) + split
// bf16 hi/lo feats (cols 0..255 of 512-wide).
// ---------------------------------------------------------------------------
template<int EPI>
__global__ __launch_bounds__(256) void gemm_bias(
    const float* __restrict__ A, const float* __restrict__ Bm,
    const float* __restrict__ bias, float* __restrict__ C2,
    unsigned short* __restrict__ fhi, unsigned short* __restrict__ flo,
    int M, int N, int K, int ldc)
{
    __shared__ float As[16][68];
    __shared__ float Bs[16][68];
    int bm = blockIdx.y << 6, bn = blockIdx.x << 6;
    int tid = threadIdx.x;
    int tm = (tid >> 4) << 2, tn = (tid & 15) << 2;
    int ar = tid >> 2, ac4 = (tid & 3) << 2;
    int br = tid >> 4, bc4 = (tid & 15) << 2;
    float acc[4][4] = {};
    for (int k0 = 0; k0 < K; k0 += 16) {
        float4 av = make_float4(0.f, 0.f, 0.f, 0.f);
        if (bm + ar < M)
            av = *(const float4*)&A[(long long)(bm + ar) * K + k0 + ac4];
        As[ac4][ar] = av.x; As[ac4 + 1][ar] = av.y;
        As[ac4 + 2][ar] = av.z; As[ac4 + 3][ar] = av.w;
        *(float4*)&Bs[br][bc4] =
            *(const float4*)&Bm[(long long)(k0 + br) * N + bn + bc4];
        __syncthreads();
        #pragma unroll
        for (int kk = 0; kk < 16; ++kk) {
            float4 a4 = *(const float4*)&As[kk][tm];
            float4 b4 = *(const float4*)&Bs[kk][tn];
            acc[0][0] += a4.x * b4.x; acc[0][1] += a4.x * b4.y;
            acc[0][2] += a4.x * b4.z; acc[0][3] += a4.x * b4.w;
            acc[1][0] += a4.y * b4.x; acc[1][1] += a4.y * b4.y;
            acc[1][2] += a4.y * b4.z; acc[1][3] += a4.y * b4.w;
            acc[2][0] += a4.z * b4.x; acc[2][1] += a4.z * b4.y;
            acc[2][2] += a4.z * b4.z; acc[2][3] += a4.z * b4.w;
            acc[3][0] += a4.w * b4.x; acc[3][1] += a4.w * b4.y;
            acc[3][2] += a4.w * b4.z; acc[3][3] += a4.w * b4.w;
        }
        __syncthreads();
    }
    #pragma unroll
    for (int i = 0; i < 4; ++i) {
        int r = bm + tm + i;
        if (r < M) {
            float v[4];
            #pragma unroll
            for (int q = 0; q < 4; ++q) {
                v[q] = acc[i][q] + bias[bn + tn + q];
                if (EPI == 1) v[q] = mishf(v[q]);
            }
            float4 o; o.x = v[0]; o.y = v[1]; o.z = v[2]; o.w = v[3];
            int rr2 = (r / 400) * 402 + (r % 400) + 1;
            *(float4*)&C2[(long long)rr2 * 256 + bn + tn] = o;
            us4 ph, pl;
            #pragma unroll
            for (int q = 0; q < 4; ++q) {
                unsigned short hh = f2bf(v[q]);
                ph[q] = hh;
                pl[q] = f2bf(v[q] - bf2f(hh));
            }
            *(us4*)&fhi[(long long)r * ldc + bn + tn] = ph;
            *(us4*)&flo[(long long)r * ldc + bn + tn] = pl;
        }
    }
}

// ---------------------------------------------------------------------------
// MFMA bf16x3-split GEMM. B pre-transposed+split [N][K] bf16 hi/lo.
// AMODE: 0 = A fp32 (split per tile), 1 = A pre-split hi/lo (straight copy).
// SPLIT out: cols<nhl -> Chi/Clo [row][col]; cols>=1024 -> V transposed (416).
// EPI: 0 none, 1 mish, 2 relu.
// ---------------------------------------------------------------------------
template<int EPI, bool GATHER, int AMODE, bool SPLIT, int MT>
__global__ __launch_bounds__(256) void gemm_mfma(
    const float* __restrict__ A,
    const unsigned short* __restrict__ Ahi, const unsigned short* __restrict__ Alo,
    const unsigned short* __restrict__ Bth, const unsigned short* __restrict__ Btl,
    const float* __restrict__ bias, float* __restrict__ C,
    int M, int K, int lda, int ldc, const int* __restrict__ gidx,
    unsigned short* __restrict__ Chi, unsigned short* __restrict__ Clo,
    int ldhl, int nhl,
    unsigned short* __restrict__ vthi, unsigned short* __restrict__ vtlo,
    long long zA, int zB, int zBias, int zC, int zChi, int zVt)
{
    constexpr int AI = MT / 32;
    __shared__ unsigned short Ah[MT * 40];
    __shared__ unsigned short Al[MT * 40];
    __shared__ unsigned short Bh[128 * 40];
    __shared__ unsigned short Bl[128 * 40];

    long long zz = blockIdx.z;
    if (AMODE == 0) A += zz * zA;
    else { Ahi += zz * zA; Alo += zz * zA; }
    Bth  += zz * (long long)zB;  Btl += zz * (long long)zB;
    bias += zz * (long long)zBias;
    C    += zz * (long long)zC;
    if (SPLIT) {
        Chi += zz * (long long)zChi; Clo += zz * (long long)zChi;
        vthi += zz * (long long)zVt; vtlo += zz * (long long)zVt;
    }

    int bm = blockIdx.y * MT, bn = blockIdx.x << 7;
    int tid = threadIdx.x;
    int lane = tid & 63, wid = tid >> 6;
    int wm = wid >> 1, wn = wid & 1;
    int fr = lane & 15, kg = (lane >> 4) << 3;

    int ar = tid >> 2, akc = (tid & 3) << 3;
    int bnr = tid >> 1, bkc = (tid & 1) << 4;
    bool astage = ar < MT;

    long long arow = 0; bool avalid = false;
    if (astage) {
        int gr = bm + ar;
        avalid = gr < M;
        if (GATHER) arow = avalid ? (long long)gidx[gr] : 0;
        else        arow = avalid ? (long long)gr : 0;
    }

    f32x4 acc[AI][4] = {};

    for (int k0 = 0; k0 < K; k0 += 32) {
        if (astage) {
            if (AMODE == 0) {
                float vv[8];
                if (avalid) {
                    float4 v0 = *(const float4*)&A[arow * lda + k0 + akc];
                    float4 v1 = *(const float4*)&A[arow * lda + k0 + akc + 4];
                    vv[0] = v0.x; vv[1] = v0.y; vv[2] = v0.z; vv[3] = v0.w;
                    vv[4] = v1.x; vv[5] = v1.y; vv[6] = v1.z; vv[7] = v1.w;
                } else {
                    #pragma unroll
                    for (int e = 0; e < 8; ++e) vv[e] = 0.f;
                }
                union { unsigned short u[8]; u32x4 v; } ph, pl;
                #pragma unroll
                for (int e = 0; e < 8; ++e) {
                    unsigned short h = f2bf(vv[e]);
                    ph.u[e] = h;
                    pl.u[e] = f2bf(vv[e] - bf2f(h));
                }
                *(u32x4*)&Ah[ar * 40 + akc] = ph.v;
                *(u32x4*)&Al[ar * 40 + akc] = pl.v;
            } else {
                u32x4 zv = {0u, 0u, 0u, 0u};
                u32x4 vh = zv, vl = zv;
                if (avalid) {
                    vh = *(const u32x4*)&Ahi[arow * lda + k0 + akc];
                    vl = *(const u32x4*)&Alo[arow * lda + k0 + akc];
                }
                *(u32x4*)&Ah[ar * 40 + akc] = vh;
                *(u32x4*)&Al[ar * 40 + akc] = vl;
            }
        }
        {
            long long boff = (long long)(bn + bnr) * K + k0 + bkc;
            *(u32x4*)&Bh[bnr * 40 + bkc]     = *(const u32x4*)&Bth[boff];
            *(u32x4*)&Bh[bnr * 40 + bkc + 8] = *(const u32x4*)&Bth[boff + 8];
            *(u32x4*)&Bl[bnr * 40 + bkc]     = *(const u32x4*)&Btl[boff];
            *(u32x4*)&Bl[bnr * 40 + bkc + 8] = *(const u32x4*)&Btl[boff + 8];
        }
        __syncthreads();

        bf16x8 af[AI], alf[AI], bfj[4], blf[4];
        #pragma unroll
        for (int i = 0; i < AI; ++i) {
            int row = (MT == 64 ? wm * 32 + i * 16 : wm * 16) + fr;
            af[i]  = *(const bf16x8*)&Ah[row * 40 + kg];
            alf[i] = *(const bf16x8*)&Al[row * 40 + kg];
        }
        #pragma unroll
        for (int j = 0; j < 4; ++j) {
            int row = wn * 64 + j * 16 + fr;
            bfj[j] = *(const bf16x8*)&Bh[row * 40 + kg];
            blf[j] = *(const bf16x8*)&Bl[row * 40 + kg];
        }
        #pragma unroll
        for (int i = 0; i < AI; ++i)
        #pragma unroll
        for (int j = 0; j < 4; ++j) {
            acc[i][j] = __builtin_amdgcn_mfma_f32_16x16x32_bf16(af[i],  bfj[j], acc[i][j], 0, 0, 0);
            acc[i][j] = __builtin_amdgcn_mfma_f32_16x16x32_bf16(af[i],  blf[j], acc[i][j], 0, 0, 0);
            acc[i][j] = __builtin_amdgcn_mfma_f32_16x16x32_bf16(alf[i], bfj[j], acc[i][j], 0, 0, 0);
        }
        __syncthreads();
    }

    #pragma unroll
    for (int i = 0; i < AI; ++i) {
        int rbase = bm + (MT == 64 ? wm * 32 + i * 16 : wm * 16) + ((lane >> 4) << 2);
        #pragma unroll
        for (int j = 0; j < 4; ++j) {
            int ccol = bn + wn * 64 + j * 16 + fr;
            float bv = bias[ccol];
            #pragma unroll
            for (int r = 0; r < 4; ++r) {
                int row = rbase + r;
                if (row < M) {
                    float val = acc[i][j][r] + bv;
                    if (EPI == 1) val = mishf(val);
                    if (EPI == 2) val = fmaxf(val, 0.f);
                    if (SPLIT) {
                        unsigned short hh = f2bf(val);
                        unsigned short ll = f2bf(val - bf2f(hh));
                        if (ccol < nhl) {
                            Chi[(long long)row * ldhl + ccol] = hh;
                            Clo[(long long)row * ldhl + ccol] = ll;
                        } else {
                            int bb = row / 400, m = row - bb * 400;
                            long long vi = ((long long)(bb * 512 + (ccol - 1024))) * 416 + m;
                            vthi[vi] = hh;
                            vtlo[vi] = ll;
                        }
                    } else {
                        C[(long long)row * ldc + ccol] = val;
                    }
                }
            }
        }
    }
}

// ---------------------------------------------------------------------------
// Weight prep kernels (write-coalesced)
// ---------------------------------------------------------------------------
__global__ __launch_bounds__(256) void prep_wqkv(
    const float* __restrict__ wq, const float* __restrict__ wk,
    const float* __restrict__ wv,
    unsigned short* __restrict__ whi, unsigned short* __restrict__ wlo,
    int obase, int total)
{
    int idx = blockIdx.x * 256 + threadIdx.x;
    if (idx >= total) return;
    int o = obase + idx / 786432;
    int rem = idx % 786432;
    int n = rem >> 9, k = rem & 511;
    int sel = n >> 9, col = n & 511;
    const float* W = sel == 0 ? wq : (sel == 1 ? wk : wv);
    float v = W[(long long)o * 262144 + k * 512 + col];
    unsigned short h = f2bf(v);
    whi[idx] = h;
    wlo[idx] = f2bf(v - bf2f(h));
}

__global__ __launch_bounds__(256) void prep_woiw(
    const float* __restrict__ wo, const float* __restrict__ wi,
    const float* __restrict__ wout,
    unsigned short* __restrict__ whi, unsigned short* __restrict__ wlo,
    int obase, int total)
{
    int idx = blockIdx.x * 256 + threadIdx.x;
    if (idx >= total) return;
    int o = obase + idx / 655360;
    int rem = idx % 655360;
    float v;
    if (rem < 262144) {
        int n = rem >> 9, k = rem & 511;
        v = wo[(long long)o * 262144 + k * 512 + n];
    } else if (rem < 524288) {
        int nk = rem - 262144;
        int n = nk >> 9, k = nk & 511;
        v = wi[(long long)o * 262144 + k * 512 + n];
    } else {
        int nk = rem - 524288;
        int n = nk >> 9, k = nk & 511;   // n < 256
        v = wout[(long long)o * 131072 + k * 256 + n];
    }
    unsigned short h = f2bf(v);
    whi[idx] = h;
    wlo[idx] = f2bf(v - bf2f(h));
}

__global__ __launch_bounds__(256) void prep_wcnn(
    const float* __restrict__ w,
    unsigned short* __restrict__ whi, unsigned short* __restrict__ wlo)
{
    int idx = blockIdx.x * 256 + threadIdx.x;
    if (idx >= 256 * 768) return;
    int n = idx / 768, k = idx % 768;
    float v = w[k * 256 + n];
    unsigned short h = f2bf(v);
    whi[idx] = h;
    wlo[idx] = f2bf(v - bf2f(h));
}

// ---------------------------------------------------------------------------
// Fused setup
// ---------------------------------------------------------------------------
__global__ __launch_bounds__(256) void setup_kernel(
    const float* __restrict__ x,
    const float* __restrict__ bq, const float* __restrict__ bk,
    const float* __restrict__ bv,
    float* __restrict__ mk, int* __restrict__ relT, int* __restrict__ convidx,
    float* __restrict__ f1pad, float* __restrict__ bqkv,
    unsigned short* __restrict__ vt_hi, unsigned short* __restrict__ vt_lo,
    int nOrg)
{
    int i = blockIdx.x * 256 + threadIdx.x;
    if (i < 3200) {
        const float* xr = x + (long long)i * 128;
        mk[i] = xr[4];
        mk[3200 + i] = fmaxf(xr[2], xr[3]);
        mk[6400 + i] = xr[0];
        mk[9600 + i] = xr[1];
        convidx[i] = (i / 400) * 402 + (i % 400);
    }
    int j = i - 3200;
    if (j >= 0 && j < 799) {
        int rel = j - 399;
        int sgn = (rel > 0) - (rel < 0);
        int ab = (rel < 300 && rel > -300) ? 299 : (rel < 0 ? -rel : rel);
        long long bpos;
        if (ab <= 300) bpos = rel;
        else {
            double lp = ceil(log((double)ab / 300.0) / log(599.0 / 300.0) * 299.0) + 300.0;
            bpos = (long long)lp * sgn;
        }
        long long c2p = bpos + 600;
        c2p = c2p < 0 ? 0 : (c2p > 1199 ? 1199 : c2p);
        relT[j] = (int)c2p;
    }
    int k = i - 4000;
    if (k >= 0 && k < 4096) {
        int b = k >> 9, rem = k & 511;
        int row = b * 402 + (rem < 256 ? 0 : 401);
        f1pad[(long long)row * 256 + (rem & 255)] = 0.f;
    }
    int m = i - 8100;
    if (m >= 0 && m < 6144) {
        int o = m / 1536, n = m % 1536;
        float v;
        if (n < 512) v = bq[o * 512 + n];
        else if (n < 1024) v = bk[o * 512 + n - 512];
        else v = bv[o * 512 + n - 1024];
        bqkv[m] = v;
    }
    int v = i - 14244;
    if (v >= 0 && v < nOrg * 65536) {   // vt pad cols [400..416) zero, as u32
        int og = v >> 16, rem = v & 65535;
        int vb = rem & 32767;
        int row = vb >> 3, c = vb & 7;
        unsigned int* p = (unsigned int*)((rem < 32768) ? vt_hi : vt_lo);
        p[(long long)og * 851968 + row * 208 + 200 + c] = 0u;
    }
}

// ---------------------------------------------------------------------------
// LayerNorm, wave-per-row. Organ-batched (o = row/rpo). RES: split residual.
// OSPL: 1 -> write split hi/lo, 0 -> write f32.
// ---------------------------------------------------------------------------
template<bool RES, int HD, int OSPL>
__global__ __launch_bounds__(256) void ln2_kernel(
    const float* __restrict__ X,
    const unsigned short* __restrict__ Rhi, const unsigned short* __restrict__ Rlo,
    const float* __restrict__ g, const float* __restrict__ be,
    float* __restrict__ Y,
    unsigned short* __restrict__ Yhi, unsigned short* __restrict__ Ylo,
    int rows, int rpo)
{
    constexpr int EPL = HD / 64;
    int wv = threadIdx.x >> 6, lane = threadIdx.x & 63;
    long long row = (long long)blockIdx.x * 4 + wv;
    if (row >= rows) return;
    int o = (int)(row / rpo);
    long long rrow = row % rpo;
    const float* x = X + row * HD;
    float v[EPL];
    #pragma unroll
    for (int q = 0; q < EPL / 4; ++q) {
        float4 a = *(const float4*)&x[lane * EPL + q * 4];
        v[q*4+0] = a.x; v[q*4+1] = a.y; v[q*4+2] = a.z; v[q*4+3] = a.w;
        if (RES) {
            us4 rh = *(const us4*)&Rhi[rrow * HD + lane * EPL + q * 4];
            us4 rl = *(const us4*)&Rlo[rrow * HD + lane * EPL + q * 4];
            #pragma unroll
            for (int e = 0; e < 4; ++e) v[q*4+e] += bf2f(rh[e]) + bf2f(rl[e]);
        }
    }
    float s = 0.f;
    #pragma unroll
    for (int e = 0; e < EPL; ++e) s += v[e];
    #pragma unroll
    for (int d = 1; d < 64; d <<= 1) s += __shfl_xor(s, d, 64);
    float mean = s * (1.f / HD);
    float s2 = 0.f;
    #pragma unroll
    for (int e = 0; e < EPL; ++e) { float d0 = v[e] - mean; s2 += d0 * d0; }
    #pragma unroll
    for (int d = 1; d < 64; d <<= 1) s2 += __shfl_xor(s2, d, 64);
    float inv = 1.f / sqrtf(s2 * (1.f / HD) + 1e-7f);
    #pragma unroll
    for (int q = 0; q < EPL / 4; ++q) {
        int c = lane * EPL + q * 4;
        float4 gg = *(const float4*)&g[o * HD + c];
        float4 bb = *(const float4*)&be[o * HD + c];
        float ov[4];
        ov[0] = (v[q*4+0] - mean) * inv * gg.x + bb.x;
        ov[1] = (v[q*4+1] - mean) * inv * gg.y + bb.y;
        ov[2] = (v[q*4+2] - mean) * inv * gg.z + bb.z;
        ov[3] = (v[q*4+3] - mean) * inv * gg.w + bb.w;
        if (OSPL) {
            us4 ph, pl;
            #pragma unroll
            for (int e = 0; e < 4; ++e) {
                unsigned short hh = f2bf(ov[e]);
                ph[e] = hh;
                pl[e] = f2bf(ov[e] - bf2f(hh));
            }
            *(us4*)&Yhi[row * HD + c] = ph;
            *(us4*)&Ylo[row * HD + c] = pl;
        } else {
            float4 of; of.x = ov[0]; of.y = ov[1]; of.z = ov[2]; of.w = ov[3];
            *(float4*)&Y[row * HD + c] = of;
        }
    }
}

// ---------------------------------------------------------------------------
// MFMA fused disentangled flash attention (round 13): KV-SPLIT.
// 2 waves per 128-thread workgroup share one (lt,h,b,o) q-tile; wave w
// processes KV tiles [w*7, min(13,w*7+7)). Each wave runs the R11
// barrier-free single-wave loop on its half, then ONE __syncthreads and a
// flash partial merge (m/l/O rescale) through LDS. Halves each wave's
// serial chain and doubles wave-level parallelism; no extra global memory.
// 1-D grid (nBlocks %8==0), XCD-swizzled.
// ---------------------------------------------------------------------------
__global__ __launch_bounds__(128) void attn_kernel(
    const unsigned short* __restrict__ qk_hi, const unsigned short* __restrict__ qk_lo,
    const unsigned short* __restrict__ vt_hi, const unsigned short* __restrict__ vt_lo,
    const unsigned short* __restrict__ pkg_hi, const unsigned short* __restrict__ pkg_lo,
    const float* __restrict__ mask,
    unsigned short* __restrict__ ctxh, unsigned short* __restrict__ ctxl)
{
    const float scale = 0.07216878364870322f;       // 1/sqrt(64*3)
    const float NEGMIN = -3.402823466e38f;
    int w = threadIdx.x >> 6;                        // KV-split index
    int lane = threadIdx.x & 63;
    // --- XCD-aware bijective tile mapping ---
    int bb = blockIdx.x;
    int per_xcd = gridDim.x >> 3;                    // gridDim.x % 8 == 0
    int t = ((bb & 7) * per_xcd) + (bb >> 3);
    int lt = t % 25;
    int combo = t / 25;                              // [0, 8*nOrg*8)
    int h = combo & 7, z = combo >> 3;
    int b = z & 7, o = z >> 3;
    qk_hi  += (long long)o * 3276800;
    qk_lo  += (long long)o * 3276800;
    vt_hi  += (long long)o * 1703936;
    vt_lo  += (long long)o * 1703936;
    pkg_hi += (long long)o * 818176;
    mask   += o * 3200;
    ctxh   += (long long)o * 1638400;
    ctxl   += (long long)o * 1638400;

    int l0 = lt * 16;                    // 25*16 = 400: q rows always valid
    int fr = lane & 15, kg8 = (lane >> 4) << 3, g4 = (lane >> 4) << 2;

    __shared__ float T2c[2][16 * 36];    // per-wave slices
    __shared__ float T3c[2][32 * 20];
    __shared__ unsigned short Sth[2][16 * 40], Stl[2][16 * 40];
    __shared__ float Om[2][16 * 64];     // partial O exchange
    __shared__ float Mm[2][16], Ll[2][16];

    // Q frag (A rows = l0 + fr), loaded once
    bf16x8 qfh[2], qfl[2];
    {
        long long base = ((long long)(b * 400 + l0 + fr)) * 1024 + h * 64 + kg8;
        #pragma unroll
        for (int kk = 0; kk < 2; ++kk) {
            qfh[kk] = *(const bf16x8*)(qk_hi + base + kk * 32);
            qfl[kk] = *(const bf16x8*)(qk_lo + base + kk * 32);
        }
    }
    float wlv_r[4], ms[4], ls[4];
    #pragma unroll
    for (int r = 0; r < 4; ++r) {
        wlv_r[r] = mask[b * 400 + l0 + g4 + r];
        ms[r] = -INFINITY;
        ls[r] = 0.f;
    }
    f32x4 O[4] = {};
    long long vtbase = ((long long)(b * 512 + h * 64)) * 416;

    int mt_begin = w * 7, mt_end = w == 0 ? 7 : 13;
    for (int mt = mt_begin; mt < mt_end; ++mt) {
        int m0 = mt * 32;
        int D0 = l0 - m0 + 368;
        // ---- load batch: K hi/lo + pk band (hi) + pq band (hi) ----
        bf16x8 kfh[2][2], kfl[2][2];
        #pragma unroll
        for (int jf = 0; jf < 2; ++jf) {
            int kr = m0 + jf * 16 + fr;
            bool valid = kr < 400;
            long long base = ((long long)(b * 400 + (valid ? kr : 0))) * 1024 + 512 + h * 64 + kg8;
            #pragma unroll
            for (int kk = 0; kk < 2; ++kk) {
                kfh[jf][kk] = load_bf8(qk_hi + base + kk * 32, valid);
                kfl[jf][kk] = load_bf8(qk_lo + base + kk * 32, valid);
            }
        }
        bf16x8 b2h[3][2], b3h[3][2];
        #pragma unroll
        for (int c = 0; c < 3; ++c) {
            int dd = D0 + c * 16 + fr;
            bool vv = (unsigned)dd < 799u;
            long long base = (long long)(vv ? dd : 0) * 1024 + h * 64 + kg8;
            #pragma unroll
            for (int kk = 0; kk < 2; ++kk) {
                b2h[c][kk] = load_bf8(pkg_hi + base + 512 + kk * 32, vv);
                b3h[c][kk] = load_bf8(pkg_hi + base + kk * 32, vv);
            }
        }
        // ---- T1 = Q@K^T (x3), T2 = Q@PKband^T (band hi-only) ----
        __builtin_amdgcn_s_setprio(1);
        f32x4 aT1[2] = {};
        #pragma unroll
        for (int jf = 0; jf < 2; ++jf)
        #pragma unroll
        for (int kk = 0; kk < 2; ++kk) {
            aT1[jf] = __builtin_amdgcn_mfma_f32_16x16x32_bf16(qfh[kk], kfh[jf][kk], aT1[jf], 0, 0, 0);
            aT1[jf] = __builtin_amdgcn_mfma_f32_16x16x32_bf16(qfh[kk], kfl[jf][kk], aT1[jf], 0, 0, 0);
            aT1[jf] = __builtin_amdgcn_mfma_f32_16x16x32_bf16(qfl[kk], kfh[jf][kk], aT1[jf], 0, 0, 0);
        }
        f32x4 aT2[3] = {};
        #pragma unroll
        for (int c = 0; c < 3; ++c)
        #pragma unroll
        for (int kk = 0; kk < 2; ++kk) {
            aT2[c] = __builtin_amdgcn_mfma_f32_16x16x32_bf16(qfh[kk], b2h[c][kk], aT2[c], 0, 0, 0);
            aT2[c] = __builtin_amdgcn_mfma_f32_16x16x32_bf16(qfl[kk], b2h[c][kk], aT2[c], 0, 0, 0);
        }
        __builtin_amdgcn_s_setprio(0);
        // ---- V loads issued here (latency hides under T3/softmax) ----
        bf16x8 vfh[4], vfl[4];
        #pragma unroll
        for (int f = 0; f < 4; ++f) {
            long long a = vtbase + (long long)(f * 16 + fr) * 416 + m0 + kg8;
            vfh[f] = *(const bf16x8*)&vt_hi[a];
            vfl[f] = *(const bf16x8*)&vt_lo[a];
        }
        float wm_c[2];
        #pragma unroll
        for (int cf = 0; cf < 2; ++cf) {
            int mg = m0 + cf * 16 + fr;
            wm_c[cf] = (mg < 400) ? mask[b * 400 + mg] : 0.f;
        }
        // ---- T3 = K@PQband^T (band hi-only, 4 (jf,c) combos) ----
        __builtin_amdgcn_s_setprio(1);
        f32x4 aT3[2][2] = {};
        #pragma unroll
        for (int jf = 0; jf < 2; ++jf)
        #pragma unroll
        for (int ci = 0; ci < 2; ++ci) {
            int c = ci + (jf ^ 1);       // jf=0 -> c in {1,2}; jf=1 -> c in {0,1}
            #pragma unroll
            for (int kk = 0; kk < 2; ++kk) {
                aT3[jf][ci] = __builtin_amdgcn_mfma_f32_16x16x32_bf16(kfh[jf][kk], b3h[c][kk], aT3[jf][ci], 0, 0, 0);
                aT3[jf][ci] = __builtin_amdgcn_mfma_f32_16x16x32_bf16(kfl[jf][kk], b3h[c][kk], aT3[jf][ci], 0, 0, 0);
            }
        }
        __builtin_amdgcn_s_setprio(0);
        // ---- banded scatter (in-wave LDS ordering, no barrier) ----
        #pragma unroll
        for (int c = 0; c < 3; ++c)
        #pragma unroll
        for (int r = 0; r < 4; ++r) {
            int i = g4 + r;
            int d = c * 16 + fr - i;
            if ((unsigned)d < 32u)
                T2c[w][i * 36 + d] = aT2[c][r];
        }
        #pragma unroll
        for (int jf = 0; jf < 2; ++jf)
        #pragma unroll
        for (int ci = 0; ci < 2; ++ci) {
            int c = ci + (jf ^ 1);
            #pragma unroll
            for (int r = 0; r < 4; ++r) {
                int j3 = jf * 16 + g4 + r;
                int d2 = c * 16 + fr + j3 - 31;
                if ((unsigned)d2 < 16u)
                    T3c[w][j3 * 20 + d2] = aT3[jf][ci][r];
            }
        }
        // ---- assemble scores ----
        float sc0[4], sc1[4];
        #pragma unroll
        for (int r = 0; r < 4; ++r) {
            int i = g4 + r;
            {
                int j = fr;
                bool jv = (m0 + j) < 400;
                sc0[r] = !jv ? -INFINITY :
                    ((wlv_r[r] != 0.f && wm_c[0] != 0.f) ?
                     (aT1[0][r] + T2c[w][i * 36 + 31 - j] + T3c[w][j * 20 + i]) * scale : NEGMIN);
            }
            {
                int j = 16 + fr;
                bool jv = (m0 + j) < 400;
                sc1[r] = !jv ? -INFINITY :
                    ((wlv_r[r] != 0.f && wm_c[1] != 0.f) ?
                     (aT1[1][r] + T2c[w][i * 36 + 31 - j] + T3c[w][j * 20 + i]) * scale : NEGMIN);
            }
        }
        // ---- wave-local flash softmax ----
        float corr[4];
        #pragma unroll
        for (int r = 0; r < 4; ++r) {
            float mx = fmaxf(sc0[r], sc1[r]);
            #pragma unroll
            for (int d = 1; d < 16; d <<= 1) mx = fmaxf(mx, __shfl_xor(mx, d, 64));
            float mn = fmaxf(ms[r], mx);
            corr[r] = __expf(ms[r] - mn);
            ms[r] = mn;
            float p0 = __expf(sc0[r] - mn), p1 = __expf(sc1[r] - mn);
            float rs = p0 + p1;
            #pragma unroll
            for (int d = 1; d < 16; d <<= 1) rs += __shfl_xor(rs, d, 64);
            ls[r] = ls[r] * corr[r] + rs;
            int i = g4 + r;
            unsigned short h0 = f2bf(p0);
            Sth[w][i * 40 + fr] = h0;
            Stl[w][i * 40 + fr] = f2bf(p0 - bf2f(h0));
            unsigned short h1 = f2bf(p1);
            Sth[w][i * 40 + 16 + fr] = h1;
            Stl[w][i * 40 + 16 + fr] = f2bf(p1 - bf2f(h1));
        }
        // ---- PV (P transposed via in-wave LDS) ----
        #pragma unroll
        for (int f = 0; f < 4; ++f)
        #pragma unroll
        for (int r = 0; r < 4; ++r) O[f][r] *= corr[r];
        bf16x8 Pha = *(const bf16x8*)&Sth[w][fr * 40 + kg8];
        bf16x8 Pla = *(const bf16x8*)&Stl[w][fr * 40 + kg8];
        __builtin_amdgcn_s_setprio(1);
        #pragma unroll
        for (int f = 0; f < 4; ++f) {
            O[f] = __builtin_amdgcn_mfma_f32_16x16x32_bf16(Pha, vfh[f], O[f], 0, 0, 0);
            O[f] = __builtin_amdgcn_mfma_f32_16x16x32_bf16(Pha, vfl[f], O[f], 0, 0, 0);
            O[f] = __builtin_amdgcn_mfma_f32_16x16x32_bf16(Pla, vfh[f], O[f], 0, 0, 0);
        }
        __builtin_amdgcn_s_setprio(0);
    }
    // ---- write partials to LDS ----
    #pragma unroll
    for (int f = 0; f < 4; ++f)
    #pragma unroll
    for (int r = 0; r < 4; ++r)
        Om[w][(g4 + r) * 64 + f * 16 + fr] = O[f][r];
    if (fr == 0) {
        #pragma unroll
        for (int r = 0; r < 4; ++r) {
            Mm[w][g4 + r] = ms[r];
            Ll[w][g4 + r] = ls[r];
        }
    }
    __syncthreads();
    // ---- flash merge: wave w writes cols [w*32, w*32+32) ----
    #pragma unroll
    for (int f2 = 0; f2 < 2; ++f2) {
        int col = w * 32 + f2 * 16 + fr;
        #pragma unroll
        for (int r = 0; r < 4; ++r) {
            int row = g4 + r;
            float m0v = Mm[0][row], m1v = Mm[1][row];
            float mv = fmaxf(m0v, m1v);
            float c0 = __expf(m0v - mv), c1 = __expf(m1v - mv);
            float lv = c0 * Ll[0][row] + c1 * Ll[1][row];
            float val = (c0 * Om[0][row * 64 + col] + c1 * Om[1][row * 64 + col]) / lv;
            long long idx = ((long long)(b * 400 + l0 + row)) * 512 + h * 64 + col;
            unsigned short hh = f2bf(val);
            ctxh[idx] = hh;
            ctxl[idx] = f2bf(val - bf2f(hh));
        }
    }
}

// ---------------------------------------------------------------------------
// Chunked pool / meanmax (full-chip), heads
// ---------------------------------------------------------------------------
__global__ __launch_bounds__(256) void pool_part(
    const float* __restrict__ in, long long inOStride,
    const float* __restrict__ mk, float* __restrict__ pp)
{
    int bi = blockIdx.x, c = blockIdx.y, t = threadIdx.x;
    int o = bi >> 3, b = bi & 7;
    int l0 = c * 31, l1 = min(400, l0 + 31);
    const float* ib = in + (long long)o * inOStride + (long long)(b * 400) * 256;
    const float* mkb = mk + o * 3200 + b * 400;
    float s = 0.f, mx = -INFINITY, sw = 0.f;
    for (int l = l0; l < l1; ++l) {
        float wv = mkb[l];
        float v = ib[(long long)l * 256 + t] * wv;
        s += v; mx = fmaxf(mx, v); sw += wv;
    }
    long long base = (long long)(c * gridDim.x + bi) * 514;
    pp[base + t] = s;
    pp[base + 256 + t] = mx;
    if (t == 0) pp[base + 512] = sw;
}

__global__ __launch_bounds__(256) void pool_merge(
    const float* __restrict__ pp, float* __restrict__ pooled, int nBI)
{
    int bi = blockIdx.x, t = threadIdx.x;
    float s = 0.f, mx = -INFINITY, sw = 0.f;
    for (int c = 0; c < 13; ++c) {
        long long base = (long long)(c * nBI + bi) * 514;
        s += pp[base + t];
        mx = fmaxf(mx, pp[base + 256 + t]);
        sw += pp[base + 512];
    }
    int o = bi >> 3, b = bi & 7;
    pooled[o * 4096 + b * 512 + t] = s / (sw + 1e-6f);
    pooled[o * 4096 + b * 512 + 256 + t] = mx;
}

__global__ __launch_bounds__(512) void mm_part(
    const unsigned short* __restrict__ fh, const unsigned short* __restrict__ fl,
    float* __restrict__ mmp)
{
    int b = blockIdx.x, c = blockIdx.y, t = threadIdx.x;
    int l0 = c * 31, l1 = min(400, l0 + 31);
    float s = 0.f, mx = -INFINITY;
    for (int l = l0; l < l1; ++l) {
        long long idx = ((long long)(b * 400 + l)) * 512 + t;
        float v = bf2f(fh[idx]) + bf2f(fl[idx]);
        s += v; mx = fmaxf(mx, v);
    }
    long long base = (long long)(c * 8 + b) * 1024;
    mmp[base + t] = s;
    mmp[base + 512 + t] = mx;
}

__global__ __launch_bounds__(512) void mm_merge(
    const float* __restrict__ mmp, float* __restrict__ mm)
{
    int b = blockIdx.x, t = threadIdx.x;
    float s = 0.f, mx = -INFINITY;
    for (int c = 0; c < 13; ++c) {
        long long base = (long long)(c * 8 + b) * 1024;
        s += mmp[base + t];
        mx = fmaxf(mx, mmp[base + 512 + t]);
    }
    mm[b * 1024 + t] = s / 400.f;
    mm[b * 1024 + 512 + t] = mx;
}

__global__ __launch_bounds__(256) void heads_kernel(
    const float* __restrict__ pooled, const float* __restrict__ mm,
    const float* __restrict__ w_bow1, const float* __restrict__ b_bow1,
    const float* __restrict__ w_bow2, const float* __restrict__ b_bow2,
    const float* __restrict__ w_ext1, const float* __restrict__ b_ext1,
    const float* __restrict__ w_ext2, const float* __restrict__ b_ext2,
    const float* __restrict__ w_org1, const float* __restrict__ b_org1,
    const float* __restrict__ w_org2, const float* __restrict__ b_org2,
    float* __restrict__ out)
{
    int b = blockIdx.x, role = blockIdx.y;
    int t = threadIdx.x;
    __shared__ float inb[1024];
    __shared__ float red[256];
    __shared__ float hid[256];
    if (role == 0) {
        inb[t] = pooled[b * 512 + t];
        inb[256 + t] = pooled[b * 512 + 256 + t];
        __syncthreads();
        float acc = b_bow1[t];
        for (int j = 0; j < 512; ++j) acc += inb[j] * w_bow1[j * 256 + t];
        red[t] = mishf(acc) * w_bow2[t];
        __syncthreads();
        for (int s = 128; s; s >>= 1) { if (t < s) red[t] += red[t + s]; __syncthreads(); }
        if (t == 0) out[b * 11 + 0] = red[0] + b_bow2[0];
    } else if (role == 1) {
        inb[t] = mm[b * 1024 + t];
        inb[256 + t] = mm[b * 1024 + 256 + t];
        inb[512 + t] = mm[b * 1024 + 512 + t];
        inb[768 + t] = mm[b * 1024 + 768 + t];
        __syncthreads();
        float acc = b_ext1[t];
        for (int j = 0; j < 1024; ++j) acc += inb[j] * w_ext1[j * 256 + t];
        red[t] = mishf(acc) * w_ext2[t];
        __syncthreads();
        for (int s = 128; s; s >>= 1) { if (t < s) red[t] += red[t + s]; __syncthreads(); }
        if (t == 0) { out[b * 11 + 1] = red[0] + b_ext2[0]; out[88 + b] = 0.f; }
    } else {
        int i = role - 2;
        inb[t] = pooled[((1 + i) * 8 + b) * 512 + t];
        inb[256 + t] = pooled[((1 + i) * 8 + b) * 512 + 256 + t];
        __syncthreads();
        float acc = b_org1[i * 256 + t];
        for (int j = 0; j < 512; ++j)
            acc += inb[j] * w_org1[((long long)i * 512 + j) * 256 + t];
        hid[t] = mishf(acc);
        __syncthreads();
        for (int c = 0; c < 3; ++c) {
            red[t] = hid[t] * w_org2[(i * 256 + t) * 3 + c];
            __syncthreads();
            for (int s = 128; s; s >>= 1) { if (t < s) red[t] += red[t + s]; __syncthreads(); }
            if (t == 0) out[b * 11 + 2 + i * 3 + c] = red[0] + b_org2[i * 3 + c];
            __syncthreads();
        }
    }
}

// ---------------------------------------------------------------------------
// Launch
// ---------------------------------------------------------------------------
extern "C" void kernel_launch(void* const* d_in, const int* in_sizes, int n_in,
                              void* d_out, int out_size, void* d_ws, size_t ws_size,
                              hipStream_t stream)
{
    const float* x      = (const float*)d_in[0];
    const float* w_mlp  = (const float*)d_in[1];
    const float* b_mlp  = (const float*)d_in[2];
    const float* w_cnn  = (const float*)d_in[3];
    const float* b_cnn  = (const float*)d_in[4];
    const float* rel_emb= (const float*)d_in[5];
    const float* rel_g  = (const float*)d_in[6];
    const float* rel_b  = (const float*)d_in[7];
    const float* wq     = (const float*)d_in[8];
    const float* wk     = (const float*)d_in[9];
    const float* wv     = (const float*)d_in[10];
    const float* wo     = (const float*)d_in[11];
    const float* wi     = (const float*)d_in[12];
    const float* bq     = (const float*)d_in[13];
    const float* bk     = (const float*)d_in[14];
    const float* bv     = (const float*)d_in[15];
    const float* bo     = (const float*)d_in[16];
    const float* bi     = (const float*)d_in[17];
    const float* wout   = (const float*)d_in[18];
    const float* bout   = (const float*)d_in[19];
    const float* ln1g   = (const float*)d_in[20];
    const float* ln1b   = (const float*)d_in[21];
    const float* ln2g   = (const float*)d_in[22];
    const float* ln2b   = (const float*)d_in[23];
    const float* w_bow1 = (const float*)d_in[24];
    const float* b_bow1 = (const float*)d_in[25];
    const float* w_bow2 = (const float*)d_in[26];
    const float* b_bow2 = (const float*)d_in[27];
    const float* w_ext1 = (const float*)d_in[28];
    const float* b_ext1 = (const float*)d_in[29];
    const float* w_ext2 = (const float*)d_in[30];
    const float* b_ext2 = (const float*)d_in[31];
    const float* w_org1 = (const float*)d_in[32];
    const float* b_org1 = (const float*)d_in[33];
    const float* w_org2 = (const float*)d_in[34];
    const float* b_org2 = (const float*)d_in[35];

    float* ws = (float*)d_ws;
    float* outf = (float*)d_out;
    const bool big = ws_size >= 143012736ull;

    if (big) {
        // ---------------- organ-batched path ----------------
        unsigned short* featsh = (unsigned short*)(ws + 0);        // 3200x512
        unsigned short* featsl = (unsigned short*)(ws + 819200);
        float* ctxR     = ws + 1638400;      // 6,553,600 fl
        float* f1pad    = ctxR;
        unsigned short* ctxh = (unsigned short*)ctxR;              // 4x3200x512
        unsigned short* ctxl = (unsigned short*)(ws + 4915200);
        float* qkA_f    = ws + 8192000;
        float* qkB_f    = ws + 14745600;
        unsigned short* qkA = (unsigned short*)qkA_f;
        unsigned short* qkB = (unsigned short*)qkB_f;
        unsigned short* rellnh = (unsigned short*)qkA_f;           // 4800x512
        unsigned short* rellnl = (unsigned short*)(ws + 8192000 + 1228800);
        unsigned short* vtA = (unsigned short*)(ws + 21299200);    // 4x4096x416
        unsigned short* vtB = (unsigned short*)(ws + 24707072);
        unsigned short* pkgA = (unsigned short*)(ws + 28114944);   // 4x799x1024
        unsigned short* pkgB = (unsigned short*)(ws + 29751296);
        unsigned short* whiA = (unsigned short*)(ws + 31387648);   // 4x786,432
        unsigned short* wloA = (unsigned short*)(ws + 32960512);
        unsigned short* wcnn_hi = (unsigned short*)(ws + 35188736);
        unsigned short* wcnn_lo = (unsigned short*)(ws + 35287040);
        float* bqkvb   = ws + 35385344;
        float* masksb  = ws + 35391488;
        float* pooledb = ws + 35404288;
        float* mmb     = ws + 35420672;
        int*   relidx  = (int*)(ws + 35428864);
        int*   convidx = (int*)(ws + 35429664);
        float* poolpart= ws + 35432864;
        float* mmpart  = ws + 35646688;
        float* tmp_all   = qkA_f;                                  // WO out (f32)
        unsigned short* h1h = (unsigned short*)qkB_f;              // LN1 out split
        unsigned short* h1l = (unsigned short*)(ws + 14745600 + 3276800);
        unsigned short* interh = (unsigned short*)qkA_f;           // WI out split
        unsigned short* interl = (unsigned short*)(ws + 8192000 + 3276800);
        float* outenc_all = (float*)vtA;                           // 4x819,200 f32
        float* outln_all  = ctxR;                                  // 4x819,200 f32
        unsigned short* whiB_all = whiA;
        unsigned short* wloB_all = wloA;

        gemm_bias<1><<<dim3(4, 50), 256, 0, stream>>>(
            x, w_mlp, b_mlp, f1pad, featsh, featsl, 3200, 256, 128, 512);
        setup_kernel<<<1080, 256, 0, stream>>>(x, bq, bk, bv, masksb, relidx, convidx,
                                               f1pad, bqkvb, vtA, vtB, 4);
        prep_wcnn<<<768, 256, 0, stream>>>(w_cnn, wcnn_hi, wcnn_lo);
        gemm_mfma<2, true, 0, true, 32><<<dim3(2, 100), 256, 0, stream>>>(
            f1pad, nullptr, nullptr, wcnn_hi, wcnn_lo, b_cnn, nullptr,
            3200, 768, 256, 0, convidx, featsh + 256, featsl + 256, 512, 1 << 30,
            nullptr, nullptr, 0, 0, 0, 0, 0, 0);

        ln2_kernel<false, 512, 1><<<1200, 256, 0, stream>>>(
            rel_emb, nullptr, nullptr, rel_g, rel_b, nullptr, rellnh, rellnl, 4800, 1200);
        prep_wqkv<<<12288, 256, 0, stream>>>(wq, wk, wv, whiA, wloA, 0, 3145728);
        gemm_mfma<0, true, 1, true, 64><<<dim3(8, 13, 4), 256, 0, stream>>>(
            nullptr, rellnh, rellnl, whiA, wloA, bqkvb, nullptr, 799, 512, 512, 0, relidx,
            pkgA, pkgB, 1024, 1024, nullptr, nullptr,
            614400, 786432, 1536, 0, 818176, 0);
        gemm_mfma<0, false, 1, true, 64><<<dim3(12, 50, 4), 256, 0, stream>>>(
            nullptr, featsh, featsl, whiA, wloA, bqkvb, nullptr, 3200, 512, 512, 0, nullptr,
            qkA, qkB, 1024, 1024, vtA, vtB,
            0, 786432, 1536, 0, 3276800, 1703936);
        prep_woiw<<<10240, 256, 0, stream>>>(wo, wi, wout, whiB_all, wloB_all,
                                             0, 2621440);
        // attention: KV-split (2 waves/WG), 6400 blocks, XCD-swizzled
        attn_kernel<<<6400, 128, 0, stream>>>(qkA, qkB, vtA, vtB,
            pkgA, pkgB, masksb, ctxh, ctxl);
        gemm_mfma<0, false, 1, false, 32><<<dim3(4, 100, 4), 256, 0, stream>>>(
            nullptr, ctxh, ctxl, whiB_all, wloB_all, bo, tmp_all,
            3200, 512, 512, 512, nullptr, nullptr, nullptr, 0, 0, nullptr, nullptr,
            1638400, 655360, 512, 1638400, 0, 0);
        ln2_kernel<true, 512, 1><<<3200, 256, 0, stream>>>(
            tmp_all, featsh, featsl, ln1g, ln1b, nullptr, h1h, h1l, 12800, 3200);
        gemm_mfma<1, false, 1, true, 32><<<dim3(4, 100, 4), 256, 0, stream>>>(
            nullptr, h1h, h1l, whiB_all + 262144, wloB_all + 262144, bi, nullptr,
            3200, 512, 512, 0, nullptr, interh, interl, 512, 1 << 30, nullptr, nullptr,
            1638400, 655360, 512, 0, 1638400, 0);
        gemm_mfma<0, false, 1, false, 32><<<dim3(2, 100, 4), 256, 0, stream>>>(
            nullptr, interh, interl, whiB_all + 524288, wloB_all + 524288, bout, outenc_all,
            3200, 512, 512, 256, nullptr, nullptr, nullptr, 0, 0, nullptr, nullptr,
            1638400, 655360, 256, 819200, 0, 0);
        ln2_kernel<false, 256, 0><<<3200, 256, 0, stream>>>(
            outenc_all, nullptr, nullptr, ln2g, ln2b, outln_all, nullptr, nullptr,
            12800, 3200);

        pool_part<<<dim3(32, 13), 256, 0, stream>>>(outln_all, 819200, masksb, poolpart);
        pool_merge<<<32, 256, 0, stream>>>(poolpart, pooledb, 32);
        mm_part<<<dim3(8, 13), 512, 0, stream>>>(featsh, featsl, mmpart);
        mm_merge<<<8, 512, 0, stream>>>(mmpart, mmb);
        heads_kernel<<<dim3(8, 5), 256, 0, stream>>>(pooledb, mmb,
            w_bow1, b_bow1, w_bow2, b_bow2, w_ext1, b_ext1, w_ext2, b_ext2,
            w_org1, b_org1, w_org2, b_org2, outf);
        return;
    }

    // ---------------- per-organ fallback path ----------------
    unsigned short* featsh = (unsigned short*)(ws + 0);
    unsigned short* featsl = (unsigned short*)(ws + 819200);
    float* ctxR    = ws + 1638400;
    float* f1pad   = ctxR;
    unsigned short* ctxh = (unsigned short*)ctxR;
    unsigned short* ctxl = (unsigned short*)(ws + 1638400 + 819200);
    float* qkvA_f  = ws + 3276800;
    float* qkvB_f  = ws + 4915200;
    unsigned short* qkv_hi = (unsigned short*)qkvA_f;
    unsigned short* qkv_lo = (unsigned short*)qkvB_f;
    unsigned short* rellnh = (unsigned short*)qkvB_f;
    unsigned short* rellnl = (unsigned short*)(ws + 4915200 + 307200);
    unsigned short* pkg_hi = (unsigned short*)(ws + 6553600);
    unsigned short* pkg_lo = (unsigned short*)(ws + 6963200);
    unsigned short* vt_hi  = (unsigned short*)(ws + 7372800);
    unsigned short* vt_lo  = (unsigned short*)(ws + 8224768);
    unsigned short* whi    = (unsigned short*)(ws + 9076736);
    unsigned short* wlo    = (unsigned short*)(ws + 9469952);
    float* bqkvb   = ws + 9863168;
    float* masksb  = ws + 9869312;
    float* pooledb = ws + 9882112;
    float* mmb     = ws + 9898496;
    int*   relidx  = (int*)(ws + 9906688);
    unsigned short* wcnn_hi = (unsigned short*)(ws + 9907488);
    unsigned short* wcnn_lo = (unsigned short*)(ws + 10005792);
    int*   convidx = (int*)(ws + 10104096);
    float* poolpart= ws + 10107296;
    float* mmpart  = ws + 10160752;
    float* tmp     = qkvA_f;
    unsigned short* h1h = (unsigned short*)qkvB_f;
    unsigned short* h1l = (unsigned short*)(ws + 4915200 + 819200);
    unsigned short* interh = (unsigned short*)qkvA_f;
    unsigned short* interl = (unsigned short*)(ws + 3276800 + 819200);
    float* outenc  = (float*)vt_hi;
    float* outln   = ctxR;

    gemm_bias<1><<<dim3(4, 50), 256, 0, stream>>>(
        x, w_mlp, b_mlp, f1pad, featsh, featsl, 3200, 256, 128, 512);
    setup_kernel<<<312, 256, 0, stream>>>(x, bq, bk, bv, masksb, relidx, convidx,
                                          f1pad, bqkvb, vt_hi, vt_lo, 1);
    prep_wcnn<<<768, 256, 0, stream>>>(w_cnn, wcnn_hi, wcnn_lo);
    gemm_mfma<2, true, 0, true, 32><<<dim3(2, 100), 256, 0, stream>>>(
        f1pad, nullptr, nullptr, wcnn_hi, wcnn_lo, b_cnn, nullptr,
        3200, 768, 256, 0, convidx, featsh + 256, featsl + 256, 512, 1 << 30,
        nullptr, nullptr, 0, 0, 0, 0, 0, 0);

    for (int o = 0; o < 4; ++o) {
        ln2_kernel<false, 512, 1><<<300, 256, 0, stream>>>(
            rel_emb + (long long)o * 614400, nullptr, nullptr,
            rel_g + o * 512, rel_b + o * 512, nullptr, rellnh, rellnl, 1200, 1200);
        prep_wqkv<<<3072, 256, 0, stream>>>(wq, wk, wv, whi, wlo, o, 786432);
        gemm_mfma<0, true, 1, true, 64><<<dim3(8, 13), 256, 0, stream>>>(
            nullptr, rellnh, rellnl, whi, wlo, bqkvb + o * 1536, nullptr,
            799, 512, 512, 0, relidx, pkg_hi, pkg_lo, 1024, 1024, nullptr, nullptr,
            0, 0, 0, 0, 0, 0);
        gemm_mfma<0, false, 1, true, 64><<<dim3(12, 50), 256, 0, stream>>>(
            nullptr, featsh, featsl, whi, wlo, bqkvb + o * 1536, nullptr,
            3200, 512, 512, 0, nullptr, qkv_hi, qkv_lo, 1024, 1024, vt_hi, vt_lo,
            0, 0, 0, 0, 0, 0);
        prep_woiw<<<2560, 256, 0, stream>>>(wo, wi, wout, whi, wlo, o, 655360);
        attn_kernel<<<1600, 128, 0, stream>>>(qkv_hi, qkv_lo, vt_hi, vt_lo,
            pkg_hi, pkg_lo, masksb + o * 3200, ctxh, ctxl);
        gemm_mfma<0, false, 1, false, 32><<<dim3(4, 100), 256, 0, stream>>>(
            nullptr, ctxh, ctxl, whi, wlo, bo + o * 512, tmp,
            3200, 512, 512, 512, nullptr, nullptr, nullptr, 0, 0, nullptr, nullptr,
            0, 0, 0, 0, 0, 0);
        ln2_kernel<true, 512, 1><<<800, 256, 0, stream>>>(
            tmp, featsh, featsl, ln1g + o * 512, ln1b + o * 512, nullptr,
            h1h, h1l, 3200, 3200);
        gemm_mfma<1, false, 1, true, 32><<<dim3(4, 100), 256, 0, stream>>>(
            nullptr, h1h, h1l, whi + 262144, wlo + 262144, bi + o * 512, nullptr,
            3200, 512, 512, 0, nullptr, interh, interl, 512, 1 << 30, nullptr, nullptr,
            0, 0, 0, 0, 0, 0);
        gemm_mfma<0, false, 1, false, 32><<<dim3(2, 100), 256, 0, stream>>>(
            nullptr, interh, interl, whi + 524288, wlo + 524288, bout + o * 256, outenc,
            3200, 512, 512, 256, nullptr, nullptr, nullptr, 0, 0, nullptr, nullptr,
            0, 0, 0, 0, 0, 0);
        ln2_kernel<false, 256, 0><<<800, 256, 0, stream>>>(
            outenc, nullptr, nullptr, ln2g + o * 256, ln2b + o * 256, outln,
            nullptr, nullptr, 3200, 3200);
        pool_part<<<dim3(8, 13), 256, 0, stream>>>(outln, 0,
                                                   masksb + o * 3200, poolpart);
        pool_merge<<<8, 256, 0, stream>>>(poolpart, pooledb + o * 4096, 8);
    }

    mm_part<<<dim3(8, 13), 512, 0, stream>>>(featsh, featsl, mmpart);
    mm_merge<<<8, 512, 0, stream>>>(mmpart, mmb);
    heads_kernel<<<dim3(8, 5), 256, 0, stream>>>(pooledb, mmb,
        w_bow1, b_bow1, w_bow2, b_bow2, w_ext1, b_ext1, w_ext2, b_ext2,
        w_org1, b_org1, w_org2, b_org2, outf);
}

// Round 14
// 706.248 us; speedup vs baseline: 1.0239x; 1.0239x over previous
//
#include <hip/hip_runtime.h>
#include <math.h>

// ---------------------------------------------------------------------------
// Model dims (fixed): B=8 L=400 F=128 D=256 T=256 H=512 NH=8 HD=64 P=1200
// ---------------------------------------------------------------------------

typedef __attribute__((ext_vector_type(8))) short bf16x8;
typedef __attribute__((ext_vector_type(4))) float f32x4;
typedef __attribute__((ext_vector_type(4))) unsigned int u32x4;
typedef __attribute__((ext_vector_type(4))) unsigned short us4;

__device__ __forceinline__ float mishf(float x) {
    float sp = fmaxf(x, 0.f) + log1pf(expf(-fabsf(x)));   // stable softplus
    return x * tanhf(sp);
}

__device__ __forceinline__ unsigned short f2bf(float f) {
    unsigned int u = __float_as_uint(f);
    u = (u + 0x7fffu + ((u >> 16) & 1u)) >> 16;           // RNE
    return (unsigned short)u;
}
__device__ __forceinline__ float bf2f(unsigned short h) {
    return __uint_as_float(((unsigned int)h) << 16);
}

// ---------------------------------------------------------------------------
// fp32 GEMM (front MLP, K=128): writes f1pad (padded conv layout) + split
// bf16 hi/lo feats (cols 0..255 of 512-wide).
// ---------------------------------------------------------------------------
template<int EPI>
__global__ __launch_bounds__(256) void gemm_bias(
    const float* __restrict__ A, const float* __restrict__ Bm,
    const float* __restrict__ bias, float* __restrict__ C2,
    unsigned short* __restrict__ fhi, unsigned short* __restrict__ flo,
    int M, int N, int K, int ldc)
{
    __shared__ float As[16][68];
    __shared__ float Bs[16][68];
    int bm = blockIdx.y << 6, bn = blockIdx.x << 6;
    int tid = threadIdx.x;
    int tm = (tid >> 4) << 2, tn = (tid & 15) << 2;
    int ar = tid >> 2, ac4 = (tid & 3) << 2;
    int br = tid >> 4, bc4 = (tid & 15) << 2;
    float acc[4][4] = {};
    for (int k0 = 0; k0 < K; k0 += 16) {
        float4 av = make_float4(0.f, 0.f, 0.f, 0.f);
        if (bm + ar < M)
            av = *(const float4*)&A[(long long)(bm + ar) * K + k0 + ac4];
        As[ac4][ar] = av.x; As[ac4 + 1][ar] = av.y;
        As[ac4 + 2][ar] = av.z; As[ac4 + 3][ar] = av.w;
        *(float4*)&Bs[br][bc4] =
            *(const float4*)&Bm[(long long)(k0 + br) * N + bn + bc4];
        __syncthreads();
        #pragma unroll
        for (int kk = 0; kk < 16; ++kk) {
            float4 a4 = *(const float4*)&As[kk][tm];
            float4 b4 = *(const float4*)&Bs[kk][tn];
            acc[0][0] += a4.x * b4.x; acc[0][1] += a4.x * b4.y;
            acc[0][2] += a4.x * b4.z; acc[0][3] += a4.x * b4.w;
            acc[1][0] += a4.y * b4.x; acc[1][1] += a4.y * b4.y;
            acc[1][2] += a4.y * b4.z; acc[1][3] += a4.y * b4.w;
            acc[2][0] += a4.z * b4.x; acc[2][1] += a4.z * b4.y;
            acc[2][2] += a4.z * b4.z; acc[2][3] += a4.z * b4.w;
            acc[3][0] += a4.w * b4.x; acc[3][1] += a4.w * b4.y;
            acc[3][2] += a4.w * b4.z; acc[3][3] += a4.w * b4.w;
        }
        __syncthreads();
    }
    #pragma unroll
    for (int i = 0; i < 4; ++i) {
        int r = bm + tm + i;
        if (r < M) {
            float v[4];
            #pragma unroll
            for (int q = 0; q < 4; ++q) {
                v[q] = acc[i][q] + bias[bn + tn + q];
                if (EPI == 1) v[q] = mishf(v[q]);
            }
            float4 o; o.x = v[0]; o.y = v[1]; o.z = v[2]; o.w = v[3];
            int rr2 = (r / 400) * 402 + (r % 400) + 1;
            *(float4*)&C2[(long long)rr2 * 256 + bn + tn] = o;
            us4 ph, pl;
            #pragma unroll
            for (int q = 0; q < 4; ++q) {
                unsigned short hh = f2bf(v[q]);
                ph[q] = hh;
                pl[q] = f2bf(v[q] - bf2f(hh));
            }
            *(us4*)&fhi[(long long)r * ldc + bn + tn] = ph;
            *(us4*)&flo[(long long)r * ldc + bn + tn] = pl;
        }
    }
}

// ---------------------------------------------------------------------------
// MFMA bf16x3-split GEMM. B pre-transposed+split [N][K] bf16 hi/lo.
// AMODE: 0 = A fp32 (split per tile), 1 = A pre-split hi/lo (straight copy).
// SPLIT out: cols<nhl -> Chi/Clo [row][col]; cols>=1024 -> V transposed (416).
// EPI: 0 none, 1 mish, 2 relu.
// ---------------------------------------------------------------------------
template<int EPI, bool GATHER, int AMODE, bool SPLIT, int MT>
__global__ __launch_bounds__(256) void gemm_mfma(
    const float* __restrict__ A,
    const unsigned short* __restrict__ Ahi, const unsigned short* __restrict__ Alo,
    const unsigned short* __restrict__ Bth, const unsigned short* __restrict__ Btl,
    const float* __restrict__ bias, float* __restrict__ C,
    int M, int K, int lda, int ldc, const int* __restrict__ gidx,
    unsigned short* __restrict__ Chi, unsigned short* __restrict__ Clo,
    int ldhl, int nhl,
    unsigned short* __restrict__ vthi, unsigned short* __restrict__ vtlo,
    long long zA, int zB, int zBias, int zC, int zChi, int zVt)
{
    constexpr int AI = MT / 32;
    __shared__ unsigned short Ah[MT * 40];
    __shared__ unsigned short Al[MT * 40];
    __shared__ unsigned short Bh[128 * 40];
    __shared__ unsigned short Bl[128 * 40];

    long long zz = blockIdx.z;
    if (AMODE == 0) A += zz * zA;
    else { Ahi += zz * zA; Alo += zz * zA; }
    Bth  += zz * (long long)zB;  Btl += zz * (long long)zB;
    bias += zz * (long long)zBias;
    C    += zz * (long long)zC;
    if (SPLIT) {
        Chi += zz * (long long)zChi; Clo += zz * (long long)zChi;
        vthi += zz * (long long)zVt; vtlo += zz * (long long)zVt;
    }

    int bm = blockIdx.y * MT, bn = blockIdx.x << 7;
    int tid = threadIdx.x;
    int lane = tid & 63, wid = tid >> 6;
    int wm = wid >> 1, wn = wid & 1;
    int fr = lane & 15, kg = (lane >> 4) << 3;

    int ar = tid >> 2, akc = (tid & 3) << 3;
    int bnr = tid >> 1, bkc = (tid & 1) << 4;
    bool astage = ar < MT;

    long long arow = 0; bool avalid = false;
    if (astage) {
        int gr = bm + ar;
        avalid = gr < M;
        if (GATHER) arow = avalid ? (long long)gidx[gr] : 0;
        else        arow = avalid ? (long long)gr : 0;
    }

    f32x4 acc[AI][4] = {};

    for (int k0 = 0; k0 < K; k0 += 32) {
        if (astage) {
            if (AMODE == 0) {
                float vv[8];
                if (avalid) {
                    float4 v0 = *(const float4*)&A[arow * lda + k0 + akc];
                    float4 v1 = *(const float4*)&A[arow * lda + k0 + akc + 4];
                    vv[0] = v0.x; vv[1] = v0.y; vv[2] = v0.z; vv[3] = v0.w;
                    vv[4] = v1.x; vv[5] = v1.y; vv[6] = v1.z; vv[7] = v1.w;
                } else {
                    #pragma unroll
                    for (int e = 0; e < 8; ++e) vv[e] = 0.f;
                }
                union { unsigned short u[8]; u32x4 v; } ph, pl;
                #pragma unroll
                for (int e = 0; e < 8; ++e) {
                    unsigned short h = f2bf(vv[e]);
                    ph.u[e] = h;
                    pl.u[e] = f2bf(vv[e] - bf2f(h));
                }
                *(u32x4*)&Ah[ar * 40 + akc] = ph.v;
                *(u32x4*)&Al[ar * 40 + akc] = pl.v;
            } else {
                u32x4 zv = {0u, 0u, 0u, 0u};
                u32x4 vh = zv, vl = zv;
                if (avalid) {
                    vh = *(const u32x4*)&Ahi[arow * lda + k0 + akc];
                    vl = *(const u32x4*)&Alo[arow * lda + k0 + akc];
                }
                *(u32x4*)&Ah[ar * 40 + akc] = vh;
                *(u32x4*)&Al[ar * 40 + akc] = vl;
            }
        }
        {
            long long boff = (long long)(bn + bnr) * K + k0 + bkc;
            *(u32x4*)&Bh[bnr * 40 + bkc]     = *(const u32x4*)&Bth[boff];
            *(u32x4*)&Bh[bnr * 40 + bkc + 8] = *(const u32x4*)&Bth[boff + 8];
            *(u32x4*)&Bl[bnr * 40 + bkc]     = *(const u32x4*)&Btl[boff];
            *(u32x4*)&Bl[bnr * 40 + bkc + 8] = *(const u32x4*)&Btl[boff + 8];
        }
        __syncthreads();

        bf16x8 af[AI], alf[AI], bfj[4], blf[4];
        #pragma unroll
        for (int i = 0; i < AI; ++i) {
            int row = (MT == 64 ? wm * 32 + i * 16 : wm * 16) + fr;
            af[i]  = *(const bf16x8*)&Ah[row * 40 + kg];
            alf[i] = *(const bf16x8*)&Al[row * 40 + kg];
        }
        #pragma unroll
        for (int j = 0; j < 4; ++j) {
            int row = wn * 64 + j * 16 + fr;
            bfj[j] = *(const bf16x8*)&Bh[row * 40 + kg];
            blf[j] = *(const bf16x8*)&Bl[row * 40 + kg];
        }
        #pragma unroll
        for (int i = 0; i < AI; ++i)
        #pragma unroll
        for (int j = 0; j < 4; ++j) {
            acc[i][j] = __builtin_amdgcn_mfma_f32_16x16x32_bf16(af[i],  bfj[j], acc[i][j], 0, 0, 0);
            acc[i][j] = __builtin_amdgcn_mfma_f32_16x16x32_bf16(af[i],  blf[j], acc[i][j], 0, 0, 0);
            acc[i][j] = __builtin_amdgcn_mfma_f32_16x16x32_bf16(alf[i], bfj[j], acc[i][j], 0, 0, 0);
        }
        __syncthreads();
    }

    #pragma unroll
    for (int i = 0; i < AI; ++i) {
        int rbase = bm + (MT == 64 ? wm * 32 + i * 16 : wm * 16) + ((lane >> 4) << 2);
        #pragma unroll
        for (int j = 0; j < 4; ++j) {
            int ccol = bn + wn * 64 + j * 16 + fr;
            float bv = bias[ccol];
            #pragma unroll
            for (int r = 0; r < 4; ++r) {
                int row = rbase + r;
                if (row < M) {
                    float val = acc[i][j][r] + bv;
                    if (EPI == 1) val = mishf(val);
                    if (EPI == 2) val = fmaxf(val, 0.f);
                    if (SPLIT) {
                        unsigned short hh = f2bf(val);
                        unsigned short ll = f2bf(val - bf2f(hh));
                        if (ccol < nhl) {
                            Chi[(long long)row * ldhl + ccol] = hh;
                            Clo[(long long)row * ldhl + ccol] = ll;
                        } else {
                            int bb = row / 400, m = row - bb * 400;
                            long long vi = ((long long)(bb * 512 + (ccol - 1024))) * 416 + m;
                            vthi[vi] = hh;
                            vtlo[vi] = ll;
                        }
                    } else {
                        C[(long long)row * ldc + ccol] = val;
                    }
                }
            }
        }
    }
}

// ---------------------------------------------------------------------------
// Weight prep kernels (write-coalesced)
// ---------------------------------------------------------------------------
__global__ __launch_bounds__(256) void prep_wqkv(
    const float* __restrict__ wq, const float* __restrict__ wk,
    const float* __restrict__ wv,
    unsigned short* __restrict__ whi, unsigned short* __restrict__ wlo,
    int obase, int total)
{
    int idx = blockIdx.x * 256 + threadIdx.x;
    if (idx >= total) return;
    int o = obase + idx / 786432;
    int rem = idx % 786432;
    int n = rem >> 9, k = rem & 511;
    int sel = n >> 9, col = n & 511;
    const float* W = sel == 0 ? wq : (sel == 1 ? wk : wv);
    float v = W[(long long)o * 262144 + k * 512 + col];
    unsigned short h = f2bf(v);
    whi[idx] = h;
    wlo[idx] = f2bf(v - bf2f(h));
}

__global__ __launch_bounds__(256) void prep_woiw(
    const float* __restrict__ wo, const float* __restrict__ wi,
    const float* __restrict__ wout,
    unsigned short* __restrict__ whi, unsigned short* __restrict__ wlo,
    int obase, int total)
{
    int idx = blockIdx.x * 256 + threadIdx.x;
    if (idx >= total) return;
    int o = obase + idx / 655360;
    int rem = idx % 655360;
    float v;
    if (rem < 262144) {
        int n = rem >> 9, k = rem & 511;
        v = wo[(long long)o * 262144 + k * 512 + n];
    } else if (rem < 524288) {
        int nk = rem - 262144;
        int n = nk >> 9, k = nk & 511;
        v = wi[(long long)o * 262144 + k * 512 + n];
    } else {
        int nk = rem - 524288;
        int n = nk >> 9, k = nk & 511;   // n < 256
        v = wout[(long long)o * 131072 + k * 256 + n];
    }
    unsigned short h = f2bf(v);
    whi[idx] = h;
    wlo[idx] = f2bf(v - bf2f(h));
}

__global__ __launch_bounds__(256) void prep_wcnn(
    const float* __restrict__ w,
    unsigned short* __restrict__ whi, unsigned short* __restrict__ wlo)
{
    int idx = blockIdx.x * 256 + threadIdx.x;
    if (idx >= 256 * 768) return;
    int n = idx / 768, k = idx % 768;
    float v = w[k * 256 + n];
    unsigned short h = f2bf(v);
    whi[idx] = h;
    wlo[idx] = f2bf(v - bf2f(h));
}

// ---------------------------------------------------------------------------
// Fused setup
// ---------------------------------------------------------------------------
__global__ __launch_bounds__(256) void setup_kernel(
    const float* __restrict__ x,
    const float* __restrict__ bq, const float* __restrict__ bk,
    const float* __restrict__ bv,
    float* __restrict__ mk, int* __restrict__ relT, int* __restrict__ convidx,
    float* __restrict__ f1pad, float* __restrict__ bqkv,
    unsigned short* __restrict__ vt_hi, unsigned short* __restrict__ vt_lo,
    int nOrg)
{
    int i = blockIdx.x * 256 + threadIdx.x;
    if (i < 3200) {
        const float* xr = x + (long long)i * 128;
        mk[i] = xr[4];
        mk[3200 + i] = fmaxf(xr[2], xr[3]);
        mk[6400 + i] = xr[0];
        mk[9600 + i] = xr[1];
        convidx[i] = (i / 400) * 402 + (i % 400);
    }
    int j = i - 3200;
    if (j >= 0 && j < 799) {
        int rel = j - 399;
        int sgn = (rel > 0) - (rel < 0);
        int ab = (rel < 300 && rel > -300) ? 299 : (rel < 0 ? -rel : rel);
        long long bpos;
        if (ab <= 300) bpos = rel;
        else {
            double lp = ceil(log((double)ab / 300.0) / log(599.0 / 300.0) * 299.0) + 300.0;
            bpos = (long long)lp * sgn;
        }
        long long c2p = bpos + 600;
        c2p = c2p < 0 ? 0 : (c2p > 1199 ? 1199 : c2p);
        relT[j] = (int)c2p;
    }
    int k = i - 4000;
    if (k >= 0 && k < 4096) {
        int b = k >> 9, rem = k & 511;
        int row = b * 402 + (rem < 256 ? 0 : 401);
        f1pad[(long long)row * 256 + (rem & 255)] = 0.f;
    }
    int m = i - 8100;
    if (m >= 0 && m < 6144) {
        int o = m / 1536, n = m % 1536;
        float v;
        if (n < 512) v = bq[o * 512 + n];
        else if (n < 1024) v = bk[o * 512 + n - 512];
        else v = bv[o * 512 + n - 1024];
        bqkv[m] = v;
    }
    int v = i - 14244;
    if (v >= 0 && v < nOrg * 65536) {   // vt pad cols [400..416) zero, as u32
        int og = v >> 16, rem = v & 65535;
        int vb = rem & 32767;
        int row = vb >> 3, c = vb & 7;
        unsigned int* p = (unsigned int*)((rem < 32768) ? vt_hi : vt_lo);
        p[(long long)og * 851968 + row * 208 + 200 + c] = 0u;
    }
}

// ---------------------------------------------------------------------------
// LayerNorm, wave-per-row. Organ-batched (o = row/rpo). RES: split residual.
// OSPL: 1 -> write split hi/lo, 0 -> write f32.
// ---------------------------------------------------------------------------
template<bool RES, int HD, int OSPL>
__global__ __launch_bounds__(256) void ln2_kernel(
    const float* __restrict__ X,
    const unsigned short* __restrict__ Rhi, const unsigned short* __restrict__ Rlo,
    const float* __restrict__ g, const float* __restrict__ be,
    float* __restrict__ Y,
    unsigned short* __restrict__ Yhi, unsigned short* __restrict__ Ylo,
    int rows, int rpo)
{
    constexpr int EPL = HD / 64;
    int wv = threadIdx.x >> 6, lane = threadIdx.x & 63;
    long long row = (long long)blockIdx.x * 4 + wv;
    if (row >= rows) return;
    int o = (int)(row / rpo);
    long long rrow = row % rpo;
    const float* x = X + row * HD;
    float v[EPL];
    #pragma unroll
    for (int q = 0; q < EPL / 4; ++q) {
        float4 a = *(const float4*)&x[lane * EPL + q * 4];
        v[q*4+0] = a.x; v[q*4+1] = a.y; v[q*4+2] = a.z; v[q*4+3] = a.w;
        if (RES) {
            us4 rh = *(const us4*)&Rhi[rrow * HD + lane * EPL + q * 4];
            us4 rl = *(const us4*)&Rlo[rrow * HD + lane * EPL + q * 4];
            #pragma unroll
            for (int e = 0; e < 4; ++e) v[q*4+e] += bf2f(rh[e]) + bf2f(rl[e]);
        }
    }
    float s = 0.f;
    #pragma unroll
    for (int e = 0; e < EPL; ++e) s += v[e];
    #pragma unroll
    for (int d = 1; d < 64; d <<= 1) s += __shfl_xor(s, d, 64);
    float mean = s * (1.f / HD);
    float s2 = 0.f;
    #pragma unroll
    for (int e = 0; e < EPL; ++e) { float d0 = v[e] - mean; s2 += d0 * d0; }
    #pragma unroll
    for (int d = 1; d < 64; d <<= 1) s2 += __shfl_xor(s2, d, 64);
    float inv = 1.f / sqrtf(s2 * (1.f / HD) + 1e-7f);
    #pragma unroll
    for (int q = 0; q < EPL / 4; ++q) {
        int c = lane * EPL + q * 4;
        float4 gg = *(const float4*)&g[o * HD + c];
        float4 bb = *(const float4*)&be[o * HD + c];
        float ov[4];
        ov[0] = (v[q*4+0] - mean) * inv * gg.x + bb.x;
        ov[1] = (v[q*4+1] - mean) * inv * gg.y + bb.y;
        ov[2] = (v[q*4+2] - mean) * inv * gg.z + bb.z;
        ov[3] = (v[q*4+3] - mean) * inv * gg.w + bb.w;
        if (OSPL) {
            us4 ph, pl;
            #pragma unroll
            for (int e = 0; e < 4; ++e) {
                unsigned short hh = f2bf(ov[e]);
                ph[e] = hh;
                pl[e] = f2bf(ov[e] - bf2f(hh));
            }
            *(us4*)&Yhi[row * HD + c] = ph;
            *(us4*)&Ylo[row * HD + c] = pl;
        } else {
            float4 of; of.x = ov[0]; of.y = ov[1]; of.z = ov[2]; of.w = ov[3];
            *(float4*)&Y[row * HD + c] = of;
        }
    }
}

// ---------------------------------------------------------------------------
// MFMA fused disentangled flash attention (round 14): single-wave blocks
// (R11 config, best measured) with STRAIGHT-LINE CLAMPED LOADS — no
// divergent exec-mask toggles around tile loads. Clamping is provably safe:
// out-of-range K/mask columns are forced to -INF by jv before use, and any
// band LDS entry that is read has dd = l-m+399 in [0,798] (unclamped).
// Grid (25, 8, 8*nOrg), XCD-swizzled, zero barriers.
// ---------------------------------------------------------------------------
__global__ __launch_bounds__(64) void attn_kernel(
    const unsigned short* __restrict__ qk_hi, const unsigned short* __restrict__ qk_lo,
    const unsigned short* __restrict__ vt_hi, const unsigned short* __restrict__ vt_lo,
    const unsigned short* __restrict__ pkg_hi, const unsigned short* __restrict__ pkg_lo,
    const float* __restrict__ mask,
    unsigned short* __restrict__ ctxh, unsigned short* __restrict__ ctxl)
{
    const float scale = 0.07216878364870322f;       // 1/sqrt(64*3)
    const float NEGMIN = -3.402823466e38f;
    // --- XCD-aware bijective swizzle ---
    int lin = blockIdx.x + 25 * (blockIdx.y + 8 * blockIdx.z);
    int gz = gridDim.z;
    int xcd = lin & 7, within = lin >> 3;
    int g = within / 25, lt = within - g * 25;
    int combo = xcd * gz + g;
    int h = combo & 7, z = combo >> 3;
    int b = z & 7, o = z >> 3;
    qk_hi  += (long long)o * 3276800;
    qk_lo  += (long long)o * 3276800;
    vt_hi  += (long long)o * 1703936;
    vt_lo  += (long long)o * 1703936;
    pkg_hi += (long long)o * 818176;
    mask   += o * 3200;
    ctxh   += (long long)o * 1638400;
    ctxl   += (long long)o * 1638400;

    int l0 = lt * 16;                    // 25*16 = 400: q rows always valid
    int lane = threadIdx.x;
    int fr = lane & 15, kg8 = (lane >> 4) << 3, g4 = (lane >> 4) << 2;

    __shared__ float T2c[16 * 36];       // [i][d], d = 31 - j
    __shared__ float T3c[32 * 20];       // [j][i]
    __shared__ unsigned short Sth[16 * 40], Stl[16 * 40];

    // Q frag (A rows = l0 + fr), loaded once
    bf16x8 qfh[2], qfl[2];
    {
        long long base = ((long long)(b * 400 + l0 + fr)) * 1024 + h * 64 + kg8;
        #pragma unroll
        for (int kk = 0; kk < 2; ++kk) {
            qfh[kk] = *(const bf16x8*)(qk_hi + base + kk * 32);
            qfl[kk] = *(const bf16x8*)(qk_lo + base + kk * 32);
        }
    }
    float wlv_r[4], ms[4], ls[4];
    #pragma unroll
    for (int r = 0; r < 4; ++r) {
        wlv_r[r] = mask[b * 400 + l0 + g4 + r];
        ms[r] = -INFINITY;
        ls[r] = 0.f;
    }
    f32x4 O[4] = {};
    long long vtbase = ((long long)(b * 512 + h * 64)) * 416;

    for (int mt = 0; mt < 13; ++mt) {
        int m0 = mt * 32;
        int D0 = l0 - m0 + 368;
        // ---- straight-line clamped load batch: K hi/lo + pk + pq bands ----
        bf16x8 kfh[2][2], kfl[2][2];
        #pragma unroll
        for (int jf = 0; jf < 2; ++jf) {
            int kr = m0 + jf * 16 + fr;
            kr = kr < 400 ? kr : 399;                       // clamp; jv masks
            long long base = ((long long)(b * 400 + kr)) * 1024 + 512 + h * 64 + kg8;
            #pragma unroll
            for (int kk = 0; kk < 2; ++kk) {
                kfh[jf][kk] = *(const bf16x8*)(qk_hi + base + kk * 32);
                kfl[jf][kk] = *(const bf16x8*)(qk_lo + base + kk * 32);
            }
        }
        bf16x8 b2h[3][2], b3h[3][2];
        #pragma unroll
        for (int c = 0; c < 3; ++c) {
            int dd = D0 + c * 16 + fr;
            dd = dd < 0 ? 0 : (dd > 798 ? 798 : dd);        // clamp; unread
            long long base = (long long)dd * 1024 + h * 64 + kg8;
            #pragma unroll
            for (int kk = 0; kk < 2; ++kk) {
                b2h[c][kk] = *(const bf16x8*)(pkg_hi + base + 512 + kk * 32);
                b3h[c][kk] = *(const bf16x8*)(pkg_hi + base + kk * 32);
            }
        }
        // ---- T1 = Q@K^T (x3), T2 = Q@PKband^T (band hi-only) ----
        __builtin_amdgcn_s_setprio(1);
        f32x4 aT1[2] = {};
        #pragma unroll
        for (int jf = 0; jf < 2; ++jf)
        #pragma unroll
        for (int kk = 0; kk < 2; ++kk) {
            aT1[jf] = __builtin_amdgcn_mfma_f32_16x16x32_bf16(qfh[kk], kfh[jf][kk], aT1[jf], 0, 0, 0);
            aT1[jf] = __builtin_amdgcn_mfma_f32_16x16x32_bf16(qfh[kk], kfl[jf][kk], aT1[jf], 0, 0, 0);
            aT1[jf] = __builtin_amdgcn_mfma_f32_16x16x32_bf16(qfl[kk], kfh[jf][kk], aT1[jf], 0, 0, 0);
        }
        f32x4 aT2[3] = {};
        #pragma unroll
        for (int c = 0; c < 3; ++c)
        #pragma unroll
        for (int kk = 0; kk < 2; ++kk) {
            aT2[c] = __builtin_amdgcn_mfma_f32_16x16x32_bf16(qfh[kk], b2h[c][kk], aT2[c], 0, 0, 0);
            aT2[c] = __builtin_amdgcn_mfma_f32_16x16x32_bf16(qfl[kk], b2h[c][kk], aT2[c], 0, 0, 0);
        }
        __builtin_amdgcn_s_setprio(0);
        // ---- V loads issued here (latency hides under T3/softmax) ----
        bf16x8 vfh[4], vfl[4];
        #pragma unroll
        for (int f = 0; f < 4; ++f) {
            long long a = vtbase + (long long)(f * 16 + fr) * 416 + m0 + kg8;
            vfh[f] = *(const bf16x8*)&vt_hi[a];
            vfl[f] = *(const bf16x8*)&vt_lo[a];
        }
        float wm_c[2];
        #pragma unroll
        for (int cf = 0; cf < 2; ++cf) {
            int mg = m0 + cf * 16 + fr;
            mg = mg < 400 ? mg : 399;                       // clamp; jv masks
            wm_c[cf] = mask[b * 400 + mg];
        }
        // ---- T3 = K@PQband^T (band hi-only, 4 (jf,c) combos) ----
        __builtin_amdgcn_s_setprio(1);
        f32x4 aT3[2][2] = {};
        #pragma unroll
        for (int jf = 0; jf < 2; ++jf)
        #pragma unroll
        for (int ci = 0; ci < 2; ++ci) {
            int c = ci + (jf ^ 1);       // jf=0 -> c in {1,2}; jf=1 -> c in {0,1}
            #pragma unroll
            for (int kk = 0; kk < 2; ++kk) {
                aT3[jf][ci] = __builtin_amdgcn_mfma_f32_16x16x32_bf16(kfh[jf][kk], b3h[c][kk], aT3[jf][ci], 0, 0, 0);
                aT3[jf][ci] = __builtin_amdgcn_mfma_f32_16x16x32_bf16(kfl[jf][kk], b3h[c][kk], aT3[jf][ci], 0, 0, 0);
            }
        }
        __builtin_amdgcn_s_setprio(0);
        // ---- banded scatter (in-wave LDS ordering, no barrier) ----
        #pragma unroll
        for (int c = 0; c < 3; ++c)
        #pragma unroll
        for (int r = 0; r < 4; ++r) {
            int i = g4 + r;
            int d = c * 16 + fr - i;
            if ((unsigned)d < 32u)
                T2c[i * 36 + d] = aT2[c][r];
        }
        #pragma unroll
        for (int jf = 0; jf < 2; ++jf)
        #pragma unroll
        for (int ci = 0; ci < 2; ++ci) {
            int c = ci + (jf ^ 1);
            #pragma unroll
            for (int r = 0; r < 4; ++r) {
                int j3 = jf * 16 + g4 + r;
                int d2 = c * 16 + fr + j3 - 31;
                if ((unsigned)d2 < 16u)
                    T3c[j3 * 20 + d2] = aT3[jf][ci][r];
            }
        }
        // ---- assemble scores ----
        float sc0[4], sc1[4];
        #pragma unroll
        for (int r = 0; r < 4; ++r) {
            int i = g4 + r;
            {
                int j = fr;
                bool jv = (m0 + j) < 400;
                sc0[r] = !jv ? -INFINITY :
                    ((wlv_r[r] != 0.f && wm_c[0] != 0.f) ?
                     (aT1[0][r] + T2c[i * 36 + 31 - j] + T3c[j * 20 + i]) * scale : NEGMIN);
            }
            {
                int j = 16 + fr;
                bool jv = (m0 + j) < 400;
                sc1[r] = !jv ? -INFINITY :
                    ((wlv_r[r] != 0.f && wm_c[1] != 0.f) ?
                     (aT1[1][r] + T2c[i * 36 + 31 - j] + T3c[j * 20 + i]) * scale : NEGMIN);
            }
        }
        // ---- wave-local flash softmax ----
        float corr[4];
        #pragma unroll
        for (int r = 0; r < 4; ++r) {
            float mx = fmaxf(sc0[r], sc1[r]);
            #pragma unroll
            for (int d = 1; d < 16; d <<= 1) mx = fmaxf(mx, __shfl_xor(mx, d, 64));
            float mn = fmaxf(ms[r], mx);
            corr[r] = __expf(ms[r] - mn);
            ms[r] = mn;
            float p0 = __expf(sc0[r] - mn), p1 = __expf(sc1[r] - mn);
            float rs = p0 + p1;
            #pragma unroll
            for (int d = 1; d < 16; d <<= 1) rs += __shfl_xor(rs, d, 64);
            ls[r] = ls[r] * corr[r] + rs;
            int i = g4 + r;
            unsigned short h0 = f2bf(p0);
            Sth[i * 40 + fr] = h0;
            Stl[i * 40 + fr] = f2bf(p0 - bf2f(h0));
            unsigned short h1 = f2bf(p1);
            Sth[i * 40 + 16 + fr] = h1;
            Stl[i * 40 + 16 + fr] = f2bf(p1 - bf2f(h1));
        }
        // ---- PV (P transposed via in-wave LDS) ----
        #pragma unroll
        for (int f = 0; f < 4; ++f)
        #pragma unroll
        for (int r = 0; r < 4; ++r) O[f][r] *= corr[r];
        bf16x8 Pha = *(const bf16x8*)&Sth[fr * 40 + kg8];
        bf16x8 Pla = *(const bf16x8*)&Stl[fr * 40 + kg8];
        __builtin_amdgcn_s_setprio(1);
        #pragma unroll
        for (int f = 0; f < 4; ++f) {
            O[f] = __builtin_amdgcn_mfma_f32_16x16x32_bf16(Pha, vfh[f], O[f], 0, 0, 0);
            O[f] = __builtin_amdgcn_mfma_f32_16x16x32_bf16(Pha, vfl[f], O[f], 0, 0, 0);
            O[f] = __builtin_amdgcn_mfma_f32_16x16x32_bf16(Pla, vfh[f], O[f], 0, 0, 0);
        }
        __builtin_amdgcn_s_setprio(0);
    }
    // ---- write ctx (split bf16 hi/lo); rows always valid ----
    #pragma unroll
    for (int f = 0; f < 4; ++f) {
        int colg = h * 64 + f * 16 + fr;
        #pragma unroll
        for (int r = 0; r < 4; ++r) {
            int lg = l0 + g4 + r;
            float val = O[f][r] / ls[r];
            long long idx = ((long long)(b * 400 + lg)) * 512 + colg;
            unsigned short hh = f2bf(val);
            ctxh[idx] = hh;
            ctxl[idx] = f2bf(val - bf2f(hh));
        }
    }
}

// ---------------------------------------------------------------------------
// Chunked pool / meanmax (full-chip), heads
// ---------------------------------------------------------------------------
__global__ __launch_bounds__(256) void pool_part(
    const float* __restrict__ in, long long inOStride,
    const float* __restrict__ mk, float* __restrict__ pp)
{
    int bi = blockIdx.x, c = blockIdx.y, t = threadIdx.x;
    int o = bi >> 3, b = bi & 7;
    int l0 = c * 31, l1 = min(400, l0 + 31);
    const float* ib = in + (long long)o * inOStride + (long long)(b * 400) * 256;
    const float* mkb = mk + o * 3200 + b * 400;
    float s = 0.f, mx = -INFINITY, sw = 0.f;
    for (int l = l0; l < l1; ++l) {
        float wv = mkb[l];
        float v = ib[(long long)l * 256 + t] * wv;
        s += v; mx = fmaxf(mx, v); sw += wv;
    }
    long long base = (long long)(c * gridDim.x + bi) * 514;
    pp[base + t] = s;
    pp[base + 256 + t] = mx;
    if (t == 0) pp[base + 512] = sw;
}

__global__ __launch_bounds__(256) void pool_merge(
    const float* __restrict__ pp, float* __restrict__ pooled, int nBI)
{
    int bi = blockIdx.x, t = threadIdx.x;
    float s = 0.f, mx = -INFINITY, sw = 0.f;
    for (int c = 0; c < 13; ++c) {
        long long base = (long long)(c * nBI + bi) * 514;
        s += pp[base + t];
        mx = fmaxf(mx, pp[base + 256 + t]);
        sw += pp[base + 512];
    }
    int o = bi >> 3, b = bi & 7;
    pooled[o * 4096 + b * 512 + t] = s / (sw + 1e-6f);
    pooled[o * 4096 + b * 512 + 256 + t] = mx;
}

__global__ __launch_bounds__(512) void mm_part(
    const unsigned short* __restrict__ fh, const unsigned short* __restrict__ fl,
    float* __restrict__ mmp)
{
    int b = blockIdx.x, c = blockIdx.y, t = threadIdx.x;
    int l0 = c * 31, l1 = min(400, l0 + 31);
    float s = 0.f, mx = -INFINITY;
    for (int l = l0; l < l1; ++l) {
        long long idx = ((long long)(b * 400 + l)) * 512 + t;
        float v = bf2f(fh[idx]) + bf2f(fl[idx]);
        s += v; mx = fmaxf(mx, v);
    }
    long long base = (long long)(c * 8 + b) * 1024;
    mmp[base + t] = s;
    mmp[base + 512 + t] = mx;
}

__global__ __launch_bounds__(512) void mm_merge(
    const float* __restrict__ mmp, float* __restrict__ mm)
{
    int b = blockIdx.x, t = threadIdx.x;
    float s = 0.f, mx = -INFINITY;
    for (int c = 0; c < 13; ++c) {
        long long base = (long long)(c * 8 + b) * 1024;
        s += mmp[base + t];
        mx = fmaxf(mx, mmp[base + 512 + t]);
    }
    mm[b * 1024 + t] = s / 400.f;
    mm[b * 1024 + 512 + t] = mx;
}

__global__ __launch_bounds__(256) void heads_kernel(
    const float* __restrict__ pooled, const float* __restrict__ mm,
    const float* __restrict__ w_bow1, const float* __restrict__ b_bow1,
    const float* __restrict__ w_bow2, const float* __restrict__ b_bow2,
    const float* __restrict__ w_ext1, const float* __restrict__ b_ext1,
    const float* __restrict__ w_ext2, const float* __restrict__ b_ext2,
    const float* __restrict__ w_org1, const float* __restrict__ b_org1,
    const float* __restrict__ w_org2, const float* __restrict__ b_org2,
    float* __restrict__ out)
{
    int b = blockIdx.x, role = blockIdx.y;
    int t = threadIdx.x;
    __shared__ float inb[1024];
    __shared__ float red[256];
    __shared__ float hid[256];
    if (role == 0) {
        inb[t] = pooled[b * 512 + t];
        inb[256 + t] = pooled[b * 512 + 256 + t];
        __syncthreads();
        float acc = b_bow1[t];
        for (int j = 0; j < 512; ++j) acc += inb[j] * w_bow1[j * 256 + t];
        red[t] = mishf(acc) * w_bow2[t];
        __syncthreads();
        for (int s = 128; s; s >>= 1) { if (t < s) red[t] += red[t + s]; __syncthreads(); }
        if (t == 0) out[b * 11 + 0] = red[0] + b_bow2[0];
    } else if (role == 1) {
        inb[t] = mm[b * 1024 + t];
        inb[256 + t] = mm[b * 1024 + 256 + t];
        inb[512 + t] = mm[b * 1024 + 512 + t];
        inb[768 + t] = mm[b * 1024 + 768 + t];
        __syncthreads();
        float acc = b_ext1[t];
        for (int j = 0; j < 1024; ++j) acc += inb[j] * w_ext1[j * 256 + t];
        red[t] = mishf(acc) * w_ext2[t];
        __syncthreads();
        for (int s = 128; s; s >>= 1) { if (t < s) red[t] += red[t + s]; __syncthreads(); }
        if (t == 0) { out[b * 11 + 1] = red[0] + b_ext2[0]; out[88 + b] = 0.f; }
    } else {
        int i = role - 2;
        inb[t] = pooled[((1 + i) * 8 + b) * 512 + t];
        inb[256 + t] = pooled[((1 + i) * 8 + b) * 512 + 256 + t];
        __syncthreads();
        float acc = b_org1[i * 256 + t];
        for (int j = 0; j < 512; ++j)
            acc += inb[j] * w_org1[((long long)i * 512 + j) * 256 + t];
        hid[t] = mishf(acc);
        __syncthreads();
        for (int c = 0; c < 3; ++c) {
            red[t] = hid[t] * w_org2[(i * 256 + t) * 3 + c];
            __syncthreads();
            for (int s = 128; s; s >>= 1) { if (t < s) red[t] += red[t + s]; __syncthreads(); }
            if (t == 0) out[b * 11 + 2 + i * 3 + c] = red[0] + b_org2[i * 3 + c];
            __syncthreads();
        }
    }
}

// ---------------------------------------------------------------------------
// Launch
// ---------------------------------------------------------------------------
extern "C" void kernel_launch(void* const* d_in, const int* in_sizes, int n_in,
                              void* d_out, int out_size, void* d_ws, size_t ws_size,
                              hipStream_t stream)
{
    const float* x      = (const float*)d_in[0];
    const float* w_mlp  = (const float*)d_in[1];
    const float* b_mlp  = (const float*)d_in[2];
    const float* w_cnn  = (const float*)d_in[3];
    const float* b_cnn  = (const float*)d_in[4];
    const float* rel_emb= (const float*)d_in[5];
    const float* rel_g  = (const float*)d_in[6];
    const float* rel_b  = (const float*)d_in[7];
    const float* wq     = (const float*)d_in[8];
    const float* wk     = (const float*)d_in[9];
    const float* wv     = (const float*)d_in[10];
    const float* wo     = (const float*)d_in[11];
    const float* wi     = (const float*)d_in[12];
    const float* bq     = (const float*)d_in[13];
    const float* bk     = (const float*)d_in[14];
    const float* bv     = (const float*)d_in[15];
    const float* bo     = (const float*)d_in[16];
    const float* bi     = (const float*)d_in[17];
    const float* wout   = (const float*)d_in[18];
    const float* bout   = (const float*)d_in[19];
    const float* ln1g   = (const float*)d_in[20];
    const float* ln1b   = (const float*)d_in[21];
    const float* ln2g   = (const float*)d_in[22];
    const float* ln2b   = (const float*)d_in[23];
    const float* w_bow1 = (const float*)d_in[24];
    const float* b_bow1 = (const float*)d_in[25];
    const float* w_bow2 = (const float*)d_in[26];
    const float* b_bow2 = (const float*)d_in[27];
    const float* w_ext1 = (const float*)d_in[28];
    const float* b_ext1 = (const float*)d_in[29];
    const float* w_ext2 = (const float*)d_in[30];
    const float* b_ext2 = (const float*)d_in[31];
    const float* w_org1 = (const float*)d_in[32];
    const float* b_org1 = (const float*)d_in[33];
    const float* w_org2 = (const float*)d_in[34];
    const float* b_org2 = (const float*)d_in[35];

    float* ws = (float*)d_ws;
    float* outf = (float*)d_out;
    const bool big = ws_size >= 143012736ull;

    if (big) {
        // ---------------- organ-batched path ----------------
        unsigned short* featsh = (unsigned short*)(ws + 0);        // 3200x512
        unsigned short* featsl = (unsigned short*)(ws + 819200);
        float* ctxR     = ws + 1638400;      // 6,553,600 fl
        float* f1pad    = ctxR;
        unsigned short* ctxh = (unsigned short*)ctxR;              // 4x3200x512
        unsigned short* ctxl = (unsigned short*)(ws + 4915200);
        float* qkA_f    = ws + 8192000;
        float* qkB_f    = ws + 14745600;
        unsigned short* qkA = (unsigned short*)qkA_f;
        unsigned short* qkB = (unsigned short*)qkB_f;
        unsigned short* rellnh = (unsigned short*)qkA_f;           // 4800x512
        unsigned short* rellnl = (unsigned short*)(ws + 8192000 + 1228800);
        unsigned short* vtA = (unsigned short*)(ws + 21299200);    // 4x4096x416
        unsigned short* vtB = (unsigned short*)(ws + 24707072);
        unsigned short* pkgA = (unsigned short*)(ws + 28114944);   // 4x799x1024
        unsigned short* pkgB = (unsigned short*)(ws + 29751296);
        unsigned short* whiA = (unsigned short*)(ws + 31387648);   // 4x786,432
        unsigned short* wloA = (unsigned short*)(ws + 32960512);
        unsigned short* wcnn_hi = (unsigned short*)(ws + 35188736);
        unsigned short* wcnn_lo = (unsigned short*)(ws + 35287040);
        float* bqkvb   = ws + 35385344;
        float* masksb  = ws + 35391488;
        float* pooledb = ws + 35404288;
        float* mmb     = ws + 35420672;
        int*   relidx  = (int*)(ws + 35428864);
        int*   convidx = (int*)(ws + 35429664);
        float* poolpart= ws + 35432864;
        float* mmpart  = ws + 35646688;
        float* tmp_all   = qkA_f;                                  // WO out (f32)
        unsigned short* h1h = (unsigned short*)qkB_f;              // LN1 out split
        unsigned short* h1l = (unsigned short*)(ws + 14745600 + 3276800);
        unsigned short* interh = (unsigned short*)qkA_f;           // WI out split
        unsigned short* interl = (unsigned short*)(ws + 8192000 + 3276800);
        float* outenc_all = (float*)vtA;                           // 4x819,200 f32
        float* outln_all  = ctxR;                                  // 4x819,200 f32
        unsigned short* whiB_all = whiA;
        unsigned short* wloB_all = wloA;

        gemm_bias<1><<<dim3(4, 50), 256, 0, stream>>>(
            x, w_mlp, b_mlp, f1pad, featsh, featsl, 3200, 256, 128, 512);
        setup_kernel<<<1080, 256, 0, stream>>>(x, bq, bk, bv, masksb, relidx, convidx,
                                               f1pad, bqkvb, vtA, vtB, 4);
        prep_wcnn<<<768, 256, 0, stream>>>(w_cnn, wcnn_hi, wcnn_lo);
        gemm_mfma<2, true, 0, true, 32><<<dim3(2, 100), 256, 0, stream>>>(
            f1pad, nullptr, nullptr, wcnn_hi, wcnn_lo, b_cnn, nullptr,
            3200, 768, 256, 0, convidx, featsh + 256, featsl + 256, 512, 1 << 30,
            nullptr, nullptr, 0, 0, 0, 0, 0, 0);

        ln2_kernel<false, 512, 1><<<1200, 256, 0, stream>>>(
            rel_emb, nullptr, nullptr, rel_g, rel_b, nullptr, rellnh, rellnl, 4800, 1200);
        prep_wqkv<<<12288, 256, 0, stream>>>(wq, wk, wv, whiA, wloA, 0, 3145728);
        gemm_mfma<0, true, 1, true, 64><<<dim3(8, 13, 4), 256, 0, stream>>>(
            nullptr, rellnh, rellnl, whiA, wloA, bqkvb, nullptr, 799, 512, 512, 0, relidx,
            pkgA, pkgB, 1024, 1024, nullptr, nullptr,
            614400, 786432, 1536, 0, 818176, 0);
        gemm_mfma<0, false, 1, true, 64><<<dim3(12, 50, 4), 256, 0, stream>>>(
            nullptr, featsh, featsl, whiA, wloA, bqkvb, nullptr, 3200, 512, 512, 0, nullptr,
            qkA, qkB, 1024, 1024, vtA, vtB,
            0, 786432, 1536, 0, 3276800, 1703936);
        prep_woiw<<<10240, 256, 0, stream>>>(wo, wi, wout, whiB_all, wloB_all,
                                             0, 2621440);
        // attention: single-wave blocks, all 4 organs, XCD-swizzled
        attn_kernel<<<dim3(25, 8, 32), 64, 0, stream>>>(qkA, qkB, vtA, vtB,
            pkgA, pkgB, masksb, ctxh, ctxl);
        gemm_mfma<0, false, 1, false, 32><<<dim3(4, 100, 4), 256, 0, stream>>>(
            nullptr, ctxh, ctxl, whiB_all, wloB_all, bo, tmp_all,
            3200, 512, 512, 512, nullptr, nullptr, nullptr, 0, 0, nullptr, nullptr,
            1638400, 655360, 512, 1638400, 0, 0);
        ln2_kernel<true, 512, 1><<<3200, 256, 0, stream>>>(
            tmp_all, featsh, featsl, ln1g, ln1b, nullptr, h1h, h1l, 12800, 3200);
        gemm_mfma<1, false, 1, true, 32><<<dim3(4, 100, 4), 256, 0, stream>>>(
            nullptr, h1h, h1l, whiB_all + 262144, wloB_all + 262144, bi, nullptr,
            3200, 512, 512, 0, nullptr, interh, interl, 512, 1 << 30, nullptr, nullptr,
            1638400, 655360, 512, 0, 1638400, 0);
        gemm_mfma<0, false, 1, false, 32><<<dim3(2, 100, 4), 256, 0, stream>>>(
            nullptr, interh, interl, whiB_all + 524288, wloB_all + 524288, bout, outenc_all,
            3200, 512, 512, 256, nullptr, nullptr, nullptr, 0, 0, nullptr, nullptr,
            1638400, 655360, 256, 819200, 0, 0);
        ln2_kernel<false, 256, 0><<<3200, 256, 0, stream>>>(
            outenc_all, nullptr, nullptr, ln2g, ln2b, outln_all, nullptr, nullptr,
            12800, 3200);

        pool_part<<<dim3(32, 13), 256, 0, stream>>>(outln_all, 819200, masksb, poolpart);
        pool_merge<<<32, 256, 0, stream>>>(poolpart, pooledb, 32);
        mm_part<<<dim3(8, 13), 512, 0, stream>>>(featsh, featsl, mmpart);
        mm_merge<<<8, 512, 0, stream>>>(mmpart, mmb);
        heads_kernel<<<dim3(8, 5), 256, 0, stream>>>(pooledb, mmb,
            w_bow1, b_bow1, w_bow2, b_bow2, w_ext1, b_ext1, w_ext2, b_ext2,
            w_org1, b_org1, w_org2, b_org2, outf);
        return;
    }

    // ---------------- per-organ fallback path ----------------
    unsigned short* featsh = (unsigned short*)(ws + 0);
    unsigned short* featsl = (unsigned short*)(ws + 819200);
    float* ctxR    = ws + 1638400;
    float* f1pad   = ctxR;
    unsigned short* ctxh = (unsigned short*)ctxR;
    unsigned short* ctxl = (unsigned short*)(ws + 1638400 + 819200);
    float* qkvA_f  = ws + 3276800;
    float* qkvB_f  = ws + 4915200;
    unsigned short* qkv_hi = (unsigned short*)qkvA_f;
    unsigned short* qkv_lo = (unsigned short*)qkvB_f;
    unsigned short* rellnh = (unsigned short*)qkvB_f;
    unsigned short* rellnl = (unsigned short*)(ws + 4915200 + 307200);
    unsigned short* pkg_hi = (unsigned short*)(ws + 6553600);
    unsigned short* pkg_lo = (unsigned short*)(ws + 6963200);
    unsigned short* vt_hi  = (unsigned short*)(ws + 7372800);
    unsigned short* vt_lo  = (unsigned short*)(ws + 8224768);
    unsigned short* whi    = (unsigned short*)(ws + 9076736);
    unsigned short* wlo    = (unsigned short*)(ws + 9469952);
    float* bqkvb   = ws + 9863168;
    float* masksb  = ws + 9869312;
    float* pooledb = ws + 9882112;
    float* mmb     = ws + 9898496;
    int*   relidx  = (int*)(ws + 9906688);
    unsigned short* wcnn_hi = (unsigned short*)(ws + 9907488);
    unsigned short* wcnn_lo = (unsigned short*)(ws + 10005792);
    int*   convidx = (int*)(ws + 10104096);
    float* poolpart= ws + 10107296;
    float* mmpart  = ws + 10160752;
    float* tmp     = qkvA_f;
    unsigned short* h1h = (unsigned short*)qkvB_f;
    unsigned short* h1l = (unsigned short*)(ws + 4915200 + 819200);
    unsigned short* interh = (unsigned short*)qkvA_f;
    unsigned short* interl = (unsigned short*)(ws + 3276800 + 819200);
    float* outenc  = (float*)vt_hi;
    float* outln   = ctxR;

    gemm_bias<1><<<dim3(4, 50), 256, 0, stream>>>(
        x, w_mlp, b_mlp, f1pad, featsh, featsl, 3200, 256, 128, 512);
    setup_kernel<<<312, 256, 0, stream>>>(x, bq, bk, bv, masksb, relidx, convidx,
                                          f1pad, bqkvb, vt_hi, vt_lo, 1);
    prep_wcnn<<<768, 256, 0, stream>>>(w_cnn, wcnn_hi, wcnn_lo);
    gemm_mfma<2, true, 0, true, 32><<<dim3(2, 100), 256, 0, stream>>>(
        f1pad, nullptr, nullptr, wcnn_hi, wcnn_lo, b_cnn, nullptr,
        3200, 768, 256, 0, convidx, featsh + 256, featsl + 256, 512, 1 << 30,
        nullptr, nullptr, 0, 0, 0, 0, 0, 0);

    for (int o = 0; o < 4; ++o) {
        ln2_kernel<false, 512, 1><<<300, 256, 0, stream>>>(
            rel_emb + (long long)o * 614400, nullptr, nullptr,
            rel_g + o * 512, rel_b + o * 512, nullptr, rellnh, rellnl, 1200, 1200);
        prep_wqkv<<<3072, 256, 0, stream>>>(wq, wk, wv, whi, wlo, o, 786432);
        gemm_mfma<0, true, 1, true, 64><<<dim3(8, 13), 256, 0, stream>>>(
            nullptr, rellnh, rellnl, whi, wlo, bqkvb + o * 1536, nullptr,
            799, 512, 512, 0, relidx, pkg_hi, pkg_lo, 1024, 1024, nullptr, nullptr,
            0, 0, 0, 0, 0, 0);
        gemm_mfma<0, false, 1, true, 64><<<dim3(12, 50), 256, 0, stream>>>(
            nullptr, featsh, featsl, whi, wlo, bqkvb + o * 1536, nullptr,
            3200, 512, 512, 0, nullptr, qkv_hi, qkv_lo, 1024, 1024, vt_hi, vt_lo,
            0, 0, 0, 0, 0, 0);
        prep_woiw<<<2560, 256, 0, stream>>>(wo, wi, wout, whi, wlo, o, 655360);
        attn_kernel<<<dim3(25, 8, 8), 64, 0, stream>>>(qkv_hi, qkv_lo, vt_hi, vt_lo,
            pkg_hi, pkg_lo, masksb + o * 3200, ctxh, ctxl);
        gemm_mfma<0, false, 1, false, 32><<<dim3(4, 100), 256, 0, stream>>>(
            nullptr, ctxh, ctxl, whi, wlo, bo + o * 512, tmp,
            3200, 512, 512, 512, nullptr, nullptr, nullptr, 0, 0, nullptr, nullptr,
            0, 0, 0, 0, 0, 0);
        ln2_kernel<true, 512, 1><<<800, 256, 0, stream>>>(
            tmp, featsh, featsl, ln1g + o * 512, ln1b + o * 512, nullptr,
            h1h, h1l, 3200, 3200);
        gemm_mfma<1, false, 1, true, 32><<<dim3(4, 100), 256, 0, stream>>>(
            nullptr, h1h, h1l, whi + 262144, wlo + 262144, bi + o * 512, nullptr,
            3200, 512, 512, 0, nullptr, interh, interl, 512, 1 << 30, nullptr, nullptr,
            0, 0, 0, 0, 0, 0);
        gemm_mfma<0, false, 1, false, 32><<<dim3(2, 100), 256, 0, stream>>>(
            nullptr, interh, interl, whi + 524288, wlo + 524288, bout + o * 256, outenc,
            3200, 512, 512, 256, nullptr, nullptr, nullptr, 0, 0, nullptr, nullptr,
            0, 0, 0, 0, 0, 0);
        ln2_kernel<false, 256, 0><<<800, 256, 0, stream>>>(
            outenc, nullptr, nullptr, ln2g + o * 256, ln2b + o * 256, outln,
            nullptr, nullptr, 3200, 3200);
        pool_part<<<dim3(8, 13), 256, 0, stream>>>(outln, 0,
                                                   masksb + o * 3200, poolpart);
        pool_merge<<<8, 256, 0, stream>>>(poolpart, pooledb + o * 4096, 8);
    }

    mm_part<<<dim3(8, 13), 512, 0, stream>>>(featsh, featsl, mmpart);
    mm_merge<<<8, 512, 0, stream>>>(mmpart, mmb);
    heads_kernel<<<dim3(8, 5), 256, 0, stream>>>(pooledb, mmb,
        w_bow1, b_bow1, w_bow2, b_bow2, w_ext1, b_ext1, w_ext2, b_ext2,
        w_org1, b_org1, w_org2, b_org2, outf);
}

// Round 15
// 681.753 us; speedup vs baseline: 1.0607x; 1.0359x over previous
//
#include <hip/hip_runtime.h>
#include <math.h>

// ---------------------------------------------------------------------------
// Model dims (fixed): B=8 L=400 F=128 D=256 T=256 H=512 NH=8 HD=64 P=1200
// ---------------------------------------------------------------------------

typedef __attribute__((ext_vector_type(8))) short bf16x8;
typedef __attribute__((ext_vector_type(4))) float f32x4;
typedef __attribute__((ext_vector_type(4))) unsigned int u32x4;
typedef __attribute__((ext_vector_type(4))) unsigned short us4;

__device__ __forceinline__ float mishf(float x) {
    float sp = fmaxf(x, 0.f) + log1pf(expf(-fabsf(x)));   // stable softplus
    return x * tanhf(sp);
}

__device__ __forceinline__ unsigned short f2bf(float f) {
    unsigned int u = __float_as_uint(f);
    u = (u + 0x7fffu + ((u >> 16) & 1u)) >> 16;           // RNE
    return (unsigned short)u;
}
__device__ __forceinline__ float bf2f(unsigned short h) {
    return __uint_as_float(((unsigned int)h) << 16);
}

// async global->LDS 16B per lane; dst is wave-uniform base (+ lane*16 in HW)
__device__ __forceinline__ void gll16(const unsigned short* g, unsigned short* l) {
    __builtin_amdgcn_global_load_lds(
        (const __attribute__((address_space(1))) void*)g,
        (__attribute__((address_space(3))) void*)l, 16, 0, 0);
}

// ---------------------------------------------------------------------------
// fp32 GEMM (front MLP, K=128): writes f1pad (padded conv layout) + split
// bf16 hi/lo feats (cols 0..255 of 512-wide).
// ---------------------------------------------------------------------------
template<int EPI>
__global__ __launch_bounds__(256) void gemm_bias(
    const float* __restrict__ A, const float* __restrict__ Bm,
    const float* __restrict__ bias, float* __restrict__ C2,
    unsigned short* __restrict__ fhi, unsigned short* __restrict__ flo,
    int M, int N, int K, int ldc)
{
    __shared__ float As[16][68];
    __shared__ float Bs[16][68];
    int bm = blockIdx.y << 6, bn = blockIdx.x << 6;
    int tid = threadIdx.x;
    int tm = (tid >> 4) << 2, tn = (tid & 15) << 2;
    int ar = tid >> 2, ac4 = (tid & 3) << 2;
    int br = tid >> 4, bc4 = (tid & 15) << 2;
    float acc[4][4] = {};
    for (int k0 = 0; k0 < K; k0 += 16) {
        float4 av = make_float4(0.f, 0.f, 0.f, 0.f);
        if (bm + ar < M)
            av = *(const float4*)&A[(long long)(bm + ar) * K + k0 + ac4];
        As[ac4][ar] = av.x; As[ac4 + 1][ar] = av.y;
        As[ac4 + 2][ar] = av.z; As[ac4 + 3][ar] = av.w;
        *(float4*)&Bs[br][bc4] =
            *(const float4*)&Bm[(long long)(k0 + br) * N + bn + bc4];
        __syncthreads();
        #pragma unroll
        for (int kk = 0; kk < 16; ++kk) {
            float4 a4 = *(const float4*)&As[kk][tm];
            float4 b4 = *(const float4*)&Bs[kk][tn];
            acc[0][0] += a4.x * b4.x; acc[0][1] += a4.x * b4.y;
            acc[0][2] += a4.x * b4.z; acc[0][3] += a4.x * b4.w;
            acc[1][0] += a4.y * b4.x; acc[1][1] += a4.y * b4.y;
            acc[1][2] += a4.y * b4.z; acc[1][3] += a4.y * b4.w;
            acc[2][0] += a4.z * b4.x; acc[2][1] += a4.z * b4.y;
            acc[2][2] += a4.z * b4.z; acc[2][3] += a4.z * b4.w;
            acc[3][0] += a4.w * b4.x; acc[3][1] += a4.w * b4.y;
            acc[3][2] += a4.w * b4.z; acc[3][3] += a4.w * b4.w;
        }
        __syncthreads();
    }
    #pragma unroll
    for (int i = 0; i < 4; ++i) {
        int r = bm + tm + i;
        if (r < M) {
            float v[4];
            #pragma unroll
            for (int q = 0; q < 4; ++q) {
                v[q] = acc[i][q] + bias[bn + tn + q];
                if (EPI == 1) v[q] = mishf(v[q]);
            }
            float4 o; o.x = v[0]; o.y = v[1]; o.z = v[2]; o.w = v[3];
            int rr2 = (r / 400) * 402 + (r % 400) + 1;
            *(float4*)&C2[(long long)rr2 * 256 + bn + tn] = o;
            us4 ph, pl;
            #pragma unroll
            for (int q = 0; q < 4; ++q) {
                unsigned short hh = f2bf(v[q]);
                ph[q] = hh;
                pl[q] = f2bf(v[q] - bf2f(hh));
            }
            *(us4*)&fhi[(long long)r * ldc + bn + tn] = ph;
            *(us4*)&flo[(long long)r * ldc + bn + tn] = pl;
        }
    }
}

// ---------------------------------------------------------------------------
// MFMA bf16x3-split GEMM. B pre-transposed+split [N][K] bf16 hi/lo.
// AMODE: 0 = A fp32 (split per tile), 1 = A pre-split hi/lo.
// GLL: stage A/B via global_load_lds (async, unpadded stride-32 LDS);
//      requires AMODE==1. OOB A-rows are index-clamped (outputs guarded).
// SPLIT out: cols<nhl -> Chi/Clo [row][col]; cols>=1024 -> V transposed (416).
// EPI: 0 none, 1 mish, 2 relu.
// ---------------------------------------------------------------------------
template<int EPI, bool GATHER, int AMODE, bool SPLIT, int MT, bool GLL>
__global__ __launch_bounds__(256) void gemm_mfma(
    const float* __restrict__ A,
    const unsigned short* __restrict__ Ahi, const unsigned short* __restrict__ Alo,
    const unsigned short* __restrict__ Bth, const unsigned short* __restrict__ Btl,
    const float* __restrict__ bias, float* __restrict__ C,
    int M, int K, int lda, int ldc, const int* __restrict__ gidx,
    unsigned short* __restrict__ Chi, unsigned short* __restrict__ Clo,
    int ldhl, int nhl,
    unsigned short* __restrict__ vthi, unsigned short* __restrict__ vtlo,
    long long zA, int zB, int zBias, int zC, int zChi, int zVt)
{
    constexpr int AI = MT / 32;
    constexpr int STR = GLL ? 32 : 40;
    __shared__ unsigned short Ah[MT * STR];
    __shared__ unsigned short Al[MT * STR];
    __shared__ unsigned short Bh[128 * STR];
    __shared__ unsigned short Bl[128 * STR];

    long long zz = blockIdx.z;
    if (AMODE == 0) A += zz * zA;
    else { Ahi += zz * zA; Alo += zz * zA; }
    Bth  += zz * (long long)zB;  Btl += zz * (long long)zB;
    bias += zz * (long long)zBias;
    C    += zz * (long long)zC;
    if (SPLIT) {
        Chi += zz * (long long)zChi; Clo += zz * (long long)zChi;
        vthi += zz * (long long)zVt; vtlo += zz * (long long)zVt;
    }

    int bm = blockIdx.y * MT, bn = blockIdx.x << 7;
    int tid = threadIdx.x;
    int lane = tid & 63, wid = tid >> 6;
    int wm = wid >> 1, wn = wid & 1;
    int fr = lane & 15, kg = (lane >> 4) << 3;

    // ---- GLL staging descriptors (wave-uniform dst, per-lane src) ----
    const unsigned short *aSrcH = nullptr, *aSrcL = nullptr;
    const unsigned short *bSrcH0 = nullptr, *bSrcL0 = nullptr;
    const unsigned short *bSrcH1 = nullptr, *bSrcL1 = nullptr;
    unsigned short *dstAh = nullptr, *dstAl = nullptr;
    unsigned short *dstBh0 = nullptr, *dstBl0 = nullptr;
    unsigned short *dstBh1 = nullptr, *dstBl1 = nullptr;
    bool doA = false;
    if (GLL) {
        int seg = (lane & 3) << 3;
        if (wid < MT / 16) {
            doA = true;
            int grow = bm + wid * 16 + (lane >> 2);
            grow = grow < M ? grow : (M - 1);
            long long arw = GATHER ? (long long)gidx[grow] : (long long)grow;
            aSrcH = Ahi + arw * lda + seg;
            aSrcL = Alo + arw * lda + seg;
            dstAh = &Ah[wid * 512];
            dstAl = &Al[wid * 512];
        }
        int br0 = bn + wid * 16 + (lane >> 2);
        int br1 = bn + (4 + wid) * 16 + (lane >> 2);
        bSrcH0 = Bth + (long long)br0 * K + seg;
        bSrcH1 = Bth + (long long)br1 * K + seg;
        bSrcL0 = Btl + (long long)br0 * K + seg;
        bSrcL1 = Btl + (long long)br1 * K + seg;
        dstBh0 = &Bh[wid * 512];       dstBh1 = &Bh[(4 + wid) * 512];
        dstBl0 = &Bl[wid * 512];       dstBl1 = &Bl[(4 + wid) * 512];
    }

    // ---- legacy staging coords (non-GLL) ----
    int ar = tid >> 2, akc = (tid & 3) << 3;
    int bnr = tid >> 1, bkc = (tid & 1) << 4;
    bool astage = ar < MT;
    long long arow = 0; bool avalid = false;
    if (!GLL && astage) {
        int gr = bm + ar;
        avalid = gr < M;
        if (GATHER) arow = avalid ? (long long)gidx[gr] : 0;
        else        arow = avalid ? (long long)gr : 0;
    }

    f32x4 acc[AI][4] = {};

    for (int k0 = 0; k0 < K; k0 += 32) {
        if (GLL) {
            if (doA) {
                gll16(aSrcH + k0, dstAh);
                gll16(aSrcL + k0, dstAl);
            }
            gll16(bSrcH0 + k0, dstBh0);
            gll16(bSrcH1 + k0, dstBh1);
            gll16(bSrcL0 + k0, dstBl0);
            gll16(bSrcL1 + k0, dstBl1);
        } else {
            if (astage) {
                if (AMODE == 0) {
                    float vv[8];
                    if (avalid) {
                        float4 v0 = *(const float4*)&A[arow * lda + k0 + akc];
                        float4 v1 = *(const float4*)&A[arow * lda + k0 + akc + 4];
                        vv[0] = v0.x; vv[1] = v0.y; vv[2] = v0.z; vv[3] = v0.w;
                        vv[4] = v1.x; vv[5] = v1.y; vv[6] = v1.z; vv[7] = v1.w;
                    } else {
                        #pragma unroll
                        for (int e = 0; e < 8; ++e) vv[e] = 0.f;
                    }
                    union { unsigned short u[8]; u32x4 v; } ph, pl;
                    #pragma unroll
                    for (int e = 0; e < 8; ++e) {
                        unsigned short h = f2bf(vv[e]);
                        ph.u[e] = h;
                        pl.u[e] = f2bf(vv[e] - bf2f(h));
                    }
                    *(u32x4*)&Ah[ar * STR + akc] = ph.v;
                    *(u32x4*)&Al[ar * STR + akc] = pl.v;
                } else {
                    u32x4 zv = {0u, 0u, 0u, 0u};
                    u32x4 vh = zv, vl = zv;
                    if (avalid) {
                        vh = *(const u32x4*)&Ahi[arow * lda + k0 + akc];
                        vl = *(const u32x4*)&Alo[arow * lda + k0 + akc];
                    }
                    *(u32x4*)&Ah[ar * STR + akc] = vh;
                    *(u32x4*)&Al[ar * STR + akc] = vl;
                }
            }
            long long boff = (long long)(bn + bnr) * K + k0 + bkc;
            *(u32x4*)&Bh[bnr * STR + bkc]     = *(const u32x4*)&Bth[boff];
            *(u32x4*)&Bh[bnr * STR + bkc + 8] = *(const u32x4*)&Bth[boff + 8];
            *(u32x4*)&Bl[bnr * STR + bkc]     = *(const u32x4*)&Btl[boff];
            *(u32x4*)&Bl[bnr * STR + bkc + 8] = *(const u32x4*)&Btl[boff + 8];
        }
        __syncthreads();

        bf16x8 af[AI], alf[AI], bfj[4], blf[4];
        #pragma unroll
        for (int i = 0; i < AI; ++i) {
            int row = (MT == 64 ? wm * 32 + i * 16 : wm * 16) + fr;
            af[i]  = *(const bf16x8*)&Ah[row * STR + kg];
            alf[i] = *(const bf16x8*)&Al[row * STR + kg];
        }
        #pragma unroll
        for (int j = 0; j < 4; ++j) {
            int row = wn * 64 + j * 16 + fr;
            bfj[j] = *(const bf16x8*)&Bh[row * STR + kg];
            blf[j] = *(const bf16x8*)&Bl[row * STR + kg];
        }
        #pragma unroll
        for (int i = 0; i < AI; ++i)
        #pragma unroll
        for (int j = 0; j < 4; ++j) {
            acc[i][j] = __builtin_amdgcn_mfma_f32_16x16x32_bf16(af[i],  bfj[j], acc[i][j], 0, 0, 0);
            acc[i][j] = __builtin_amdgcn_mfma_f32_16x16x32_bf16(af[i],  blf[j], acc[i][j], 0, 0, 0);
            acc[i][j] = __builtin_amdgcn_mfma_f32_16x16x32_bf16(alf[i], bfj[j], acc[i][j], 0, 0, 0);
        }
        __syncthreads();
    }

    #pragma unroll
    for (int i = 0; i < AI; ++i) {
        int rbase = bm + (MT == 64 ? wm * 32 + i * 16 : wm * 16) + ((lane >> 4) << 2);
        #pragma unroll
        for (int j = 0; j < 4; ++j) {
            int ccol = bn + wn * 64 + j * 16 + fr;
            float bv = bias[ccol];
            #pragma unroll
            for (int r = 0; r < 4; ++r) {
                int row = rbase + r;
                if (row < M) {
                    float val = acc[i][j][r] + bv;
                    if (EPI == 1) val = mishf(val);
                    if (EPI == 2) val = fmaxf(val, 0.f);
                    if (SPLIT) {
                        unsigned short hh = f2bf(val);
                        unsigned short ll = f2bf(val - bf2f(hh));
                        if (ccol < nhl) {
                            Chi[(long long)row * ldhl + ccol] = hh;
                            Clo[(long long)row * ldhl + ccol] = ll;
                        } else {
                            int bb = row / 400, m = row - bb * 400;
                            long long vi = ((long long)(bb * 512 + (ccol - 1024))) * 416 + m;
                            vthi[vi] = hh;
                            vtlo[vi] = ll;
                        }
                    } else {
                        C[(long long)row * ldc + ccol] = val;
                    }
                }
            }
        }
    }
}

// ---------------------------------------------------------------------------
// Weight prep kernels (write-coalesced)
// ---------------------------------------------------------------------------
__global__ __launch_bounds__(256) void prep_wqkv(
    const float* __restrict__ wq, const float* __restrict__ wk,
    const float* __restrict__ wv,
    unsigned short* __restrict__ whi, unsigned short* __restrict__ wlo,
    int obase, int total)
{
    int idx = blockIdx.x * 256 + threadIdx.x;
    if (idx >= total) return;
    int o = obase + idx / 786432;
    int rem = idx % 786432;
    int n = rem >> 9, k = rem & 511;
    int sel = n >> 9, col = n & 511;
    const float* W = sel == 0 ? wq : (sel == 1 ? wk : wv);
    float v = W[(long long)o * 262144 + k * 512 + col];
    unsigned short h = f2bf(v);
    whi[idx] = h;
    wlo[idx] = f2bf(v - bf2f(h));
}

__global__ __launch_bounds__(256) void prep_woiw(
    const float* __restrict__ wo, const float* __restrict__ wi,
    const float* __restrict__ wout,
    unsigned short* __restrict__ whi, unsigned short* __restrict__ wlo,
    int obase, int total)
{
    int idx = blockIdx.x * 256 + threadIdx.x;
    if (idx >= total) return;
    int o = obase + idx / 655360;
    int rem = idx % 655360;
    float v;
    if (rem < 262144) {
        int n = rem >> 9, k = rem & 511;
        v = wo[(long long)o * 262144 + k * 512 + n];
    } else if (rem < 524288) {
        int nk = rem - 262144;
        int n = nk >> 9, k = nk & 511;
        v = wi[(long long)o * 262144 + k * 512 + n];
    } else {
        int nk = rem - 524288;
        int n = nk >> 9, k = nk & 511;   // n < 256
        v = wout[(long long)o * 131072 + k * 256 + n];
    }
    unsigned short h = f2bf(v);
    whi[idx] = h;
    wlo[idx] = f2bf(v - bf2f(h));
}

__global__ __launch_bounds__(256) void prep_wcnn(
    const float* __restrict__ w,
    unsigned short* __restrict__ whi, unsigned short* __restrict__ wlo)
{
    int idx = blockIdx.x * 256 + threadIdx.x;
    if (idx >= 256 * 768) return;
    int n = idx / 768, k = idx % 768;
    float v = w[k * 256 + n];
    unsigned short h = f2bf(v);
    whi[idx] = h;
    wlo[idx] = f2bf(v - bf2f(h));
}

// ---------------------------------------------------------------------------
// Fused setup
// ---------------------------------------------------------------------------
__global__ __launch_bounds__(256) void setup_kernel(
    const float* __restrict__ x,
    const float* __restrict__ bq, const float* __restrict__ bk,
    const float* __restrict__ bv,
    float* __restrict__ mk, int* __restrict__ relT, int* __restrict__ convidx,
    float* __restrict__ f1pad, float* __restrict__ bqkv,
    unsigned short* __restrict__ vt_hi, unsigned short* __restrict__ vt_lo,
    int nOrg)
{
    int i = blockIdx.x * 256 + threadIdx.x;
    if (i < 3200) {
        const float* xr = x + (long long)i * 128;
        mk[i] = xr[4];
        mk[3200 + i] = fmaxf(xr[2], xr[3]);
        mk[6400 + i] = xr[0];
        mk[9600 + i] = xr[1];
        convidx[i] = (i / 400) * 402 + (i % 400);
    }
    int j = i - 3200;
    if (j >= 0 && j < 799) {
        int rel = j - 399;
        int sgn = (rel > 0) - (rel < 0);
        int ab = (rel < 300 && rel > -300) ? 299 : (rel < 0 ? -rel : rel);
        long long bpos;
        if (ab <= 300) bpos = rel;
        else {
            double lp = ceil(log((double)ab / 300.0) / log(599.0 / 300.0) * 299.0) + 300.0;
            bpos = (long long)lp * sgn;
        }
        long long c2p = bpos + 600;
        c2p = c2p < 0 ? 0 : (c2p > 1199 ? 1199 : c2p);
        relT[j] = (int)c2p;
    }
    int k = i - 4000;
    if (k >= 0 && k < 4096) {
        int b = k >> 9, rem = k & 511;
        int row = b * 402 + (rem < 256 ? 0 : 401);
        f1pad[(long long)row * 256 + (rem & 255)] = 0.f;
    }
    int m = i - 8100;
    if (m >= 0 && m < 6144) {
        int o = m / 1536, n = m % 1536;
        float v;
        if (n < 512) v = bq[o * 512 + n];
        else if (n < 1024) v = bk[o * 512 + n - 512];
        else v = bv[o * 512 + n - 1024];
        bqkv[m] = v;
    }
    int v = i - 14244;
    if (v >= 0 && v < nOrg * 65536) {   // vt pad cols [400..416) zero, as u32
        int og = v >> 16, rem = v & 65535;
        int vb = rem & 32767;
        int row = vb >> 3, c = vb & 7;
        unsigned int* p = (unsigned int*)((rem < 32768) ? vt_hi : vt_lo);
        p[(long long)og * 851968 + row * 208 + 200 + c] = 0u;
    }
}

// ---------------------------------------------------------------------------
// LayerNorm, wave-per-row. Organ-batched (o = row/rpo). RES: split residual.
// OSPL: 1 -> write split hi/lo, 0 -> write f32.
// ---------------------------------------------------------------------------
template<bool RES, int HD, int OSPL>
__global__ __launch_bounds__(256) void ln2_kernel(
    const float* __restrict__ X,
    const unsigned short* __restrict__ Rhi, const unsigned short* __restrict__ Rlo,
    const float* __restrict__ g, const float* __restrict__ be,
    float* __restrict__ Y,
    unsigned short* __restrict__ Yhi, unsigned short* __restrict__ Ylo,
    int rows, int rpo)
{
    constexpr int EPL = HD / 64;
    int wv = threadIdx.x >> 6, lane = threadIdx.x & 63;
    long long row = (long long)blockIdx.x * 4 + wv;
    if (row >= rows) return;
    int o = (int)(row / rpo);
    long long rrow = row % rpo;
    const float* x = X + row * HD;
    float v[EPL];
    #pragma unroll
    for (int q = 0; q < EPL / 4; ++q) {
        float4 a = *(const float4*)&x[lane * EPL + q * 4];
        v[q*4+0] = a.x; v[q*4+1] = a.y; v[q*4+2] = a.z; v[q*4+3] = a.w;
        if (RES) {
            us4 rh = *(const us4*)&Rhi[rrow * HD + lane * EPL + q * 4];
            us4 rl = *(const us4*)&Rlo[rrow * HD + lane * EPL + q * 4];
            #pragma unroll
            for (int e = 0; e < 4; ++e) v[q*4+e] += bf2f(rh[e]) + bf2f(rl[e]);
        }
    }
    float s = 0.f;
    #pragma unroll
    for (int e = 0; e < EPL; ++e) s += v[e];
    #pragma unroll
    for (int d = 1; d < 64; d <<= 1) s += __shfl_xor(s, d, 64);
    float mean = s * (1.f / HD);
    float s2 = 0.f;
    #pragma unroll
    for (int e = 0; e < EPL; ++e) { float d0 = v[e] - mean; s2 += d0 * d0; }
    #pragma unroll
    for (int d = 1; d < 64; d <<= 1) s2 += __shfl_xor(s2, d, 64);
    float inv = 1.f / sqrtf(s2 * (1.f / HD) + 1e-7f);
    #pragma unroll
    for (int q = 0; q < EPL / 4; ++q) {
        int c = lane * EPL + q * 4;
        float4 gg = *(const float4*)&g[o * HD + c];
        float4 bb = *(const float4*)&be[o * HD + c];
        float ov[4];
        ov[0] = (v[q*4+0] - mean) * inv * gg.x + bb.x;
        ov[1] = (v[q*4+1] - mean) * inv * gg.y + bb.y;
        ov[2] = (v[q*4+2] - mean) * inv * gg.z + bb.z;
        ov[3] = (v[q*4+3] - mean) * inv * gg.w + bb.w;
        if (OSPL) {
            us4 ph, pl;
            #pragma unroll
            for (int e = 0; e < 4; ++e) {
                unsigned short hh = f2bf(ov[e]);
                ph[e] = hh;
                pl[e] = f2bf(ov[e] - bf2f(hh));
            }
            *(us4*)&Yhi[row * HD + c] = ph;
            *(us4*)&Ylo[row * HD + c] = pl;
        } else {
            float4 of; of.x = ov[0]; of.y = ov[1]; of.z = ov[2]; of.w = ov[3];
            *(float4*)&Y[row * HD + c] = of;
        }
    }
}

// ---------------------------------------------------------------------------
// MFMA fused disentangled flash attention (R14 config, best measured):
// single-wave blocks, straight-line clamped loads, zero barriers.
// Grid (25, 8, 8*nOrg), XCD-swizzled.
// ---------------------------------------------------------------------------
__global__ __launch_bounds__(64) void attn_kernel(
    const unsigned short* __restrict__ qk_hi, const unsigned short* __restrict__ qk_lo,
    const unsigned short* __restrict__ vt_hi, const unsigned short* __restrict__ vt_lo,
    const unsigned short* __restrict__ pkg_hi, const unsigned short* __restrict__ pkg_lo,
    const float* __restrict__ mask,
    unsigned short* __restrict__ ctxh, unsigned short* __restrict__ ctxl)
{
    const float scale = 0.07216878364870322f;       // 1/sqrt(64*3)
    const float NEGMIN = -3.402823466e38f;
    int lin = blockIdx.x + 25 * (blockIdx.y + 8 * blockIdx.z);
    int gz = gridDim.z;
    int xcd = lin & 7, within = lin >> 3;
    int g = within / 25, lt = within - g * 25;
    int combo = xcd * gz + g;
    int h = combo & 7, z = combo >> 3;
    int b = z & 7, o = z >> 3;
    qk_hi  += (long long)o * 3276800;
    qk_lo  += (long long)o * 3276800;
    vt_hi  += (long long)o * 1703936;
    vt_lo  += (long long)o * 1703936;
    pkg_hi += (long long)o * 818176;
    mask   += o * 3200;
    ctxh   += (long long)o * 1638400;
    ctxl   += (long long)o * 1638400;

    int l0 = lt * 16;
    int lane = threadIdx.x;
    int fr = lane & 15, kg8 = (lane >> 4) << 3, g4 = (lane >> 4) << 2;

    __shared__ float T2c[16 * 36];
    __shared__ float T3c[32 * 20];
    __shared__ unsigned short Sth[16 * 40], Stl[16 * 40];

    bf16x8 qfh[2], qfl[2];
    {
        long long base = ((long long)(b * 400 + l0 + fr)) * 1024 + h * 64 + kg8;
        #pragma unroll
        for (int kk = 0; kk < 2; ++kk) {
            qfh[kk] = *(const bf16x8*)(qk_hi + base + kk * 32);
            qfl[kk] = *(const bf16x8*)(qk_lo + base + kk * 32);
        }
    }
    float wlv_r[4], ms[4], ls[4];
    #pragma unroll
    for (int r = 0; r < 4; ++r) {
        wlv_r[r] = mask[b * 400 + l0 + g4 + r];
        ms[r] = -INFINITY;
        ls[r] = 0.f;
    }
    f32x4 O[4] = {};
    long long vtbase = ((long long)(b * 512 + h * 64)) * 416;

    for (int mt = 0; mt < 13; ++mt) {
        int m0 = mt * 32;
        int D0 = l0 - m0 + 368;
        bf16x8 kfh[2][2], kfl[2][2];
        #pragma unroll
        for (int jf = 0; jf < 2; ++jf) {
            int kr = m0 + jf * 16 + fr;
            kr = kr < 400 ? kr : 399;
            long long base = ((long long)(b * 400 + kr)) * 1024 + 512 + h * 64 + kg8;
            #pragma unroll
            for (int kk = 0; kk < 2; ++kk) {
                kfh[jf][kk] = *(const bf16x8*)(qk_hi + base + kk * 32);
                kfl[jf][kk] = *(const bf16x8*)(qk_lo + base + kk * 32);
            }
        }
        bf16x8 b2h[3][2], b3h[3][2];
        #pragma unroll
        for (int c = 0; c < 3; ++c) {
            int dd = D0 + c * 16 + fr;
            dd = dd < 0 ? 0 : (dd > 798 ? 798 : dd);
            long long base = (long long)dd * 1024 + h * 64 + kg8;
            #pragma unroll
            for (int kk = 0; kk < 2; ++kk) {
                b2h[c][kk] = *(const bf16x8*)(pkg_hi + base + 512 + kk * 32);
                b3h[c][kk] = *(const bf16x8*)(pkg_hi + base + kk * 32);
            }
        }
        __builtin_amdgcn_s_setprio(1);
        f32x4 aT1[2] = {};
        #pragma unroll
        for (int jf = 0; jf < 2; ++jf)
        #pragma unroll
        for (int kk = 0; kk < 2; ++kk) {
            aT1[jf] = __builtin_amdgcn_mfma_f32_16x16x32_bf16(qfh[kk], kfh[jf][kk], aT1[jf], 0, 0, 0);
            aT1[jf] = __builtin_amdgcn_mfma_f32_16x16x32_bf16(qfh[kk], kfl[jf][kk], aT1[jf], 0, 0, 0);
            aT1[jf] = __builtin_amdgcn_mfma_f32_16x16x32_bf16(qfl[kk], kfh[jf][kk], aT1[jf], 0, 0, 0);
        }
        f32x4 aT2[3] = {};
        #pragma unroll
        for (int c = 0; c < 3; ++c)
        #pragma unroll
        for (int kk = 0; kk < 2; ++kk) {
            aT2[c] = __builtin_amdgcn_mfma_f32_16x16x32_bf16(qfh[kk], b2h[c][kk], aT2[c], 0, 0, 0);
            aT2[c] = __builtin_amdgcn_mfma_f32_16x16x32_bf16(qfl[kk], b2h[c][kk], aT2[c], 0, 0, 0);
        }
        __builtin_amdgcn_s_setprio(0);
        bf16x8 vfh[4], vfl[4];
        #pragma unroll
        for (int f = 0; f < 4; ++f) {
            long long a = vtbase + (long long)(f * 16 + fr) * 416 + m0 + kg8;
            vfh[f] = *(const bf16x8*)&vt_hi[a];
            vfl[f] = *(const bf16x8*)&vt_lo[a];
        }
        float wm_c[2];
        #pragma unroll
        for (int cf = 0; cf < 2; ++cf) {
            int mg = m0 + cf * 16 + fr;
            mg = mg < 400 ? mg : 399;
            wm_c[cf] = mask[b * 400 + mg];
        }
        __builtin_amdgcn_s_setprio(1);
        f32x4 aT3[2][2] = {};
        #pragma unroll
        for (int jf = 0; jf < 2; ++jf)
        #pragma unroll
        for (int ci = 0; ci < 2; ++ci) {
            int c = ci + (jf ^ 1);
            #pragma unroll
            for (int kk = 0; kk < 2; ++kk) {
                aT3[jf][ci] = __builtin_amdgcn_mfma_f32_16x16x32_bf16(kfh[jf][kk], b3h[c][kk], aT3[jf][ci], 0, 0, 0);
                aT3[jf][ci] = __builtin_amdgcn_mfma_f32_16x16x32_bf16(kfl[jf][kk], b3h[c][kk], aT3[jf][ci], 0, 0, 0);
            }
        }
        __builtin_amdgcn_s_setprio(0);
        #pragma unroll
        for (int c = 0; c < 3; ++c)
        #pragma unroll
        for (int r = 0; r < 4; ++r) {
            int i = g4 + r;
            int d = c * 16 + fr - i;
            if ((unsigned)d < 32u)
                T2c[i * 36 + d] = aT2[c][r];
        }
        #pragma unroll
        for (int jf = 0; jf < 2; ++jf)
        #pragma unroll
        for (int ci = 0; ci < 2; ++ci) {
            int c = ci + (jf ^ 1);
            #pragma unroll
            for (int r = 0; r < 4; ++r) {
                int j3 = jf * 16 + g4 + r;
                int d2 = c * 16 + fr + j3 - 31;
                if ((unsigned)d2 < 16u)
                    T3c[j3 * 20 + d2] = aT3[jf][ci][r];
            }
        }
        float sc0[4], sc1[4];
        #pragma unroll
        for (int r = 0; r < 4; ++r) {
            int i = g4 + r;
            {
                int j = fr;
                bool jv = (m0 + j) < 400;
                sc0[r] = !jv ? -INFINITY :
                    ((wlv_r[r] != 0.f && wm_c[0] != 0.f) ?
                     (aT1[0][r] + T2c[i * 36 + 31 - j] + T3c[j * 20 + i]) * scale : NEGMIN);
            }
            {
                int j = 16 + fr;
                bool jv = (m0 + j) < 400;
                sc1[r] = !jv ? -INFINITY :
                    ((wlv_r[r] != 0.f && wm_c[1] != 0.f) ?
                     (aT1[1][r] + T2c[i * 36 + 31 - j] + T3c[j * 20 + i]) * scale : NEGMIN);
            }
        }
        float corr[4];
        #pragma unroll
        for (int r = 0; r < 4; ++r) {
            float mx = fmaxf(sc0[r], sc1[r]);
            #pragma unroll
            for (int d = 1; d < 16; d <<= 1) mx = fmaxf(mx, __shfl_xor(mx, d, 64));
            float mn = fmaxf(ms[r], mx);
            corr[r] = __expf(ms[r] - mn);
            ms[r] = mn;
            float p0 = __expf(sc0[r] - mn), p1 = __expf(sc1[r] - mn);
            float rs = p0 + p1;
            #pragma unroll
            for (int d = 1; d < 16; d <<= 1) rs += __shfl_xor(rs, d, 64);
            ls[r] = ls[r] * corr[r] + rs;
            int i = g4 + r;
            unsigned short h0 = f2bf(p0);
            Sth[i * 40 + fr] = h0;
            Stl[i * 40 + fr] = f2bf(p0 - bf2f(h0));
            unsigned short h1 = f2bf(p1);
            Sth[i * 40 + 16 + fr] = h1;
            Stl[i * 40 + 16 + fr] = f2bf(p1 - bf2f(h1));
        }
        #pragma unroll
        for (int f = 0; f < 4; ++f)
        #pragma unroll
        for (int r = 0; r < 4; ++r) O[f][r] *= corr[r];
        bf16x8 Pha = *(const bf16x8*)&Sth[fr * 40 + kg8];
        bf16x8 Pla = *(const bf16x8*)&Stl[fr * 40 + kg8];
        __builtin_amdgcn_s_setprio(1);
        #pragma unroll
        for (int f = 0; f < 4; ++f) {
            O[f] = __builtin_amdgcn_mfma_f32_16x16x32_bf16(Pha, vfh[f], O[f], 0, 0, 0);
            O[f] = __builtin_amdgcn_mfma_f32_16x16x32_bf16(Pha, vfl[f], O[f], 0, 0, 0);
            O[f] = __builtin_amdgcn_mfma_f32_16x16x32_bf16(Pla, vfh[f], O[f], 0, 0, 0);
        }
        __builtin_amdgcn_s_setprio(0);
    }
    #pragma unroll
    for (int f = 0; f < 4; ++f) {
        int colg = h * 64 + f * 16 + fr;
        #pragma unroll
        for (int r = 0; r < 4; ++r) {
            int lg = l0 + g4 + r;
            float val = O[f][r] / ls[r];
            long long idx = ((long long)(b * 400 + lg)) * 512 + colg;
            unsigned short hh = f2bf(val);
            ctxh[idx] = hh;
            ctxl[idx] = f2bf(val - bf2f(hh));
        }
    }
}

// ---------------------------------------------------------------------------
// Chunked pool / meanmax (full-chip), heads
// ---------------------------------------------------------------------------
__global__ __launch_bounds__(256) void pool_part(
    const float* __restrict__ in, long long inOStride,
    const float* __restrict__ mk, float* __restrict__ pp)
{
    int bi = blockIdx.x, c = blockIdx.y, t = threadIdx.x;
    int o = bi >> 3, b = bi & 7;
    int l0 = c * 31, l1 = min(400, l0 + 31);
    const float* ib = in + (long long)o * inOStride + (long long)(b * 400) * 256;
    const float* mkb = mk + o * 3200 + b * 400;
    float s = 0.f, mx = -INFINITY, sw = 0.f;
    for (int l = l0; l < l1; ++l) {
        float wv = mkb[l];
        float v = ib[(long long)l * 256 + t] * wv;
        s += v; mx = fmaxf(mx, v); sw += wv;
    }
    long long base = (long long)(c * gridDim.x + bi) * 514;
    pp[base + t] = s;
    pp[base + 256 + t] = mx;
    if (t == 0) pp[base + 512] = sw;
}

__global__ __launch_bounds__(256) void pool_merge(
    const float* __restrict__ pp, float* __restrict__ pooled, int nBI)
{
    int bi = blockIdx.x, t = threadIdx.x;
    float s = 0.f, mx = -INFINITY, sw = 0.f;
    for (int c = 0; c < 13; ++c) {
        long long base = (long long)(c * nBI + bi) * 514;
        s += pp[base + t];
        mx = fmaxf(mx, pp[base + 256 + t]);
        sw += pp[base + 512];
    }
    int o = bi >> 3, b = bi & 7;
    pooled[o * 4096 + b * 512 + t] = s / (sw + 1e-6f);
    pooled[o * 4096 + b * 512 + 256 + t] = mx;
}

__global__ __launch_bounds__(512) void mm_part(
    const unsigned short* __restrict__ fh, const unsigned short* __restrict__ fl,
    float* __restrict__ mmp)
{
    int b = blockIdx.x, c = blockIdx.y, t = threadIdx.x;
    int l0 = c * 31, l1 = min(400, l0 + 31);
    float s = 0.f, mx = -INFINITY;
    for (int l = l0; l < l1; ++l) {
        long long idx = ((long long)(b * 400 + l)) * 512 + t;
        float v = bf2f(fh[idx]) + bf2f(fl[idx]);
        s += v; mx = fmaxf(mx, v);
    }
    long long base = (long long)(c * 8 + b) * 1024;
    mmp[base + t] = s;
    mmp[base + 512 + t] = mx;
}

__global__ __launch_bounds__(512) void mm_merge(
    const float* __restrict__ mmp, float* __restrict__ mm)
{
    int b = blockIdx.x, t = threadIdx.x;
    float s = 0.f, mx = -INFINITY;
    for (int c = 0; c < 13; ++c) {
        long long base = (long long)(c * 8 + b) * 1024;
        s += mmp[base + t];
        mx = fmaxf(mx, mmp[base + 512 + t]);
    }
    mm[b * 1024 + t] = s / 400.f;
    mm[b * 1024 + 512 + t] = mx;
}

__global__ __launch_bounds__(256) void heads_kernel(
    const float* __restrict__ pooled, const float* __restrict__ mm,
    const float* __restrict__ w_bow1, const float* __restrict__ b_bow1,
    const float* __restrict__ w_bow2, const float* __restrict__ b_bow2,
    const float* __restrict__ w_ext1, const float* __restrict__ b_ext1,
    const float* __restrict__ w_ext2, const float* __restrict__ b_ext2,
    const float* __restrict__ w_org1, const float* __restrict__ b_org1,
    const float* __restrict__ w_org2, const float* __restrict__ b_org2,
    float* __restrict__ out)
{
    int b = blockIdx.x, role = blockIdx.y;
    int t = threadIdx.x;
    __shared__ float inb[1024];
    __shared__ float red[256];
    __shared__ float hid[256];
    if (role == 0) {
        inb[t] = pooled[b * 512 + t];
        inb[256 + t] = pooled[b * 512 + 256 + t];
        __syncthreads();
        float acc = b_bow1[t];
        for (int j = 0; j < 512; ++j) acc += inb[j] * w_bow1[j * 256 + t];
        red[t] = mishf(acc) * w_bow2[t];
        __syncthreads();
        for (int s = 128; s; s >>= 1) { if (t < s) red[t] += red[t + s]; __syncthreads(); }
        if (t == 0) out[b * 11 + 0] = red[0] + b_bow2[0];
    } else if (role == 1) {
        inb[t] = mm[b * 1024 + t];
        inb[256 + t] = mm[b * 1024 + 256 + t];
        inb[512 + t] = mm[b * 1024 + 512 + t];
        inb[768 + t] = mm[b * 1024 + 768 + t];
        __syncthreads();
        float acc = b_ext1[t];
        for (int j = 0; j < 1024; ++j) acc += inb[j] * w_ext1[j * 256 + t];
        red[t] = mishf(acc) * w_ext2[t];
        __syncthreads();
        for (int s = 128; s; s >>= 1) { if (t < s) red[t] += red[t + s]; __syncthreads(); }
        if (t == 0) { out[b * 11 + 1] = red[0] + b_ext2[0]; out[88 + b] = 0.f; }
    } else {
        int i = role - 2;
        inb[t] = pooled[((1 + i) * 8 + b) * 512 + t];
        inb[256 + t] = pooled[((1 + i) * 8 + b) * 512 + 256 + t];
        __syncthreads();
        float acc = b_org1[i * 256 + t];
        for (int j = 0; j < 512; ++j)
            acc += inb[j] * w_org1[((long long)i * 512 + j) * 256 + t];
        hid[t] = mishf(acc);
        __syncthreads();
        for (int c = 0; c < 3; ++c) {
            red[t] = hid[t] * w_org2[(i * 256 + t) * 3 + c];
            __syncthreads();
            for (int s = 128; s; s >>= 1) { if (t < s) red[t] += red[t + s]; __syncthreads(); }
            if (t == 0) out[b * 11 + 2 + i * 3 + c] = red[0] + b_org2[i * 3 + c];
            __syncthreads();
        }
    }
}

// ---------------------------------------------------------------------------
// Launch
// ---------------------------------------------------------------------------
extern "C" void kernel_launch(void* const* d_in, const int* in_sizes, int n_in,
                              void* d_out, int out_size, void* d_ws, size_t ws_size,
                              hipStream_t stream)
{
    const float* x      = (const float*)d_in[0];
    const float* w_mlp  = (const float*)d_in[1];
    const float* b_mlp  = (const float*)d_in[2];
    const float* w_cnn  = (const float*)d_in[3];
    const float* b_cnn  = (const float*)d_in[4];
    const float* rel_emb= (const float*)d_in[5];
    const float* rel_g  = (const float*)d_in[6];
    const float* rel_b  = (const float*)d_in[7];
    const float* wq     = (const float*)d_in[8];
    const float* wk     = (const float*)d_in[9];
    const float* wv     = (const float*)d_in[10];
    const float* wo     = (const float*)d_in[11];
    const float* wi     = (const float*)d_in[12];
    const float* bq     = (const float*)d_in[13];
    const float* bk     = (const float*)d_in[14];
    const float* bv     = (const float*)d_in[15];
    const float* bo     = (const float*)d_in[16];
    const float* bi     = (const float*)d_in[17];
    const float* wout   = (const float*)d_in[18];
    const float* bout   = (const float*)d_in[19];
    const float* ln1g   = (const float*)d_in[20];
    const float* ln1b   = (const float*)d_in[21];
    const float* ln2g   = (const float*)d_in[22];
    const float* ln2b   = (const float*)d_in[23];
    const float* w_bow1 = (const float*)d_in[24];
    const float* b_bow1 = (const float*)d_in[25];
    const float* w_bow2 = (const float*)d_in[26];
    const float* b_bow2 = (const float*)d_in[27];
    const float* w_ext1 = (const float*)d_in[28];
    const float* b_ext1 = (const float*)d_in[29];
    const float* w_ext2 = (const float*)d_in[30];
    const float* b_ext2 = (const float*)d_in[31];
    const float* w_org1 = (const float*)d_in[32];
    const float* b_org1 = (const float*)d_in[33];
    const float* w_org2 = (const float*)d_in[34];
    const float* b_org2 = (const float*)d_in[35];

    float* ws = (float*)d_ws;
    float* outf = (float*)d_out;
    const bool big = ws_size >= 143012736ull;

    if (big) {
        // ---------------- organ-batched path ----------------
        unsigned short* featsh = (unsigned short*)(ws + 0);        // 3200x512
        unsigned short* featsl = (unsigned short*)(ws + 819200);
        float* ctxR     = ws + 1638400;      // 6,553,600 fl
        float* f1pad    = ctxR;
        unsigned short* ctxh = (unsigned short*)ctxR;              // 4x3200x512
        unsigned short* ctxl = (unsigned short*)(ws + 4915200);
        float* qkA_f    = ws + 8192000;
        float* qkB_f    = ws + 14745600;
        unsigned short* qkA = (unsigned short*)qkA_f;
        unsigned short* qkB = (unsigned short*)qkB_f;
        unsigned short* rellnh = (unsigned short*)qkA_f;           // 4800x512
        unsigned short* rellnl = (unsigned short*)(ws + 8192000 + 1228800);
        unsigned short* vtA = (unsigned short*)(ws + 21299200);    // 4x4096x416
        unsigned short* vtB = (unsigned short*)(ws + 24707072);
        unsigned short* pkgA = (unsigned short*)(ws + 28114944);   // 4x799x1024
        unsigned short* pkgB = (unsigned short*)(ws + 29751296);
        unsigned short* whiA = (unsigned short*)(ws + 31387648);   // 4x786,432
        unsigned short* wloA = (unsigned short*)(ws + 32960512);
        unsigned short* wcnn_hi = (unsigned short*)(ws + 35188736);
        unsigned short* wcnn_lo = (unsigned short*)(ws + 35287040);
        float* bqkvb   = ws + 35385344;
        float* masksb  = ws + 35391488;
        float* pooledb = ws + 35404288;
        float* mmb     = ws + 35420672;
        int*   relidx  = (int*)(ws + 35428864);
        int*   convidx = (int*)(ws + 35429664);
        float* poolpart= ws + 35432864;
        float* mmpart  = ws + 35646688;
        float* tmp_all   = qkA_f;                                  // WO out (f32)
        unsigned short* h1h = (unsigned short*)qkB_f;              // LN1 out split
        unsigned short* h1l = (unsigned short*)(ws + 14745600 + 3276800);
        unsigned short* interh = (unsigned short*)qkA_f;           // WI out split
        unsigned short* interl = (unsigned short*)(ws + 8192000 + 3276800);
        float* outenc_all = (float*)vtA;                           // 4x819,200 f32
        float* outln_all  = ctxR;                                  // 4x819,200 f32
        unsigned short* whiB_all = whiA;
        unsigned short* wloB_all = wloA;

        gemm_bias<1><<<dim3(4, 50), 256, 0, stream>>>(
            x, w_mlp, b_mlp, f1pad, featsh, featsl, 3200, 256, 128, 512);
        setup_kernel<<<1080, 256, 0, stream>>>(x, bq, bk, bv, masksb, relidx, convidx,
                                               f1pad, bqkvb, vtA, vtB, 4);
        prep_wcnn<<<768, 256, 0, stream>>>(w_cnn, wcnn_hi, wcnn_lo);
        gemm_mfma<2, true, 0, true, 32, false><<<dim3(2, 100), 256, 0, stream>>>(
            f1pad, nullptr, nullptr, wcnn_hi, wcnn_lo, b_cnn, nullptr,
            3200, 768, 256, 0, convidx, featsh + 256, featsl + 256, 512, 1 << 30,
            nullptr, nullptr, 0, 0, 0, 0, 0, 0);

        ln2_kernel<false, 512, 1><<<1200, 256, 0, stream>>>(
            rel_emb, nullptr, nullptr, rel_g, rel_b, nullptr, rellnh, rellnl, 4800, 1200);
        prep_wqkv<<<12288, 256, 0, stream>>>(wq, wk, wv, whiA, wloA, 0, 3145728);
        gemm_mfma<0, true, 1, true, 64, true><<<dim3(8, 13, 4), 256, 0, stream>>>(
            nullptr, rellnh, rellnl, whiA, wloA, bqkvb, nullptr, 799, 512, 512, 0, relidx,
            pkgA, pkgB, 1024, 1024, nullptr, nullptr,
            614400, 786432, 1536, 0, 818176, 0);
        gemm_mfma<0, false, 1, true, 64, true><<<dim3(12, 50, 4), 256, 0, stream>>>(
            nullptr, featsh, featsl, whiA, wloA, bqkvb, nullptr, 3200, 512, 512, 0, nullptr,
            qkA, qkB, 1024, 1024, vtA, vtB,
            0, 786432, 1536, 0, 3276800, 1703936);
        prep_woiw<<<10240, 256, 0, stream>>>(wo, wi, wout, whiB_all, wloB_all,
                                             0, 2621440);
        attn_kernel<<<dim3(25, 8, 32), 64, 0, stream>>>(qkA, qkB, vtA, vtB,
            pkgA, pkgB, masksb, ctxh, ctxl);
        gemm_mfma<0, false, 1, false, 32, true><<<dim3(4, 100, 4), 256, 0, stream>>>(
            nullptr, ctxh, ctxl, whiB_all, wloB_all, bo, tmp_all,
            3200, 512, 512, 512, nullptr, nullptr, nullptr, 0, 0, nullptr, nullptr,
            1638400, 655360, 512, 1638400, 0, 0);
        ln2_kernel<true, 512, 1><<<3200, 256, 0, stream>>>(
            tmp_all, featsh, featsl, ln1g, ln1b, nullptr, h1h, h1l, 12800, 3200);
        gemm_mfma<1, false, 1, true, 32, true><<<dim3(4, 100, 4), 256, 0, stream>>>(
            nullptr, h1h, h1l, whiB_all + 262144, wloB_all + 262144, bi, nullptr,
            3200, 512, 512, 0, nullptr, interh, interl, 512, 1 << 30, nullptr, nullptr,
            1638400, 655360, 512, 0, 1638400, 0);
        gemm_mfma<0, false, 1, false, 32, true><<<dim3(2, 100, 4), 256, 0, stream>>>(
            nullptr, interh, interl, whiB_all + 524288, wloB_all + 524288, bout, outenc_all,
            3200, 512, 512, 256, nullptr, nullptr, nullptr, 0, 0, nullptr, nullptr,
            1638400, 655360, 256, 819200, 0, 0);
        ln2_kernel<false, 256, 0><<<3200, 256, 0, stream>>>(
            outenc_all, nullptr, nullptr, ln2g, ln2b, outln_all, nullptr, nullptr,
            12800, 3200);

        pool_part<<<dim3(32, 13), 256, 0, stream>>>(outln_all, 819200, masksb, poolpart);
        pool_merge<<<32, 256, 0, stream>>>(poolpart, pooledb, 32);
        mm_part<<<dim3(8, 13), 512, 0, stream>>>(featsh, featsl, mmpart);
        mm_merge<<<8, 512, 0, stream>>>(mmpart, mmb);
        heads_kernel<<<dim3(8, 5), 256, 0, stream>>>(pooledb, mmb,
            w_bow1, b_bow1, w_bow2, b_bow2, w_ext1, b_ext1, w_ext2, b_ext2,
            w_org1, b_org1, w_org2, b_org2, outf);
        return;
    }

    // ---------------- per-organ fallback path ----------------
    unsigned short* featsh = (unsigned short*)(ws + 0);
    unsigned short* featsl = (unsigned short*)(ws + 819200);
    float* ctxR    = ws + 1638400;
    float* f1pad   = ctxR;
    unsigned short* ctxh = (unsigned short*)ctxR;
    unsigned short* ctxl = (unsigned short*)(ws + 1638400 + 819200);
    float* qkvA_f  = ws + 3276800;
    float* qkvB_f  = ws + 4915200;
    unsigned short* qkv_hi = (unsigned short*)qkvA_f;
    unsigned short* qkv_lo = (unsigned short*)qkvB_f;
    unsigned short* rellnh = (unsigned short*)qkvB_f;
    unsigned short* rellnl = (unsigned short*)(ws + 4915200 + 307200);
    unsigned short* pkg_hi = (unsigned short*)(ws + 6553600);
    unsigned short* pkg_lo = (unsigned short*)(ws + 6963200);
    unsigned short* vt_hi  = (unsigned short*)(ws + 7372800);
    unsigned short* vt_lo  = (unsigned short*)(ws + 8224768);
    unsigned short* whi    = (unsigned short*)(ws + 9076736);
    unsigned short* wlo    = (unsigned short*)(ws + 9469952);
    float* bqkvb   = ws + 9863168;
    float* masksb  = ws + 9869312;
    float* pooledb = ws + 9882112;
    float* mmb     = ws + 9898496;
    int*   relidx  = (int*)(ws + 9906688);
    unsigned short* wcnn_hi = (unsigned short*)(ws + 9907488);
    unsigned short* wcnn_lo = (unsigned short*)(ws + 10005792);
    int*   convidx = (int*)(ws + 10104096);
    float* poolpart= ws + 10107296;
    float* mmpart  = ws + 10160752;
    float* tmp     = qkvA_f;
    unsigned short* h1h = (unsigned short*)qkvB_f;
    unsigned short* h1l = (unsigned short*)(ws + 4915200 + 819200);
    unsigned short* interh = (unsigned short*)qkvA_f;
    unsigned short* interl = (unsigned short*)(ws + 3276800 + 819200);
    float* outenc  = (float*)vt_hi;
    float* outln   = ctxR;

    gemm_bias<1><<<dim3(4, 50), 256, 0, stream>>>(
        x, w_mlp, b_mlp, f1pad, featsh, featsl, 3200, 256, 128, 512);
    setup_kernel<<<312, 256, 0, stream>>>(x, bq, bk, bv, masksb, relidx, convidx,
                                          f1pad, bqkvb, vt_hi, vt_lo, 1);
    prep_wcnn<<<768, 256, 0, stream>>>(w_cnn, wcnn_hi, wcnn_lo);
    gemm_mfma<2, true, 0, true, 32, false><<<dim3(2, 100), 256, 0, stream>>>(
        f1pad, nullptr, nullptr, wcnn_hi, wcnn_lo, b_cnn, nullptr,
        3200, 768, 256, 0, convidx, featsh + 256, featsl + 256, 512, 1 << 30,
        nullptr, nullptr, 0, 0, 0, 0, 0, 0);

    for (int o = 0; o < 4; ++o) {
        ln2_kernel<false, 512, 1><<<300, 256, 0, stream>>>(
            rel_emb + (long long)o * 614400, nullptr, nullptr,
            rel_g + o * 512, rel_b + o * 512, nullptr, rellnh, rellnl, 1200, 1200);
        prep_wqkv<<<3072, 256, 0, stream>>>(wq, wk, wv, whi, wlo, o, 786432);
        gemm_mfma<0, true, 1, true, 64, true><<<dim3(8, 13), 256, 0, stream>>>(
            nullptr, rellnh, rellnl, whi, wlo, bqkvb + o * 1536, nullptr,
            799, 512, 512, 0, relidx, pkg_hi, pkg_lo, 1024, 1024, nullptr, nullptr,
            0, 0, 0, 0, 0, 0);
        gemm_mfma<0, false, 1, true, 64, true><<<dim3(12, 50), 256, 0, stream>>>(
            nullptr, featsh, featsl, whi, wlo, bqkvb + o * 1536, nullptr,
            3200, 512, 512, 0, nullptr, qkv_hi, qkv_lo, 1024, 1024, vt_hi, vt_lo,
            0, 0, 0, 0, 0, 0);
        prep_woiw<<<2560, 256, 0, stream>>>(wo, wi, wout, whi, wlo, o, 655360);
        attn_kernel<<<dim3(25, 8, 8), 64, 0, stream>>>(qkv_hi, qkv_lo, vt_hi, vt_lo,
            pkg_hi, pkg_lo, masksb + o * 3200, ctxh, ctxl);
        gemm_mfma<0, false, 1, false, 32, true><<<dim3(4, 100), 256, 0, stream>>>(
            nullptr, ctxh, ctxl, whi, wlo, bo + o * 512, tmp,
            3200, 512, 512, 512, nullptr, nullptr, nullptr, 0, 0, nullptr, nullptr,
            0, 0, 0, 0, 0, 0);
        ln2_kernel<true, 512, 1><<<800, 256, 0, stream>>>(
            tmp, featsh, featsl, ln1g + o * 512, ln1b + o * 512, nullptr,
            h1h, h1l, 3200, 3200);
        gemm_mfma<1, false, 1, true, 32, true><<<dim3(4, 100), 256, 0, stream>>>(
            nullptr, h1h, h1l, whi + 262144, wlo + 262144, bi + o * 512, nullptr,
            3200, 512, 512, 0, nullptr, interh, interl, 512, 1 << 30, nullptr, nullptr,
            0, 0, 0, 0, 0, 0);
        gemm_mfma<0, false, 1, false, 32, true><<<dim3(2, 100), 256, 0, stream>>>(
            nullptr, interh, interl, whi + 524288, wlo + 524288, bout + o * 256, outenc,
            3200, 512, 512, 256, nullptr, nullptr, nullptr, 0, 0, nullptr, nullptr,
            0, 0, 0, 0, 0, 0);
        ln2_kernel<false, 256, 0><<<800, 256, 0, stream>>>(
            outenc, nullptr, nullptr, ln2g + o * 256, ln2b + o * 256, outln,
            nullptr, nullptr, 3200, 3200);
        pool_part<<<dim3(8, 13), 256, 0, stream>>>(outln, 0,
                                                   masksb + o * 3200, poolpart);
        pool_merge<<<8, 256, 0, stream>>>(poolpart, pooledb + o * 4096, 8);
    }

    mm_part<<<dim3(8, 13), 512, 0, stream>>>(featsh, featsl, mmpart);
    mm_merge<<<8, 512, 0, stream>>>(mmpart, mmb);
    heads_kernel<<<dim3(8, 5), 256, 0, stream>>>(pooledb, mmb,
        w_bow1, b_bow1, w_bow2, b_bow2, w_ext1, b_ext1, w_ext2, b_ext2,
        w_org1, b_org1, w_org2, b_org2, outf);
}

// Round 16
// 618.660 us; speedup vs baseline: 1.1688x; 1.1020x over previous
//
#include <hip/hip_runtime.h>
#include <math.h>

// ---------------------------------------------------------------------------
// Model dims (fixed): B=8 L=400 F=128 D=256 T=256 H=512 NH=8 HD=64 P=1200
// ---------------------------------------------------------------------------

typedef __attribute__((ext_vector_type(8))) short bf16x8;
typedef __attribute__((ext_vector_type(4))) float f32x4;
typedef __attribute__((ext_vector_type(4))) unsigned int u32x4;
typedef __attribute__((ext_vector_type(4))) unsigned short us4;

__device__ __forceinline__ float mishf(float x) {
    float sp = fmaxf(x, 0.f) + log1pf(expf(-fabsf(x)));   // stable softplus
    return x * tanhf(sp);
}

__device__ __forceinline__ unsigned short f2bf(float f) {
    unsigned int u = __float_as_uint(f);
    u = (u + 0x7fffu + ((u >> 16) & 1u)) >> 16;           // RNE
    return (unsigned short)u;
}
__device__ __forceinline__ float bf2f(unsigned short h) {
    return __uint_as_float(((unsigned int)h) << 16);
}

// async global->LDS 16B per lane; dst is wave-uniform base (+ lane*16 in HW)
__device__ __forceinline__ void gll16(const unsigned short* g, unsigned short* l) {
    __builtin_amdgcn_global_load_lds(
        (const __attribute__((address_space(1))) void*)g,
        (__attribute__((address_space(3))) void*)l, 16, 0, 0);
}

// ---------------------------------------------------------------------------
// fp32 GEMM (front MLP, K=128): writes f1pad (padded conv layout) + split
// bf16 hi/lo feats (cols 0..255 of 512-wide).
// ---------------------------------------------------------------------------
template<int EPI>
__global__ __launch_bounds__(256) void gemm_bias(
    const float* __restrict__ A, const float* __restrict__ Bm,
    const float* __restrict__ bias, float* __restrict__ C2,
    unsigned short* __restrict__ fhi, unsigned short* __restrict__ flo,
    int M, int N, int K, int ldc)
{
    __shared__ float As[16][68];
    __shared__ float Bs[16][68];
    int bm = blockIdx.y << 6, bn = blockIdx.x << 6;
    int tid = threadIdx.x;
    int tm = (tid >> 4) << 2, tn = (tid & 15) << 2;
    int ar = tid >> 2, ac4 = (tid & 3) << 2;
    int br = tid >> 4, bc4 = (tid & 15) << 2;
    float acc[4][4] = {};
    for (int k0 = 0; k0 < K; k0 += 16) {
        float4 av = make_float4(0.f, 0.f, 0.f, 0.f);
        if (bm + ar < M)
            av = *(const float4*)&A[(long long)(bm + ar) * K + k0 + ac4];
        As[ac4][ar] = av.x; As[ac4 + 1][ar] = av.y;
        As[ac4 + 2][ar] = av.z; As[ac4 + 3][ar] = av.w;
        *(float4*)&Bs[br][bc4] =
            *(const float4*)&Bm[(long long)(k0 + br) * N + bn + bc4];
        __syncthreads();
        #pragma unroll
        for (int kk = 0; kk < 16; ++kk) {
            float4 a4 = *(const float4*)&As[kk][tm];
            float4 b4 = *(const float4*)&Bs[kk][tn];
            acc[0][0] += a4.x * b4.x; acc[0][1] += a4.x * b4.y;
            acc[0][2] += a4.x * b4.z; acc[0][3] += a4.x * b4.w;
            acc[1][0] += a4.y * b4.x; acc[1][1] += a4.y * b4.y;
            acc[1][2] += a4.y * b4.z; acc[1][3] += a4.y * b4.w;
            acc[2][0] += a4.z * b4.x; acc[2][1] += a4.z * b4.y;
            acc[2][2] += a4.z * b4.z; acc[2][3] += a4.z * b4.w;
            acc[3][0] += a4.w * b4.x; acc[3][1] += a4.w * b4.y;
            acc[3][2] += a4.w * b4.z; acc[3][3] += a4.w * b4.w;
        }
        __syncthreads();
    }
    #pragma unroll
    for (int i = 0; i < 4; ++i) {
        int r = bm + tm + i;
        if (r < M) {
            float v[4];
            #pragma unroll
            for (int q = 0; q < 4; ++q) {
                v[q] = acc[i][q] + bias[bn + tn + q];
                if (EPI == 1) v[q] = mishf(v[q]);
            }
            float4 o; o.x = v[0]; o.y = v[1]; o.z = v[2]; o.w = v[3];
            int rr2 = (r / 400) * 402 + (r % 400) + 1;
            *(float4*)&C2[(long long)rr2 * 256 + bn + tn] = o;
            us4 ph, pl;
            #pragma unroll
            for (int q = 0; q < 4; ++q) {
                unsigned short hh = f2bf(v[q]);
                ph[q] = hh;
                pl[q] = f2bf(v[q] - bf2f(hh));
            }
            *(us4*)&fhi[(long long)r * ldc + bn + tn] = ph;
            *(us4*)&flo[(long long)r * ldc + bn + tn] = pl;
        }
    }
}

// ---------------------------------------------------------------------------
// MFMA bf16x3-split GEMM. B pre-transposed+split [N][K] bf16 hi/lo.
// AMODE: 0 = A fp32 (split per tile), 1 = A pre-split hi/lo.
// GLL: stage A/B via global_load_lds (async, unpadded stride-32 LDS).
// SPLIT out: cols<nhl -> Chi/Clo [row][col]; cols>=1024 -> V transposed (416).
// EPI: 0 none, 1 mish, 2 relu.
// ---------------------------------------------------------------------------
template<int EPI, bool GATHER, int AMODE, bool SPLIT, int MT, bool GLL>
__global__ __launch_bounds__(256) void gemm_mfma(
    const float* __restrict__ A,
    const unsigned short* __restrict__ Ahi, const unsigned short* __restrict__ Alo,
    const unsigned short* __restrict__ Bth, const unsigned short* __restrict__ Btl,
    const float* __restrict__ bias, float* __restrict__ C,
    int M, int K, int lda, int ldc, const int* __restrict__ gidx,
    unsigned short* __restrict__ Chi, unsigned short* __restrict__ Clo,
    int ldhl, int nhl,
    unsigned short* __restrict__ vthi, unsigned short* __restrict__ vtlo,
    long long zA, int zB, int zBias, int zC, int zChi, int zVt)
{
    constexpr int AI = MT / 32;
    constexpr int STR = GLL ? 32 : 40;
    __shared__ unsigned short Ah[MT * STR];
    __shared__ unsigned short Al[MT * STR];
    __shared__ unsigned short Bh[128 * STR];
    __shared__ unsigned short Bl[128 * STR];

    long long zz = blockIdx.z;
    if (AMODE == 0) A += zz * zA;
    else { Ahi += zz * zA; Alo += zz * zA; }
    Bth  += zz * (long long)zB;  Btl += zz * (long long)zB;
    bias += zz * (long long)zBias;
    C    += zz * (long long)zC;
    if (SPLIT) {
        Chi += zz * (long long)zChi; Clo += zz * (long long)zChi;
        vthi += zz * (long long)zVt; vtlo += zz * (long long)zVt;
    }

    int bm = blockIdx.y * MT, bn = blockIdx.x << 7;
    int tid = threadIdx.x;
    int lane = tid & 63, wid = tid >> 6;
    int wm = wid >> 1, wn = wid & 1;
    int fr = lane & 15, kg = (lane >> 4) << 3;

    // ---- GLL staging descriptors (wave-uniform dst, per-lane src) ----
    const unsigned short *aSrcH = nullptr, *aSrcL = nullptr;
    const unsigned short *bSrcH0 = nullptr, *bSrcL0 = nullptr;
    const unsigned short *bSrcH1 = nullptr, *bSrcL1 = nullptr;
    unsigned short *dstAh = nullptr, *dstAl = nullptr;
    unsigned short *dstBh0 = nullptr, *dstBl0 = nullptr;
    unsigned short *dstBh1 = nullptr, *dstBl1 = nullptr;
    bool doA = false;
    if (GLL) {
        int seg = (lane & 3) << 3;
        if (wid < MT / 16) {
            doA = true;
            int grow = bm + wid * 16 + (lane >> 2);
            grow = grow < M ? grow : (M - 1);
            long long arw = GATHER ? (long long)gidx[grow] : (long long)grow;
            aSrcH = Ahi + arw * lda + seg;
            aSrcL = Alo + arw * lda + seg;
            dstAh = &Ah[wid * 512];
            dstAl = &Al[wid * 512];
        }
        int br0 = bn + wid * 16 + (lane >> 2);
        int br1 = bn + (4 + wid) * 16 + (lane >> 2);
        bSrcH0 = Bth + (long long)br0 * K + seg;
        bSrcH1 = Bth + (long long)br1 * K + seg;
        bSrcL0 = Btl + (long long)br0 * K + seg;
        bSrcL1 = Btl + (long long)br1 * K + seg;
        dstBh0 = &Bh[wid * 512];       dstBh1 = &Bh[(4 + wid) * 512];
        dstBl0 = &Bl[wid * 512];       dstBl1 = &Bl[(4 + wid) * 512];
    }

    // ---- legacy staging coords (non-GLL) ----
    int ar = tid >> 2, akc = (tid & 3) << 3;
    int bnr = tid >> 1, bkc = (tid & 1) << 4;
    bool astage = ar < MT;
    long long arow = 0; bool avalid = false;
    if (!GLL && astage) {
        int gr = bm + ar;
        avalid = gr < M;
        if (GATHER) arow = avalid ? (long long)gidx[gr] : 0;
        else        arow = avalid ? (long long)gr : 0;
    }

    f32x4 acc[AI][4] = {};

    for (int k0 = 0; k0 < K; k0 += 32) {
        if (GLL) {
            if (doA) {
                gll16(aSrcH + k0, dstAh);
                gll16(aSrcL + k0, dstAl);
            }
            gll16(bSrcH0 + k0, dstBh0);
            gll16(bSrcH1 + k0, dstBh1);
            gll16(bSrcL0 + k0, dstBl0);
            gll16(bSrcL1 + k0, dstBl1);
        } else {
            if (astage) {
                if (AMODE == 0) {
                    float vv[8];
                    if (avalid) {
                        float4 v0 = *(const float4*)&A[arow * lda + k0 + akc];
                        float4 v1 = *(const float4*)&A[arow * lda + k0 + akc + 4];
                        vv[0] = v0.x; vv[1] = v0.y; vv[2] = v0.z; vv[3] = v0.w;
                        vv[4] = v1.x; vv[5] = v1.y; vv[6] = v1.z; vv[7] = v1.w;
                    } else {
                        #pragma unroll
                        for (int e = 0; e < 8; ++e) vv[e] = 0.f;
                    }
                    union { unsigned short u[8]; u32x4 v; } ph, pl;
                    #pragma unroll
                    for (int e = 0; e < 8; ++e) {
                        unsigned short h = f2bf(vv[e]);
                        ph.u[e] = h;
                        pl.u[e] = f2bf(vv[e] - bf2f(h));
                    }
                    *(u32x4*)&Ah[ar * STR + akc] = ph.v;
                    *(u32x4*)&Al[ar * STR + akc] = pl.v;
                } else {
                    u32x4 zv = {0u, 0u, 0u, 0u};
                    u32x4 vh = zv, vl = zv;
                    if (avalid) {
                        vh = *(const u32x4*)&Ahi[arow * lda + k0 + akc];
                        vl = *(const u32x4*)&Alo[arow * lda + k0 + akc];
                    }
                    *(u32x4*)&Ah[ar * STR + akc] = vh;
                    *(u32x4*)&Al[ar * STR + akc] = vl;
                }
            }
            long long boff = (long long)(bn + bnr) * K + k0 + bkc;
            *(u32x4*)&Bh[bnr * STR + bkc]     = *(const u32x4*)&Bth[boff];
            *(u32x4*)&Bh[bnr * STR + bkc + 8] = *(const u32x4*)&Bth[boff + 8];
            *(u32x4*)&Bl[bnr * STR + bkc]     = *(const u32x4*)&Btl[boff];
            *(u32x4*)&Bl[bnr * STR + bkc + 8] = *(const u32x4*)&Btl[boff + 8];
        }
        __syncthreads();

        bf16x8 af[AI], alf[AI], bfj[4], blf[4];
        #pragma unroll
        for (int i = 0; i < AI; ++i) {
            int row = (MT == 64 ? wm * 32 + i * 16 : wm * 16) + fr;
            af[i]  = *(const bf16x8*)&Ah[row * STR + kg];
            alf[i] = *(const bf16x8*)&Al[row * STR + kg];
        }
        #pragma unroll
        for (int j = 0; j < 4; ++j) {
            int row = wn * 64 + j * 16 + fr;
            bfj[j] = *(const bf16x8*)&Bh[row * STR + kg];
            blf[j] = *(const bf16x8*)&Bl[row * STR + kg];
        }
        #pragma unroll
        for (int i = 0; i < AI; ++i)
        #pragma unroll
        for (int j = 0; j < 4; ++j) {
            acc[i][j] = __builtin_amdgcn_mfma_f32_16x16x32_bf16(af[i],  bfj[j], acc[i][j], 0, 0, 0);
            acc[i][j] = __builtin_amdgcn_mfma_f32_16x16x32_bf16(af[i],  blf[j], acc[i][j], 0, 0, 0);
            acc[i][j] = __builtin_amdgcn_mfma_f32_16x16x32_bf16(alf[i], bfj[j], acc[i][j], 0, 0, 0);
        }
        __syncthreads();
    }

    #pragma unroll
    for (int i = 0; i < AI; ++i) {
        int rbase = bm + (MT == 64 ? wm * 32 + i * 16 : wm * 16) + ((lane >> 4) << 2);
        #pragma unroll
        for (int j = 0; j < 4; ++j) {
            int ccol = bn + wn * 64 + j * 16 + fr;
            float bv = bias[ccol];
            #pragma unroll
            for (int r = 0; r < 4; ++r) {
                int row = rbase + r;
                if (row < M) {
                    float val = acc[i][j][r] + bv;
                    if (EPI == 1) val = mishf(val);
                    if (EPI == 2) val = fmaxf(val, 0.f);
                    if (SPLIT) {
                        unsigned short hh = f2bf(val);
                        unsigned short ll = f2bf(val - bf2f(hh));
                        if (ccol < nhl) {
                            Chi[(long long)row * ldhl + ccol] = hh;
                            Clo[(long long)row * ldhl + ccol] = ll;
                        } else {
                            int bb = row / 400, m = row - bb * 400;
                            long long vi = ((long long)(bb * 512 + (ccol - 1024))) * 416 + m;
                            vthi[vi] = hh;
                            vtlo[vi] = ll;
                        }
                    } else {
                        C[(long long)row * ldc + ccol] = val;
                    }
                }
            }
        }
    }
}

// ---------------------------------------------------------------------------
// Weight prep kernels (write-coalesced)
// ---------------------------------------------------------------------------
__global__ __launch_bounds__(256) void prep_wqkv(
    const float* __restrict__ wq, const float* __restrict__ wk,
    const float* __restrict__ wv,
    unsigned short* __restrict__ whi, unsigned short* __restrict__ wlo,
    int obase, int total)
{
    int idx = blockIdx.x * 256 + threadIdx.x;
    if (idx >= total) return;
    int o = obase + idx / 786432;
    int rem = idx % 786432;
    int n = rem >> 9, k = rem & 511;
    int sel = n >> 9, col = n & 511;
    const float* W = sel == 0 ? wq : (sel == 1 ? wk : wv);
    float v = W[(long long)o * 262144 + k * 512 + col];
    unsigned short h = f2bf(v);
    whi[idx] = h;
    wlo[idx] = f2bf(v - bf2f(h));
}

__global__ __launch_bounds__(256) void prep_woiw(
    const float* __restrict__ wo, const float* __restrict__ wi,
    const float* __restrict__ wout,
    unsigned short* __restrict__ whi, unsigned short* __restrict__ wlo,
    int obase, int total)
{
    int idx = blockIdx.x * 256 + threadIdx.x;
    if (idx >= total) return;
    int o = obase + idx / 655360;
    int rem = idx % 655360;
    float v;
    if (rem < 262144) {
        int n = rem >> 9, k = rem & 511;
        v = wo[(long long)o * 262144 + k * 512 + n];
    } else if (rem < 524288) {
        int nk = rem - 262144;
        int n = nk >> 9, k = nk & 511;
        v = wi[(long long)o * 262144 + k * 512 + n];
    } else {
        int nk = rem - 524288;
        int n = nk >> 9, k = nk & 511;   // n < 256
        v = wout[(long long)o * 131072 + k * 256 + n];
    }
    unsigned short h = f2bf(v);
    whi[idx] = h;
    wlo[idx] = f2bf(v - bf2f(h));
}

__global__ __launch_bounds__(256) void prep_wcnn(
    const float* __restrict__ w,
    unsigned short* __restrict__ whi, unsigned short* __restrict__ wlo)
{
    int idx = blockIdx.x * 256 + threadIdx.x;
    if (idx >= 256 * 768) return;
    int n = idx / 768, k = idx % 768;
    float v = w[k * 256 + n];
    unsigned short h = f2bf(v);
    whi[idx] = h;
    wlo[idx] = f2bf(v - bf2f(h));
}

// ---------------------------------------------------------------------------
// Fused setup
// ---------------------------------------------------------------------------
__global__ __launch_bounds__(256) void setup_kernel(
    const float* __restrict__ x,
    const float* __restrict__ bq, const float* __restrict__ bk,
    const float* __restrict__ bv,
    float* __restrict__ mk, int* __restrict__ relT, int* __restrict__ convidx,
    float* __restrict__ f1pad, float* __restrict__ bqkv,
    unsigned short* __restrict__ vt_hi, unsigned short* __restrict__ vt_lo,
    int nOrg)
{
    int i = blockIdx.x * 256 + threadIdx.x;
    if (i < 3200) {
        const float* xr = x + (long long)i * 128;
        mk[i] = xr[4];
        mk[3200 + i] = fmaxf(xr[2], xr[3]);
        mk[6400 + i] = xr[0];
        mk[9600 + i] = xr[1];
        convidx[i] = (i / 400) * 402 + (i % 400);
    }
    int j = i - 3200;
    if (j >= 0 && j < 799) {
        int rel = j - 399;
        int sgn = (rel > 0) - (rel < 0);
        int ab = (rel < 300 && rel > -300) ? 299 : (rel < 0 ? -rel : rel);
        long long bpos;
        if (ab <= 300) bpos = rel;
        else {
            double lp = ceil(log((double)ab / 300.0) / log(599.0 / 300.0) * 299.0) + 300.0;
            bpos = (long long)lp * sgn;
        }
        long long c2p = bpos + 600;
        c2p = c2p < 0 ? 0 : (c2p > 1199 ? 1199 : c2p);
        relT[j] = (int)c2p;
    }
    int k = i - 4000;
    if (k >= 0 && k < 4096) {
        int b = k >> 9, rem = k & 511;
        int row = b * 402 + (rem < 256 ? 0 : 401);
        f1pad[(long long)row * 256 + (rem & 255)] = 0.f;
    }
    int m = i - 8100;
    if (m >= 0 && m < 6144) {
        int o = m / 1536, n = m % 1536;
        float v;
        if (n < 512) v = bq[o * 512 + n];
        else if (n < 1024) v = bk[o * 512 + n - 512];
        else v = bv[o * 512 + n - 1024];
        bqkv[m] = v;
    }
    int v = i - 14244;
    if (v >= 0 && v < nOrg * 65536) {   // vt pad cols [400..416) zero, as u32
        int og = v >> 16, rem = v & 65535;
        int vb = rem & 32767;
        int row = vb >> 3, c = vb & 7;
        unsigned int* p = (unsigned int*)((rem < 32768) ? vt_hi : vt_lo);
        p[(long long)og * 851968 + row * 208 + 200 + c] = 0u;
    }
}

// ---------------------------------------------------------------------------
// LayerNorm, wave-per-row. Organ-batched (o = row/rpo). RES: split residual.
// OSPL: 1 -> write split hi/lo, 0 -> write f32.
// ---------------------------------------------------------------------------
template<bool RES, int HD, int OSPL>
__global__ __launch_bounds__(256) void ln2_kernel(
    const float* __restrict__ X,
    const unsigned short* __restrict__ Rhi, const unsigned short* __restrict__ Rlo,
    const float* __restrict__ g, const float* __restrict__ be,
    float* __restrict__ Y,
    unsigned short* __restrict__ Yhi, unsigned short* __restrict__ Ylo,
    int rows, int rpo)
{
    constexpr int EPL = HD / 64;
    int wv = threadIdx.x >> 6, lane = threadIdx.x & 63;
    long long row = (long long)blockIdx.x * 4 + wv;
    if (row >= rows) return;
    int o = (int)(row / rpo);
    long long rrow = row % rpo;
    const float* x = X + row * HD;
    float v[EPL];
    #pragma unroll
    for (int q = 0; q < EPL / 4; ++q) {
        float4 a = *(const float4*)&x[lane * EPL + q * 4];
        v[q*4+0] = a.x; v[q*4+1] = a.y; v[q*4+2] = a.z; v[q*4+3] = a.w;
        if (RES) {
            us4 rh = *(const us4*)&Rhi[rrow * HD + lane * EPL + q * 4];
            us4 rl = *(const us4*)&Rlo[rrow * HD + lane * EPL + q * 4];
            #pragma unroll
            for (int e = 0; e < 4; ++e) v[q*4+e] += bf2f(rh[e]) + bf2f(rl[e]);
        }
    }
    float s = 0.f;
    #pragma unroll
    for (int e = 0; e < EPL; ++e) s += v[e];
    #pragma unroll
    for (int d = 1; d < 64; d <<= 1) s += __shfl_xor(s, d, 64);
    float mean = s * (1.f / HD);
    float s2 = 0.f;
    #pragma unroll
    for (int e = 0; e < EPL; ++e) { float d0 = v[e] - mean; s2 += d0 * d0; }
    #pragma unroll
    for (int d = 1; d < 64; d <<= 1) s2 += __shfl_xor(s2, d, 64);
    float inv = 1.f / sqrtf(s2 * (1.f / HD) + 1e-7f);
    #pragma unroll
    for (int q = 0; q < EPL / 4; ++q) {
        int c = lane * EPL + q * 4;
        float4 gg = *(const float4*)&g[o * HD + c];
        float4 bb = *(const float4*)&be[o * HD + c];
        float ov[4];
        ov[0] = (v[q*4+0] - mean) * inv * gg.x + bb.x;
        ov[1] = (v[q*4+1] - mean) * inv * gg.y + bb.y;
        ov[2] = (v[q*4+2] - mean) * inv * gg.z + bb.z;
        ov[3] = (v[q*4+3] - mean) * inv * gg.w + bb.w;
        if (OSPL) {
            us4 ph, pl;
            #pragma unroll
            for (int e = 0; e < 4; ++e) {
                unsigned short hh = f2bf(ov[e]);
                ph[e] = hh;
                pl[e] = f2bf(ov[e] - bf2f(hh));
            }
            *(us4*)&Yhi[row * HD + c] = ph;
            *(us4*)&Ylo[row * HD + c] = pl;
        } else {
            float4 of; of.x = ov[0]; of.y = ov[1]; of.z = ov[2]; of.w = ov[3];
            *(float4*)&Y[row * HD + c] = of;
        }
    }
}

// ---------------------------------------------------------------------------
// MFMA fused disentangled flash attention (round 16): HI-ONLY operands.
// Q/K/V/bands/P all plain bf16 (hi) -> 22 MFMAs + 22 loads per tile (was
// 52+28); fp32 MFMA accumulation throughout; ctx still written hi/lo split.
// Single-wave blocks, straight-line clamped loads, zero barriers.
// Grid (25, 8, 8*nOrg), XCD-swizzled.
// ---------------------------------------------------------------------------
__global__ __launch_bounds__(64) void attn_kernel(
    const unsigned short* __restrict__ qk_hi, const unsigned short* __restrict__ qk_lo,
    const unsigned short* __restrict__ vt_hi, const unsigned short* __restrict__ vt_lo,
    const unsigned short* __restrict__ pkg_hi, const unsigned short* __restrict__ pkg_lo,
    const float* __restrict__ mask,
    unsigned short* __restrict__ ctxh, unsigned short* __restrict__ ctxl)
{
    const float scale = 0.07216878364870322f;       // 1/sqrt(64*3)
    const float NEGMIN = -3.402823466e38f;
    int lin = blockIdx.x + 25 * (blockIdx.y + 8 * blockIdx.z);
    int gz = gridDim.z;
    int xcd = lin & 7, within = lin >> 3;
    int g = within / 25, lt = within - g * 25;
    int combo = xcd * gz + g;
    int h = combo & 7, z = combo >> 3;
    int b = z & 7, o = z >> 3;
    qk_hi  += (long long)o * 3276800;
    vt_hi  += (long long)o * 1703936;
    pkg_hi += (long long)o * 818176;
    mask   += o * 3200;
    ctxh   += (long long)o * 1638400;
    ctxl   += (long long)o * 1638400;

    int l0 = lt * 16;
    int lane = threadIdx.x;
    int fr = lane & 15, kg8 = (lane >> 4) << 3, g4 = (lane >> 4) << 2;

    __shared__ float T2c[16 * 36];
    __shared__ float T3c[32 * 20];
    __shared__ unsigned short Sth[16 * 40];

    // Q frag (hi only), loaded once
    bf16x8 qf[2];
    {
        long long base = ((long long)(b * 400 + l0 + fr)) * 1024 + h * 64 + kg8;
        #pragma unroll
        for (int kk = 0; kk < 2; ++kk)
            qf[kk] = *(const bf16x8*)(qk_hi + base + kk * 32);
    }
    float wlv_r[4], ms[4], ls[4];
    #pragma unroll
    for (int r = 0; r < 4; ++r) {
        wlv_r[r] = mask[b * 400 + l0 + g4 + r];
        ms[r] = -INFINITY;
        ls[r] = 0.f;
    }
    f32x4 O[4] = {};
    long long vtbase = ((long long)(b * 512 + h * 64)) * 416;

    for (int mt = 0; mt < 13; ++mt) {
        int m0 = mt * 32;
        int D0 = l0 - m0 + 368;
        // ---- straight-line clamped load batch (all hi-only) ----
        bf16x8 kf[2][2];
        #pragma unroll
        for (int jf = 0; jf < 2; ++jf) {
            int kr = m0 + jf * 16 + fr;
            kr = kr < 400 ? kr : 399;
            long long base = ((long long)(b * 400 + kr)) * 1024 + 512 + h * 64 + kg8;
            #pragma unroll
            for (int kk = 0; kk < 2; ++kk)
                kf[jf][kk] = *(const bf16x8*)(qk_hi + base + kk * 32);
        }
        bf16x8 b2h[3][2], b3h[3][2];
        #pragma unroll
        for (int c = 0; c < 3; ++c) {
            int dd = D0 + c * 16 + fr;
            dd = dd < 0 ? 0 : (dd > 798 ? 798 : dd);
            long long base = (long long)dd * 1024 + h * 64 + kg8;
            #pragma unroll
            for (int kk = 0; kk < 2; ++kk) {
                b2h[c][kk] = *(const bf16x8*)(pkg_hi + base + 512 + kk * 32);
                b3h[c][kk] = *(const bf16x8*)(pkg_hi + base + kk * 32);
            }
        }
        bf16x8 vf[4];
        #pragma unroll
        for (int f = 0; f < 4; ++f) {
            long long a = vtbase + (long long)(f * 16 + fr) * 416 + m0 + kg8;
            vf[f] = *(const bf16x8*)&vt_hi[a];
        }
        float wm_c[2];
        #pragma unroll
        for (int cf = 0; cf < 2; ++cf) {
            int mg = m0 + cf * 16 + fr;
            mg = mg < 400 ? mg : 399;
            wm_c[cf] = mask[b * 400 + mg];
        }
        // ---- T1 = Q@K^T, T2 = Q@PKband^T ----
        __builtin_amdgcn_s_setprio(1);
        f32x4 aT1[2] = {};
        #pragma unroll
        for (int jf = 0; jf < 2; ++jf)
        #pragma unroll
        for (int kk = 0; kk < 2; ++kk)
            aT1[jf] = __builtin_amdgcn_mfma_f32_16x16x32_bf16(qf[kk], kf[jf][kk], aT1[jf], 0, 0, 0);
        f32x4 aT2[3] = {};
        #pragma unroll
        for (int c = 0; c < 3; ++c)
        #pragma unroll
        for (int kk = 0; kk < 2; ++kk)
            aT2[c] = __builtin_amdgcn_mfma_f32_16x16x32_bf16(qf[kk], b2h[c][kk], aT2[c], 0, 0, 0);
        // ---- T3 = K@PQband^T (4 (jf,c) combos) ----
        f32x4 aT3[2][2] = {};
        #pragma unroll
        for (int jf = 0; jf < 2; ++jf)
        #pragma unroll
        for (int ci = 0; ci < 2; ++ci) {
            int c = ci + (jf ^ 1);
            #pragma unroll
            for (int kk = 0; kk < 2; ++kk)
                aT3[jf][ci] = __builtin_amdgcn_mfma_f32_16x16x32_bf16(kf[jf][kk], b3h[c][kk], aT3[jf][ci], 0, 0, 0);
        }
        __builtin_amdgcn_s_setprio(0);
        // ---- banded scatter (in-wave LDS ordering, no barrier) ----
        #pragma unroll
        for (int c = 0; c < 3; ++c)
        #pragma unroll
        for (int r = 0; r < 4; ++r) {
            int i = g4 + r;
            int d = c * 16 + fr - i;
            if ((unsigned)d < 32u)
                T2c[i * 36 + d] = aT2[c][r];
        }
        #pragma unroll
        for (int jf = 0; jf < 2; ++jf)
        #pragma unroll
        for (int ci = 0; ci < 2; ++ci) {
            int c = ci + (jf ^ 1);
            #pragma unroll
            for (int r = 0; r < 4; ++r) {
                int j3 = jf * 16 + g4 + r;
                int d2 = c * 16 + fr + j3 - 31;
                if ((unsigned)d2 < 16u)
                    T3c[j3 * 20 + d2] = aT3[jf][ci][r];
            }
        }
        // ---- assemble scores ----
        float sc0[4], sc1[4];
        #pragma unroll
        for (int r = 0; r < 4; ++r) {
            int i = g4 + r;
            {
                int j = fr;
                bool jv = (m0 + j) < 400;
                sc0[r] = !jv ? -INFINITY :
                    ((wlv_r[r] != 0.f && wm_c[0] != 0.f) ?
                     (aT1[0][r] + T2c[i * 36 + 31 - j] + T3c[j * 20 + i]) * scale : NEGMIN);
            }
            {
                int j = 16 + fr;
                bool jv = (m0 + j) < 400;
                sc1[r] = !jv ? -INFINITY :
                    ((wlv_r[r] != 0.f && wm_c[1] != 0.f) ?
                     (aT1[1][r] + T2c[i * 36 + 31 - j] + T3c[j * 20 + i]) * scale : NEGMIN);
            }
        }
        // ---- wave-local flash softmax ----
        float corr[4];
        #pragma unroll
        for (int r = 0; r < 4; ++r) {
            float mx = fmaxf(sc0[r], sc1[r]);
            #pragma unroll
            for (int d = 1; d < 16; d <<= 1) mx = fmaxf(mx, __shfl_xor(mx, d, 64));
            float mn = fmaxf(ms[r], mx);
            corr[r] = __expf(ms[r] - mn);
            ms[r] = mn;
            float p0 = __expf(sc0[r] - mn), p1 = __expf(sc1[r] - mn);
            float rs = p0 + p1;
            #pragma unroll
            for (int d = 1; d < 16; d <<= 1) rs += __shfl_xor(rs, d, 64);
            ls[r] = ls[r] * corr[r] + rs;
            int i = g4 + r;
            Sth[i * 40 + fr] = f2bf(p0);
            Sth[i * 40 + 16 + fr] = f2bf(p1);
        }
        // ---- PV (P transposed via in-wave LDS, hi-only) ----
        #pragma unroll
        for (int f = 0; f < 4; ++f)
        #pragma unroll
        for (int r = 0; r < 4; ++r) O[f][r] *= corr[r];
        bf16x8 Pha = *(const bf16x8*)&Sth[fr * 40 + kg8];
        __builtin_amdgcn_s_setprio(1);
        #pragma unroll
        for (int f = 0; f < 4; ++f)
            O[f] = __builtin_amdgcn_mfma_f32_16x16x32_bf16(Pha, vf[f], O[f], 0, 0, 0);
        __builtin_amdgcn_s_setprio(0);
    }
    // ---- write ctx (split bf16 hi/lo); rows always valid ----
    #pragma unroll
    for (int f = 0; f < 4; ++f) {
        int colg = h * 64 + f * 16 + fr;
        #pragma unroll
        for (int r = 0; r < 4; ++r) {
            int lg = l0 + g4 + r;
            float val = O[f][r] / ls[r];
            long long idx = ((long long)(b * 400 + lg)) * 512 + colg;
            unsigned short hh = f2bf(val);
            ctxh[idx] = hh;
            ctxl[idx] = f2bf(val - bf2f(hh));
        }
    }
}

// ---------------------------------------------------------------------------
// Chunked pool / meanmax (full-chip), heads
// ---------------------------------------------------------------------------
__global__ __launch_bounds__(256) void pool_part(
    const float* __restrict__ in, long long inOStride,
    const float* __restrict__ mk, float* __restrict__ pp)
{
    int bi = blockIdx.x, c = blockIdx.y, t = threadIdx.x;
    int o = bi >> 3, b = bi & 7;
    int l0 = c * 31, l1 = min(400, l0 + 31);
    const float* ib = in + (long long)o * inOStride + (long long)(b * 400) * 256;
    const float* mkb = mk + o * 3200 + b * 400;
    float s = 0.f, mx = -INFINITY, sw = 0.f;
    for (int l = l0; l < l1; ++l) {
        float wv = mkb[l];
        float v = ib[(long long)l * 256 + t] * wv;
        s += v; mx = fmaxf(mx, v); sw += wv;
    }
    long long base = (long long)(c * gridDim.x + bi) * 514;
    pp[base + t] = s;
    pp[base + 256 + t] = mx;
    if (t == 0) pp[base + 512] = sw;
}

__global__ __launch_bounds__(256) void pool_merge(
    const float* __restrict__ pp, float* __restrict__ pooled, int nBI)
{
    int bi = blockIdx.x, t = threadIdx.x;
    float s = 0.f, mx = -INFINITY, sw = 0.f;
    for (int c = 0; c < 13; ++c) {
        long long base = (long long)(c * nBI + bi) * 514;
        s += pp[base + t];
        mx = fmaxf(mx, pp[base + 256 + t]);
        sw += pp[base + 512];
    }
    int o = bi >> 3, b = bi & 7;
    pooled[o * 4096 + b * 512 + t] = s / (sw + 1e-6f);
    pooled[o * 4096 + b * 512 + 256 + t] = mx;
}

__global__ __launch_bounds__(512) void mm_part(
    const unsigned short* __restrict__ fh, const unsigned short* __restrict__ fl,
    float* __restrict__ mmp)
{
    int b = blockIdx.x, c = blockIdx.y, t = threadIdx.x;
    int l0 = c * 31, l1 = min(400, l0 + 31);
    float s = 0.f, mx = -INFINITY;
    for (int l = l0; l < l1; ++l) {
        long long idx = ((long long)(b * 400 + l)) * 512 + t;
        float v = bf2f(fh[idx]) + bf2f(fl[idx]);
        s += v; mx = fmaxf(mx, v);
    }
    long long base = (long long)(c * 8 + b) * 1024;
    mmp[base + t] = s;
    mmp[base + 512 + t] = mx;
}

__global__ __launch_bounds__(512) void mm_merge(
    const float* __restrict__ mmp, float* __restrict__ mm)
{
    int b = blockIdx.x, t = threadIdx.x;
    float s = 0.f, mx = -INFINITY;
    for (int c = 0; c < 13; ++c) {
        long long base = (long long)(c * 8 + b) * 1024;
        s += mmp[base + t];
        mx = fmaxf(mx, mmp[base + 512 + t]);
    }
    mm[b * 1024 + t] = s / 400.f;
    mm[b * 1024 + 512 + t] = mx;
}

__global__ __launch_bounds__(256) void heads_kernel(
    const float* __restrict__ pooled, const float* __restrict__ mm,
    const float* __restrict__ w_bow1, const float* __restrict__ b_bow1,
    const float* __restrict__ w_bow2, const float* __restrict__ b_bow2,
    const float* __restrict__ w_ext1, const float* __restrict__ b_ext1,
    const float* __restrict__ w_ext2, const float* __restrict__ b_ext2,
    const float* __restrict__ w_org1, const float* __restrict__ b_org1,
    const float* __restrict__ w_org2, const float* __restrict__ b_org2,
    float* __restrict__ out)
{
    int b = blockIdx.x, role = blockIdx.y;
    int t = threadIdx.x;
    __shared__ float inb[1024];
    __shared__ float red[256];
    __shared__ float hid[256];
    if (role == 0) {
        inb[t] = pooled[b * 512 + t];
        inb[256 + t] = pooled[b * 512 + 256 + t];
        __syncthreads();
        float acc = b_bow1[t];
        for (int j = 0; j < 512; ++j) acc += inb[j] * w_bow1[j * 256 + t];
        red[t] = mishf(acc) * w_bow2[t];
        __syncthreads();
        for (int s = 128; s; s >>= 1) { if (t < s) red[t] += red[t + s]; __syncthreads(); }
        if (t == 0) out[b * 11 + 0] = red[0] + b_bow2[0];
    } else if (role == 1) {
        inb[t] = mm[b * 1024 + t];
        inb[256 + t] = mm[b * 1024 + 256 + t];
        inb[512 + t] = mm[b * 1024 + 512 + t];
        inb[768 + t] = mm[b * 1024 + 768 + t];
        __syncthreads();
        float acc = b_ext1[t];
        for (int j = 0; j < 1024; ++j) acc += inb[j] * w_ext1[j * 256 + t];
        red[t] = mishf(acc) * w_ext2[t];
        __syncthreads();
        for (int s = 128; s; s >>= 1) { if (t < s) red[t] += red[t + s]; __syncthreads(); }
        if (t == 0) { out[b * 11 + 1] = red[0] + b_ext2[0]; out[88 + b] = 0.f; }
    } else {
        int i = role - 2;
        inb[t] = pooled[((1 + i) * 8 + b) * 512 + t];
        inb[256 + t] = pooled[((1 + i) * 8 + b) * 512 + 256 + t];
        __syncthreads();
        float acc = b_org1[i * 256 + t];
        for (int j = 0; j < 512; ++j)
            acc += inb[j] * w_org1[((long long)i * 512 + j) * 256 + t];
        hid[t] = mishf(acc);
        __syncthreads();
        for (int c = 0; c < 3; ++c) {
            red[t] = hid[t] * w_org2[(i * 256 + t) * 3 + c];
            __syncthreads();
            for (int s = 128; s; s >>= 1) { if (t < s) red[t] += red[t + s]; __syncthreads(); }
            if (t == 0) out[b * 11 + 2 + i * 3 + c] = red[0] + b_org2[i * 3 + c];
            __syncthreads();
        }
    }
}

// ---------------------------------------------------------------------------
// Launch
// ---------------------------------------------------------------------------
extern "C" void kernel_launch(void* const* d_in, const int* in_sizes, int n_in,
                              void* d_out, int out_size, void* d_ws, size_t ws_size,
                              hipStream_t stream)
{
    const float* x      = (const float*)d_in[0];
    const float* w_mlp  = (const float*)d_in[1];
    const float* b_mlp  = (const float*)d_in[2];
    const float* w_cnn  = (const float*)d_in[3];
    const float* b_cnn  = (const float*)d_in[4];
    const float* rel_emb= (const float*)d_in[5];
    const float* rel_g  = (const float*)d_in[6];
    const float* rel_b  = (const float*)d_in[7];
    const float* wq     = (const float*)d_in[8];
    const float* wk     = (const float*)d_in[9];
    const float* wv     = (const float*)d_in[10];
    const float* wo     = (const float*)d_in[11];
    const float* wi     = (const float*)d_in[12];
    const float* bq     = (const float*)d_in[13];
    const float* bk     = (const float*)d_in[14];
    const float* bv     = (const float*)d_in[15];
    const float* bo     = (const float*)d_in[16];
    const float* bi     = (const float*)d_in[17];
    const float* wout   = (const float*)d_in[18];
    const float* bout   = (const float*)d_in[19];
    const float* ln1g   = (const float*)d_in[20];
    const float* ln1b   = (const float*)d_in[21];
    const float* ln2g   = (const float*)d_in[22];
    const float* ln2b   = (const float*)d_in[23];
    const float* w_bow1 = (const float*)d_in[24];
    const float* b_bow1 = (const float*)d_in[25];
    const float* w_bow2 = (const float*)d_in[26];
    const float* b_bow2 = (const float*)d_in[27];
    const float* w_ext1 = (const float*)d_in[28];
    const float* b_ext1 = (const float*)d_in[29];
    const float* w_ext2 = (const float*)d_in[30];
    const float* b_ext2 = (const float*)d_in[31];
    const float* w_org1 = (const float*)d_in[32];
    const float* b_org1 = (const float*)d_in[33];
    const float* w_org2 = (const float*)d_in[34];
    const float* b_org2 = (const float*)d_in[35];

    float* ws = (float*)d_ws;
    float* outf = (float*)d_out;
    const bool big = ws_size >= 143012736ull;

    if (big) {
        // ---------------- organ-batched path ----------------
        unsigned short* featsh = (unsigned short*)(ws + 0);        // 3200x512
        unsigned short* featsl = (unsigned short*)(ws + 819200);
        float* ctxR     = ws + 1638400;      // 6,553,600 fl
        float* f1pad    = ctxR;
        unsigned short* ctxh = (unsigned short*)ctxR;              // 4x3200x512
        unsigned short* ctxl = (unsigned short*)(ws + 4915200);
        float* qkA_f    = ws + 8192000;
        float* qkB_f    = ws + 14745600;
        unsigned short* qkA = (unsigned short*)qkA_f;
        unsigned short* qkB = (unsigned short*)qkB_f;
        unsigned short* rellnh = (unsigned short*)qkA_f;           // 4800x512
        unsigned short* rellnl = (unsigned short*)(ws + 8192000 + 1228800);
        unsigned short* vtA = (unsigned short*)(ws + 21299200);    // 4x4096x416
        unsigned short* vtB = (unsigned short*)(ws + 24707072);
        unsigned short* pkgA = (unsigned short*)(ws + 28114944);   // 4x799x1024
        unsigned short* pkgB = (unsigned short*)(ws + 29751296);
        unsigned short* whiA = (unsigned short*)(ws + 31387648);   // 4x786,432
        unsigned short* wloA = (unsigned short*)(ws + 32960512);
        unsigned short* wcnn_hi = (unsigned short*)(ws + 35188736);
        unsigned short* wcnn_lo = (unsigned short*)(ws + 35287040);
        float* bqkvb   = ws + 35385344;
        float* masksb  = ws + 35391488;
        float* pooledb = ws + 35404288;
        float* mmb     = ws + 35420672;
        int*   relidx  = (int*)(ws + 35428864);
        int*   convidx = (int*)(ws + 35429664);
        float* poolpart= ws + 35432864;
        float* mmpart  = ws + 35646688;
        float* tmp_all   = qkA_f;                                  // WO out (f32)
        unsigned short* h1h = (unsigned short*)qkB_f;              // LN1 out split
        unsigned short* h1l = (unsigned short*)(ws + 14745600 + 3276800);
        unsigned short* interh = (unsigned short*)qkA_f;           // WI out split
        unsigned short* interl = (unsigned short*)(ws + 8192000 + 3276800);
        float* outenc_all = (float*)vtA;                           // 4x819,200 f32
        float* outln_all  = ctxR;                                  // 4x819,200 f32
        unsigned short* whiB_all = whiA;
        unsigned short* wloB_all = wloA;

        gemm_bias<1><<<dim3(4, 50), 256, 0, stream>>>(
            x, w_mlp, b_mlp, f1pad, featsh, featsl, 3200, 256, 128, 512);
        setup_kernel<<<1080, 256, 0, stream>>>(x, bq, bk, bv, masksb, relidx, convidx,
                                               f1pad, bqkvb, vtA, vtB, 4);
        prep_wcnn<<<768, 256, 0, stream>>>(w_cnn, wcnn_hi, wcnn_lo);
        gemm_mfma<2, true, 0, true, 32, false><<<dim3(2, 100), 256, 0, stream>>>(
            f1pad, nullptr, nullptr, wcnn_hi, wcnn_lo, b_cnn, nullptr,
            3200, 768, 256, 0, convidx, featsh + 256, featsl + 256, 512, 1 << 30,
            nullptr, nullptr, 0, 0, 0, 0, 0, 0);

        ln2_kernel<false, 512, 1><<<1200, 256, 0, stream>>>(
            rel_emb, nullptr, nullptr, rel_g, rel_b, nullptr, rellnh, rellnl, 4800, 1200);
        prep_wqkv<<<12288, 256, 0, stream>>>(wq, wk, wv, whiA, wloA, 0, 3145728);
        gemm_mfma<0, true, 1, true, 64, true><<<dim3(8, 13, 4), 256, 0, stream>>>(
            nullptr, rellnh, rellnl, whiA, wloA, bqkvb, nullptr, 799, 512, 512, 0, relidx,
            pkgA, pkgB, 1024, 1024, nullptr, nullptr,
            614400, 786432, 1536, 0, 818176, 0);
        gemm_mfma<0, false, 1, true, 64, true><<<dim3(12, 50, 4), 256, 0, stream>>>(
            nullptr, featsh, featsl, whiA, wloA, bqkvb, nullptr, 3200, 512, 512, 0, nullptr,
            qkA, qkB, 1024, 1024, vtA, vtB,
            0, 786432, 1536, 0, 3276800, 1703936);
        prep_woiw<<<10240, 256, 0, stream>>>(wo, wi, wout, whiB_all, wloB_all,
                                             0, 2621440);
        attn_kernel<<<dim3(25, 8, 32), 64, 0, stream>>>(qkA, qkB, vtA, vtB,
            pkgA, pkgB, masksb, ctxh, ctxl);
        gemm_mfma<0, false, 1, false, 32, true><<<dim3(4, 100, 4), 256, 0, stream>>>(
            nullptr, ctxh, ctxl, whiB_all, wloB_all, bo, tmp_all,
            3200, 512, 512, 512, nullptr, nullptr, nullptr, 0, 0, nullptr, nullptr,
            1638400, 655360, 512, 1638400, 0, 0);
        ln2_kernel<true, 512, 1><<<3200, 256, 0, stream>>>(
            tmp_all, featsh, featsl, ln1g, ln1b, nullptr, h1h, h1l, 12800, 3200);
        gemm_mfma<1, false, 1, true, 32, true><<<dim3(4, 100, 4), 256, 0, stream>>>(
            nullptr, h1h, h1l, whiB_all + 262144, wloB_all + 262144, bi, nullptr,
            3200, 512, 512, 0, nullptr, interh, interl, 512, 1 << 30, nullptr, nullptr,
            1638400, 655360, 512, 0, 1638400, 0);
        gemm_mfma<0, false, 1, false, 32, true><<<dim3(2, 100, 4), 256, 0, stream>>>(
            nullptr, interh, interl, whiB_all + 524288, wloB_all + 524288, bout, outenc_all,
            3200, 512, 512, 256, nullptr, nullptr, nullptr, 0, 0, nullptr, nullptr,
            1638400, 655360, 256, 819200, 0, 0);
        ln2_kernel<false, 256, 0><<<3200, 256, 0, stream>>>(
            outenc_all, nullptr, nullptr, ln2g, ln2b, outln_all, nullptr, nullptr,
            12800, 3200);

        pool_part<<<dim3(32, 13), 256, 0, stream>>>(outln_all, 819200, masksb, poolpart);
        pool_merge<<<32, 256, 0, stream>>>(poolpart, pooledb, 32);
        mm_part<<<dim3(8, 13), 512, 0, stream>>>(featsh, featsl, mmpart);
        mm_merge<<<8, 512, 0, stream>>>(mmpart, mmb);
        heads_kernel<<<dim3(8, 5), 256, 0, stream>>>(pooledb, mmb,
            w_bow1, b_bow1, w_bow2, b_bow2, w_ext1, b_ext1, w_ext2, b_ext2,
            w_org1, b_org1, w_org2, b_org2, outf);
        return;
    }

    // ---------------- per-organ fallback path ----------------
    unsigned short* featsh = (unsigned short*)(ws + 0);
    unsigned short* featsl = (unsigned short*)(ws + 819200);
    float* ctxR    = ws + 1638400;
    float* f1pad   = ctxR;
    unsigned short* ctxh = (unsigned short*)ctxR;
    unsigned short* ctxl = (unsigned short*)(ws + 1638400 + 819200);
    float* qkvA_f  = ws + 3276800;
    float* qkvB_f  = ws + 4915200;
    unsigned short* qkv_hi = (unsigned short*)qkvA_f;
    unsigned short* qkv_lo = (unsigned short*)qkvB_f;
    unsigned short* rellnh = (unsigned short*)qkvB_f;
    unsigned short* rellnl = (unsigned short*)(ws + 4915200 + 307200);
    unsigned short* pkg_hi = (unsigned short*)(ws + 6553600);
    unsigned short* pkg_lo = (unsigned short*)(ws + 6963200);
    unsigned short* vt_hi  = (unsigned short*)(ws + 7372800);
    unsigned short* vt_lo  = (unsigned short*)(ws + 8224768);
    unsigned short* whi    = (unsigned short*)(ws + 9076736);
    unsigned short* wlo    = (unsigned short*)(ws + 9469952);
    float* bqkvb   = ws + 9863168;
    float* masksb  = ws + 9869312;
    float* pooledb = ws + 9882112;
    float* mmb     = ws + 9898496;
    int*   relidx  = (int*)(ws + 9906688);
    unsigned short* wcnn_hi = (unsigned short*)(ws + 9907488);
    unsigned short* wcnn_lo = (unsigned short*)(ws + 10005792);
    int*   convidx = (int*)(ws + 10104096);
    float* poolpart= ws + 10107296;
    float* mmpart  = ws + 10160752;
    float* tmp     = qkvA_f;
    unsigned short* h1h = (unsigned short*)qkvB_f;
    unsigned short* h1l = (unsigned short*)(ws + 4915200 + 819200);
    unsigned short* interh = (unsigned short*)qkvA_f;
    unsigned short* interl = (unsigned short*)(ws + 3276800 + 819200);
    float* outenc  = (float*)vt_hi;
    float* outln   = ctxR;

    gemm_bias<1><<<dim3(4, 50), 256, 0, stream>>>(
        x, w_mlp, b_mlp, f1pad, featsh, featsl, 3200, 256, 128, 512);
    setup_kernel<<<312, 256, 0, stream>>>(x, bq, bk, bv, masksb, relidx, convidx,
                                          f1pad, bqkvb, vt_hi, vt_lo, 1);
    prep_wcnn<<<768, 256, 0, stream>>>(w_cnn, wcnn_hi, wcnn_lo);
    gemm_mfma<2, true, 0, true, 32, false><<<dim3(2, 100), 256, 0, stream>>>(
        f1pad, nullptr, nullptr, wcnn_hi, wcnn_lo, b_cnn, nullptr,
        3200, 768, 256, 0, convidx, featsh + 256, featsl + 256, 512, 1 << 30,
        nullptr, nullptr, 0, 0, 0, 0, 0, 0);

    for (int o = 0; o < 4; ++o) {
        ln2_kernel<false, 512, 1><<<300, 256, 0, stream>>>(
            rel_emb + (long long)o * 614400, nullptr, nullptr,
            rel_g + o * 512, rel_b + o * 512, nullptr, rellnh, rellnl, 1200, 1200);
        prep_wqkv<<<3072, 256, 0, stream>>>(wq, wk, wv, whi, wlo, o, 786432);
        gemm_mfma<0, true, 1, true, 64, true><<<dim3(8, 13), 256, 0, stream>>>(
            nullptr, rellnh, rellnl, whi, wlo, bqkvb + o * 1536, nullptr,
            799, 512, 512, 0, relidx, pkg_hi, pkg_lo, 1024, 1024, nullptr, nullptr,
            0, 0, 0, 0, 0, 0);
        gemm_mfma<0, false, 1, true, 64, true><<<dim3(12, 50), 256, 0, stream>>>(
            nullptr, featsh, featsl, whi, wlo, bqkvb + o * 1536, nullptr,
            3200, 512, 512, 0, nullptr, qkv_hi, qkv_lo, 1024, 1024, vt_hi, vt_lo,
            0, 0, 0, 0, 0, 0);
        prep_woiw<<<2560, 256, 0, stream>>>(wo, wi, wout, whi, wlo, o, 655360);
        attn_kernel<<<dim3(25, 8, 8), 64, 0, stream>>>(qkv_hi, qkv_lo, vt_hi, vt_lo,
            pkg_hi, pkg_lo, masksb + o * 3200, ctxh, ctxl);
        gemm_mfma<0, false, 1, false, 32, true><<<dim3(4, 100), 256, 0, stream>>>(
            nullptr, ctxh, ctxl, whi, wlo, bo + o * 512, tmp,
            3200, 512, 512, 512, nullptr, nullptr, nullptr, 0, 0, nullptr, nullptr,
            0, 0, 0, 0, 0, 0);
        ln2_kernel<true, 512, 1><<<800, 256, 0, stream>>>(
            tmp, featsh, featsl, ln1g + o * 512, ln1b + o * 512, nullptr,
            h1h, h1l, 3200, 3200);
        gemm_mfma<1, false, 1, true, 32, true><<<dim3(4, 100), 256, 0, stream>>>(
            nullptr, h1h, h1l, whi + 262144, wlo + 262144, bi + o * 512, nullptr,
            3200, 512, 512, 0, nullptr, interh, interl, 512, 1 << 30, nullptr, nullptr,
            0, 0, 0, 0, 0, 0);
        gemm_mfma<0, false, 1, false, 32, true><<<dim3(2, 100), 256, 0, stream>>>(
            nullptr, interh, interl, whi + 524288, wlo + 524288, bout + o * 256, outenc,
            3200, 512, 512, 256, nullptr, nullptr, nullptr, 0, 0, nullptr, nullptr,
            0, 0, 0, 0, 0, 0);
        ln2_kernel<false, 256, 0><<<800, 256, 0, stream>>>(
            outenc, nullptr, nullptr, ln2g + o * 256, ln2b + o * 256, outln,
            nullptr, nullptr, 3200, 3200);
        pool_part<<<dim3(8, 13), 256, 0, stream>>>(outln, 0,
                                                   masksb + o * 3200, poolpart);
        pool_merge<<<8, 256, 0, stream>>>(poolpart, pooledb + o * 4096, 8);
    }

    mm_part<<<dim3(8, 13), 512, 0, stream>>>(featsh, featsl, mmpart);
    mm_merge<<<8, 512, 0, stream>>>(mmpart, mmb);
    heads_kernel<<<dim3(8, 5), 256, 0, stream>>>(pooledb, mmb,
        w_bow1, b_bow1, w_bow2, b_bow2, w_ext1, b_ext1, w_ext2, b_ext2,
        w_org1, b_org1, w_org2, b_org2, outf);
}

// Round 17
// 551.802 us; speedup vs baseline: 1.3104x; 1.1212x over previous
//
#include <hip/hip_runtime.h>
#include <math.h>

// ---------------------------------------------------------------------------
// Model dims (fixed): B=8 L=400 F=128 D=256 T=256 H=512 NH=8 HD=64 P=1200
// ---------------------------------------------------------------------------

typedef __attribute__((ext_vector_type(8))) short bf16x8;
typedef __attribute__((ext_vector_type(4))) float f32x4;
typedef __attribute__((ext_vector_type(4))) unsigned int u32x4;
typedef __attribute__((ext_vector_type(4))) unsigned short us4;

__device__ __forceinline__ float mishf(float x) {
    float sp = fmaxf(x, 0.f) + log1pf(expf(-fabsf(x)));   // stable softplus
    return x * tanhf(sp);
}

__device__ __forceinline__ unsigned short f2bf(float f) {
    unsigned int u = __float_as_uint(f);
    u = (u + 0x7fffu + ((u >> 16) & 1u)) >> 16;           // RNE
    return (unsigned short)u;
}
__device__ __forceinline__ float bf2f(unsigned short h) {
    return __uint_as_float(((unsigned int)h) << 16);
}

// async global->LDS 16B per lane; dst is wave-uniform base (+ lane*16 in HW)
__device__ __forceinline__ void gll16(const unsigned short* g, unsigned short* l) {
    __builtin_amdgcn_global_load_lds(
        (const __attribute__((address_space(1))) void*)g,
        (__attribute__((address_space(3))) void*)l, 16, 0, 0);
}

// ---------------------------------------------------------------------------
// fp32 GEMM (front MLP, K=128): writes f1pad (padded conv layout) + split
// bf16 hi/lo feats (cols 0..255 of 512-wide).
// ---------------------------------------------------------------------------
template<int EPI>
__global__ __launch_bounds__(256) void gemm_bias(
    const float* __restrict__ A, const float* __restrict__ Bm,
    const float* __restrict__ bias, float* __restrict__ C2,
    unsigned short* __restrict__ fhi, unsigned short* __restrict__ flo,
    int M, int N, int K, int ldc)
{
    __shared__ float As[16][68];
    __shared__ float Bs[16][68];
    int bm = blockIdx.y << 6, bn = blockIdx.x << 6;
    int tid = threadIdx.x;
    int tm = (tid >> 4) << 2, tn = (tid & 15) << 2;
    int ar = tid >> 2, ac4 = (tid & 3) << 2;
    int br = tid >> 4, bc4 = (tid & 15) << 2;
    float acc[4][4] = {};
    for (int k0 = 0; k0 < K; k0 += 16) {
        float4 av = make_float4(0.f, 0.f, 0.f, 0.f);
        if (bm + ar < M)
            av = *(const float4*)&A[(long long)(bm + ar) * K + k0 + ac4];
        As[ac4][ar] = av.x; As[ac4 + 1][ar] = av.y;
        As[ac4 + 2][ar] = av.z; As[ac4 + 3][ar] = av.w;
        *(float4*)&Bs[br][bc4] =
            *(const float4*)&Bm[(long long)(k0 + br) * N + bn + bc4];
        __syncthreads();
        #pragma unroll
        for (int kk = 0; kk < 16; ++kk) {
            float4 a4 = *(const float4*)&As[kk][tm];
            float4 b4 = *(const float4*)&Bs[kk][tn];
            acc[0][0] += a4.x * b4.x; acc[0][1] += a4.x * b4.y;
            acc[0][2] += a4.x * b4.z; acc[0][3] += a4.x * b4.w;
            acc[1][0] += a4.y * b4.x; acc[1][1] += a4.y * b4.y;
            acc[1][2] += a4.y * b4.z; acc[1][3] += a4.y * b4.w;
            acc[2][0] += a4.z * b4.x; acc[2][1] += a4.z * b4.y;
            acc[2][2] += a4.z * b4.z; acc[2][3] += a4.z * b4.w;
            acc[3][0] += a4.w * b4.x; acc[3][1] += a4.w * b4.y;
            acc[3][2] += a4.w * b4.z; acc[3][3] += a4.w * b4.w;
        }
        __syncthreads();
    }
    #pragma unroll
    for (int i = 0; i < 4; ++i) {
        int r = bm + tm + i;
        if (r < M) {
            float v[4];
            #pragma unroll
            for (int q = 0; q < 4; ++q) {
                v[q] = acc[i][q] + bias[bn + tn + q];
                if (EPI == 1) v[q] = mishf(v[q]);
            }
            float4 o; o.x = v[0]; o.y = v[1]; o.z = v[2]; o.w = v[3];
            int rr2 = (r / 400) * 402 + (r % 400) + 1;
            *(float4*)&C2[(long long)rr2 * 256 + bn + tn] = o;
            us4 ph, pl;
            #pragma unroll
            for (int q = 0; q < 4; ++q) {
                unsigned short hh = f2bf(v[q]);
                ph[q] = hh;
                pl[q] = f2bf(v[q] - bf2f(hh));
            }
            *(us4*)&fhi[(long long)r * ldc + bn + tn] = ph;
            *(us4*)&flo[(long long)r * ldc + bn + tn] = pl;
        }
    }
}

// ---------------------------------------------------------------------------
// MFMA bf16 GEMM. B pre-transposed+split [N][K] bf16 hi/lo.
// AMODE: 0 = A fp32 (split per tile), 1 = A pre-split hi/lo.
// XLV: 3 = x3-split (fp32-accurate), 1 = hi-only single MFMA.
// GLL: stage A/B via global_load_lds (async, unpadded stride-32 LDS).
// SPLIT out: cols<nhl -> Chi(/Clo if OUTLO); cols>=1024 -> V transposed (416).
// EPI: 0 none, 1 mish, 2 relu.
// ---------------------------------------------------------------------------
template<int EPI, bool GATHER, int AMODE, bool SPLIT, int MT, bool GLL,
         int XLV, bool OUTLO>
__global__ __launch_bounds__(256) void gemm_mfma(
    const float* __restrict__ A,
    const unsigned short* __restrict__ Ahi, const unsigned short* __restrict__ Alo,
    const unsigned short* __restrict__ Bth, const unsigned short* __restrict__ Btl,
    const float* __restrict__ bias, float* __restrict__ C,
    int M, int K, int lda, int ldc, const int* __restrict__ gidx,
    unsigned short* __restrict__ Chi, unsigned short* __restrict__ Clo,
    int ldhl, int nhl,
    unsigned short* __restrict__ vthi, unsigned short* __restrict__ vtlo,
    long long zA, int zB, int zBias, int zC, int zChi, int zVt)
{
    constexpr int AI = MT / 32;
    constexpr int STR = GLL ? 32 : 40;
    __shared__ unsigned short Ah[MT * STR];
    __shared__ unsigned short Al[(XLV == 3) ? MT * STR : 16];
    __shared__ unsigned short Bh[128 * STR];
    __shared__ unsigned short Bl[(XLV == 3) ? 128 * STR : 16];

    long long zz = blockIdx.z;
    if (AMODE == 0) A += zz * zA;
    else { Ahi += zz * zA; Alo += zz * zA; }
    Bth  += zz * (long long)zB;  Btl += zz * (long long)zB;
    bias += zz * (long long)zBias;
    C    += zz * (long long)zC;
    if (SPLIT) {
        Chi += zz * (long long)zChi; Clo += zz * (long long)zChi;
        vthi += zz * (long long)zVt; vtlo += zz * (long long)zVt;
    }

    int bm = blockIdx.y * MT, bn = blockIdx.x << 7;
    int tid = threadIdx.x;
    int lane = tid & 63, wid = tid >> 6;
    int wm = wid >> 1, wn = wid & 1;
    int fr = lane & 15, kg = (lane >> 4) << 3;

    // ---- GLL staging descriptors (wave-uniform dst, per-lane src) ----
    const unsigned short *aSrcH = nullptr, *aSrcL = nullptr;
    const unsigned short *bSrcH0 = nullptr, *bSrcL0 = nullptr;
    const unsigned short *bSrcH1 = nullptr, *bSrcL1 = nullptr;
    unsigned short *dstAh = nullptr, *dstAl = nullptr;
    unsigned short *dstBh0 = nullptr, *dstBl0 = nullptr;
    unsigned short *dstBh1 = nullptr, *dstBl1 = nullptr;
    bool doA = false;
    if (GLL) {
        int seg = (lane & 3) << 3;
        if (wid < MT / 16) {
            doA = true;
            int grow = bm + wid * 16 + (lane >> 2);
            grow = grow < M ? grow : (M - 1);
            long long arw = GATHER ? (long long)gidx[grow] : (long long)grow;
            aSrcH = Ahi + arw * lda + seg;
            aSrcL = Alo + arw * lda + seg;
            dstAh = &Ah[wid * 512];
            dstAl = &Al[(XLV == 3) ? wid * 512 : 0];
        }
        int br0 = bn + wid * 16 + (lane >> 2);
        int br1 = bn + (4 + wid) * 16 + (lane >> 2);
        bSrcH0 = Bth + (long long)br0 * K + seg;
        bSrcH1 = Bth + (long long)br1 * K + seg;
        bSrcL0 = Btl + (long long)br0 * K + seg;
        bSrcL1 = Btl + (long long)br1 * K + seg;
        dstBh0 = &Bh[wid * 512];       dstBh1 = &Bh[(4 + wid) * 512];
        dstBl0 = &Bl[(XLV == 3) ? wid * 512 : 0];
        dstBl1 = &Bl[(XLV == 3) ? (4 + wid) * 512 : 0];
    }

    // ---- legacy staging coords (non-GLL) ----
    int ar = tid >> 2, akc = (tid & 3) << 3;
    int bnr = tid >> 1, bkc = (tid & 1) << 4;
    bool astage = ar < MT;
    long long arow = 0; bool avalid = false;
    if (!GLL && astage) {
        int gr = bm + ar;
        avalid = gr < M;
        if (GATHER) arow = avalid ? (long long)gidx[gr] : 0;
        else        arow = avalid ? (long long)gr : 0;
    }

    f32x4 acc[AI][4] = {};

    for (int k0 = 0; k0 < K; k0 += 32) {
        if (GLL) {
            if (doA) {
                gll16(aSrcH + k0, dstAh);
                if (XLV == 3) gll16(aSrcL + k0, dstAl);
            }
            gll16(bSrcH0 + k0, dstBh0);
            gll16(bSrcH1 + k0, dstBh1);
            if (XLV == 3) {
                gll16(bSrcL0 + k0, dstBl0);
                gll16(bSrcL1 + k0, dstBl1);
            }
        } else {
            if (astage) {
                if (AMODE == 0) {
                    float vv[8];
                    if (avalid) {
                        float4 v0 = *(const float4*)&A[arow * lda + k0 + akc];
                        float4 v1 = *(const float4*)&A[arow * lda + k0 + akc + 4];
                        vv[0] = v0.x; vv[1] = v0.y; vv[2] = v0.z; vv[3] = v0.w;
                        vv[4] = v1.x; vv[5] = v1.y; vv[6] = v1.z; vv[7] = v1.w;
                    } else {
                        #pragma unroll
                        for (int e = 0; e < 8; ++e) vv[e] = 0.f;
                    }
                    union { unsigned short u[8]; u32x4 v; } ph, pl;
                    #pragma unroll
                    for (int e = 0; e < 8; ++e) {
                        unsigned short h = f2bf(vv[e]);
                        ph.u[e] = h;
                        pl.u[e] = f2bf(vv[e] - bf2f(h));
                    }
                    *(u32x4*)&Ah[ar * STR + akc] = ph.v;
                    if (XLV == 3) *(u32x4*)&Al[ar * STR + akc] = pl.v;
                } else {
                    u32x4 zv = {0u, 0u, 0u, 0u};
                    u32x4 vh = zv, vl = zv;
                    if (avalid) {
                        vh = *(const u32x4*)&Ahi[arow * lda + k0 + akc];
                        if (XLV == 3) vl = *(const u32x4*)&Alo[arow * lda + k0 + akc];
                    }
                    *(u32x4*)&Ah[ar * STR + akc] = vh;
                    if (XLV == 3) *(u32x4*)&Al[ar * STR + akc] = vl;
                }
            }
            long long boff = (long long)(bn + bnr) * K + k0 + bkc;
            *(u32x4*)&Bh[bnr * STR + bkc]     = *(const u32x4*)&Bth[boff];
            *(u32x4*)&Bh[bnr * STR + bkc + 8] = *(const u32x4*)&Bth[boff + 8];
            if (XLV == 3) {
                *(u32x4*)&Bl[bnr * STR + bkc]     = *(const u32x4*)&Btl[boff];
                *(u32x4*)&Bl[bnr * STR + bkc + 8] = *(const u32x4*)&Btl[boff + 8];
            }
        }
        __syncthreads();

        bf16x8 af[AI], alf[AI], bfj[4], blf[4];
        #pragma unroll
        for (int i = 0; i < AI; ++i) {
            int row = (MT == 64 ? wm * 32 + i * 16 : wm * 16) + fr;
            af[i]  = *(const bf16x8*)&Ah[row * STR + kg];
            if (XLV == 3) alf[i] = *(const bf16x8*)&Al[row * STR + kg];
        }
        #pragma unroll
        for (int j = 0; j < 4; ++j) {
            int row = wn * 64 + j * 16 + fr;
            bfj[j] = *(const bf16x8*)&Bh[row * STR + kg];
            if (XLV == 3) blf[j] = *(const bf16x8*)&Bl[row * STR + kg];
        }
        #pragma unroll
        for (int i = 0; i < AI; ++i)
        #pragma unroll
        for (int j = 0; j < 4; ++j) {
            acc[i][j] = __builtin_amdgcn_mfma_f32_16x16x32_bf16(af[i], bfj[j], acc[i][j], 0, 0, 0);
            if (XLV == 3) {
                acc[i][j] = __builtin_amdgcn_mfma_f32_16x16x32_bf16(af[i],  blf[j], acc[i][j], 0, 0, 0);
                acc[i][j] = __builtin_amdgcn_mfma_f32_16x16x32_bf16(alf[i], bfj[j], acc[i][j], 0, 0, 0);
            }
        }
        __syncthreads();
    }

    #pragma unroll
    for (int i = 0; i < AI; ++i) {
        int rbase = bm + (MT == 64 ? wm * 32 + i * 16 : wm * 16) + ((lane >> 4) << 2);
        #pragma unroll
        for (int j = 0; j < 4; ++j) {
            int ccol = bn + wn * 64 + j * 16 + fr;
            float bv = bias[ccol];
            #pragma unroll
            for (int r = 0; r < 4; ++r) {
                int row = rbase + r;
                if (row < M) {
                    float val = acc[i][j][r] + bv;
                    if (EPI == 1) val = mishf(val);
                    if (EPI == 2) val = fmaxf(val, 0.f);
                    if (SPLIT) {
                        unsigned short hh = f2bf(val);
                        if (ccol < nhl) {
                            Chi[(long long)row * ldhl + ccol] = hh;
                            if (OUTLO)
                                Clo[(long long)row * ldhl + ccol] = f2bf(val - bf2f(hh));
                        } else {
                            int bb = row / 400, m = row - bb * 400;
                            long long vi = ((long long)(bb * 512 + (ccol - 1024))) * 416 + m;
                            vthi[vi] = hh;
                            if (OUTLO)
                                vtlo[vi] = f2bf(val - bf2f(hh));
                        }
                    } else {
                        C[(long long)row * ldc + ccol] = val;
                    }
                }
            }
        }
    }
}

// ---------------------------------------------------------------------------
// Weight prep kernels (write-coalesced). wloEn: write lo half.
// ---------------------------------------------------------------------------
__global__ __launch_bounds__(256) void prep_wqkv(
    const float* __restrict__ wq, const float* __restrict__ wk,
    const float* __restrict__ wv,
    unsigned short* __restrict__ whi, unsigned short* __restrict__ wlo,
    int obase, int total, int wloEn)
{
    int idx = blockIdx.x * 256 + threadIdx.x;
    if (idx >= total) return;
    int o = obase + idx / 786432;
    int rem = idx % 786432;
    int n = rem >> 9, k = rem & 511;
    int sel = n >> 9, col = n & 511;
    const float* W = sel == 0 ? wq : (sel == 1 ? wk : wv);
    float v = W[(long long)o * 262144 + k * 512 + col];
    unsigned short h = f2bf(v);
    whi[idx] = h;
    if (wloEn) wlo[idx] = f2bf(v - bf2f(h));
}

__global__ __launch_bounds__(256) void prep_woiw(
    const float* __restrict__ wo, const float* __restrict__ wi,
    const float* __restrict__ wout,
    unsigned short* __restrict__ whi, unsigned short* __restrict__ wlo,
    int obase, int total)
{
    int idx = blockIdx.x * 256 + threadIdx.x;
    if (idx >= total) return;
    int o = obase + idx / 655360;
    int rem = idx % 655360;
    float v;
    if (rem < 262144) {
        int n = rem >> 9, k = rem & 511;
        v = wo[(long long)o * 262144 + k * 512 + n];
    } else if (rem < 524288) {
        int nk = rem - 262144;
        int n = nk >> 9, k = nk & 511;
        v = wi[(long long)o * 262144 + k * 512 + n];
    } else {
        int nk = rem - 524288;
        int n = nk >> 9, k = nk & 511;   // n < 256
        v = wout[(long long)o * 131072 + k * 256 + n];
    }
    unsigned short h = f2bf(v);
    whi[idx] = h;
    wlo[idx] = f2bf(v - bf2f(h));
}

__global__ __launch_bounds__(256) void prep_wcnn(
    const float* __restrict__ w,
    unsigned short* __restrict__ whi, unsigned short* __restrict__ wlo)
{
    int idx = blockIdx.x * 256 + threadIdx.x;
    if (idx >= 256 * 768) return;
    int n = idx / 768, k = idx % 768;
    float v = w[k * 256 + n];
    unsigned short h = f2bf(v);
    whi[idx] = h;
    wlo[idx] = f2bf(v - bf2f(h));
}

// ---------------------------------------------------------------------------
// Fused setup
// ---------------------------------------------------------------------------
__global__ __launch_bounds__(256) void setup_kernel(
    const float* __restrict__ x,
    const float* __restrict__ bq, const float* __restrict__ bk,
    const float* __restrict__ bv,
    float* __restrict__ mk, int* __restrict__ relT, int* __restrict__ convidx,
    float* __restrict__ f1pad, float* __restrict__ bqkv,
    unsigned short* __restrict__ vt_hi, unsigned short* __restrict__ vt_lo,
    int nOrg)
{
    int i = blockIdx.x * 256 + threadIdx.x;
    if (i < 3200) {
        const float* xr = x + (long long)i * 128;
        mk[i] = xr[4];
        mk[3200 + i] = fmaxf(xr[2], xr[3]);
        mk[6400 + i] = xr[0];
        mk[9600 + i] = xr[1];
        convidx[i] = (i / 400) * 402 + (i % 400);
    }
    int j = i - 3200;
    if (j >= 0 && j < 799) {
        int rel = j - 399;
        int sgn = (rel > 0) - (rel < 0);
        int ab = (rel < 300 && rel > -300) ? 299 : (rel < 0 ? -rel : rel);
        long long bpos;
        if (ab <= 300) bpos = rel;
        else {
            double lp = ceil(log((double)ab / 300.0) / log(599.0 / 300.0) * 299.0) + 300.0;
            bpos = (long long)lp * sgn;
        }
        long long c2p = bpos + 600;
        c2p = c2p < 0 ? 0 : (c2p > 1199 ? 1199 : c2p);
        relT[j] = (int)c2p;
    }
    int k = i - 4000;
    if (k >= 0 && k < 4096) {
        int b = k >> 9, rem = k & 511;
        int row = b * 402 + (rem < 256 ? 0 : 401);
        f1pad[(long long)row * 256 + (rem & 255)] = 0.f;
    }
    int m = i - 8100;
    if (m >= 0 && m < 6144) {
        int o = m / 1536, n = m % 1536;
        float v;
        if (n < 512) v = bq[o * 512 + n];
        else if (n < 1024) v = bk[o * 512 + n - 512];
        else v = bv[o * 512 + n - 1024];
        bqkv[m] = v;
    }
    int v = i - 14244;
    if (v >= 0 && v < nOrg * 65536) {   // vt pad cols [400..416) zero, as u32
        int og = v >> 16, rem = v & 65535;
        int vb = rem & 32767;
        int row = vb >> 3, c = vb & 7;
        unsigned int* p = (unsigned int*)((rem < 32768) ? vt_hi : vt_lo);
        p[(long long)og * 851968 + row * 208 + 200 + c] = 0u;
    }
}

// ---------------------------------------------------------------------------
// LayerNorm, wave-per-row. Organ-batched (o = row/rpo). RES: split residual.
// OSPL: 1 -> write split hi/lo, 0 -> write f32.
// ---------------------------------------------------------------------------
template<bool RES, int HD, int OSPL>
__global__ __launch_bounds__(256) void ln2_kernel(
    const float* __restrict__ X,
    const unsigned short* __restrict__ Rhi, const unsigned short* __restrict__ Rlo,
    const float* __restrict__ g, const float* __restrict__ be,
    float* __restrict__ Y,
    unsigned short* __restrict__ Yhi, unsigned short* __restrict__ Ylo,
    int rows, int rpo)
{
    constexpr int EPL = HD / 64;
    int wv = threadIdx.x >> 6, lane = threadIdx.x & 63;
    long long row = (long long)blockIdx.x * 4 + wv;
    if (row >= rows) return;
    int o = (int)(row / rpo);
    long long rrow = row % rpo;
    const float* x = X + row * HD;
    float v[EPL];
    #pragma unroll
    for (int q = 0; q < EPL / 4; ++q) {
        float4 a = *(const float4*)&x[lane * EPL + q * 4];
        v[q*4+0] = a.x; v[q*4+1] = a.y; v[q*4+2] = a.z; v[q*4+3] = a.w;
        if (RES) {
            us4 rh = *(const us4*)&Rhi[rrow * HD + lane * EPL + q * 4];
            us4 rl = *(const us4*)&Rlo[rrow * HD + lane * EPL + q * 4];
            #pragma unroll
            for (int e = 0; e < 4; ++e) v[q*4+e] += bf2f(rh[e]) + bf2f(rl[e]);
        }
    }
    float s = 0.f;
    #pragma unroll
    for (int e = 0; e < EPL; ++e) s += v[e];
    #pragma unroll
    for (int d = 1; d < 64; d <<= 1) s += __shfl_xor(s, d, 64);
    float mean = s * (1.f / HD);
    float s2 = 0.f;
    #pragma unroll
    for (int e = 0; e < EPL; ++e) { float d0 = v[e] - mean; s2 += d0 * d0; }
    #pragma unroll
    for (int d = 1; d < 64; d <<= 1) s2 += __shfl_xor(s2, d, 64);
    float inv = 1.f / sqrtf(s2 * (1.f / HD) + 1e-7f);
    #pragma unroll
    for (int q = 0; q < EPL / 4; ++q) {
        int c = lane * EPL + q * 4;
        float4 gg = *(const float4*)&g[o * HD + c];
        float4 bb = *(const float4*)&be[o * HD + c];
        float ov[4];
        ov[0] = (v[q*4+0] - mean) * inv * gg.x + bb.x;
        ov[1] = (v[q*4+1] - mean) * inv * gg.y + bb.y;
        ov[2] = (v[q*4+2] - mean) * inv * gg.z + bb.z;
        ov[3] = (v[q*4+3] - mean) * inv * gg.w + bb.w;
        if (OSPL) {
            us4 ph, pl;
            #pragma unroll
            for (int e = 0; e < 4; ++e) {
                unsigned short hh = f2bf(ov[e]);
                ph[e] = hh;
                pl[e] = f2bf(ov[e] - bf2f(hh));
            }
            *(us4*)&Yhi[row * HD + c] = ph;
            *(us4*)&Ylo[row * HD + c] = pl;
        } else {
            float4 of; of.x = ov[0]; of.y = ov[1]; of.z = ov[2]; of.w = ov[3];
            *(float4*)&Y[row * HD + c] = of;
        }
    }
}

// ---------------------------------------------------------------------------
// MFMA fused disentangled flash attention (R16 config, best measured):
// HI-ONLY operands, single-wave blocks, straight-line clamped loads,
// zero barriers. Grid (25, 8, 8*nOrg), XCD-swizzled.
// ---------------------------------------------------------------------------
__global__ __launch_bounds__(64) void attn_kernel(
    const unsigned short* __restrict__ qk_hi, const unsigned short* __restrict__ qk_lo,
    const unsigned short* __restrict__ vt_hi, const unsigned short* __restrict__ vt_lo,
    const unsigned short* __restrict__ pkg_hi, const unsigned short* __restrict__ pkg_lo,
    const float* __restrict__ mask,
    unsigned short* __restrict__ ctxh, unsigned short* __restrict__ ctxl)
{
    const float scale = 0.07216878364870322f;       // 1/sqrt(64*3)
    const float NEGMIN = -3.402823466e38f;
    int lin = blockIdx.x + 25 * (blockIdx.y + 8 * blockIdx.z);
    int gz = gridDim.z;
    int xcd = lin & 7, within = lin >> 3;
    int g = within / 25, lt = within - g * 25;
    int combo = xcd * gz + g;
    int h = combo & 7, z = combo >> 3;
    int b = z & 7, o = z >> 3;
    qk_hi  += (long long)o * 3276800;
    vt_hi  += (long long)o * 1703936;
    pkg_hi += (long long)o * 818176;
    mask   += o * 3200;
    ctxh   += (long long)o * 1638400;
    ctxl   += (long long)o * 1638400;

    int l0 = lt * 16;
    int lane = threadIdx.x;
    int fr = lane & 15, kg8 = (lane >> 4) << 3, g4 = (lane >> 4) << 2;

    __shared__ float T2c[16 * 36];
    __shared__ float T3c[32 * 20];
    __shared__ unsigned short Sth[16 * 40];

    bf16x8 qf[2];
    {
        long long base = ((long long)(b * 400 + l0 + fr)) * 1024 + h * 64 + kg8;
        #pragma unroll
        for (int kk = 0; kk < 2; ++kk)
            qf[kk] = *(const bf16x8*)(qk_hi + base + kk * 32);
    }
    float wlv_r[4], ms[4], ls[4];
    #pragma unroll
    for (int r = 0; r < 4; ++r) {
        wlv_r[r] = mask[b * 400 + l0 + g4 + r];
        ms[r] = -INFINITY;
        ls[r] = 0.f;
    }
    f32x4 O[4] = {};
    long long vtbase = ((long long)(b * 512 + h * 64)) * 416;

    for (int mt = 0; mt < 13; ++mt) {
        int m0 = mt * 32;
        int D0 = l0 - m0 + 368;
        bf16x8 kf[2][2];
        #pragma unroll
        for (int jf = 0; jf < 2; ++jf) {
            int kr = m0 + jf * 16 + fr;
            kr = kr < 400 ? kr : 399;
            long long base = ((long long)(b * 400 + kr)) * 1024 + 512 + h * 64 + kg8;
            #pragma unroll
            for (int kk = 0; kk < 2; ++kk)
                kf[jf][kk] = *(const bf16x8*)(qk_hi + base + kk * 32);
        }
        bf16x8 b2h[3][2], b3h[3][2];
        #pragma unroll
        for (int c = 0; c < 3; ++c) {
            int dd = D0 + c * 16 + fr;
            dd = dd < 0 ? 0 : (dd > 798 ? 798 : dd);
            long long base = (long long)dd * 1024 + h * 64 + kg8;
            #pragma unroll
            for (int kk = 0; kk < 2; ++kk) {
                b2h[c][kk] = *(const bf16x8*)(pkg_hi + base + 512 + kk * 32);
                b3h[c][kk] = *(const bf16x8*)(pkg_hi + base + kk * 32);
            }
        }
        bf16x8 vf[4];
        #pragma unroll
        for (int f = 0; f < 4; ++f) {
            long long a = vtbase + (long long)(f * 16 + fr) * 416 + m0 + kg8;
            vf[f] = *(const bf16x8*)&vt_hi[a];
        }
        float wm_c[2];
        #pragma unroll
        for (int cf = 0; cf < 2; ++cf) {
            int mg = m0 + cf * 16 + fr;
            mg = mg < 400 ? mg : 399;
            wm_c[cf] = mask[b * 400 + mg];
        }
        __builtin_amdgcn_s_setprio(1);
        f32x4 aT1[2] = {};
        #pragma unroll
        for (int jf = 0; jf < 2; ++jf)
        #pragma unroll
        for (int kk = 0; kk < 2; ++kk)
            aT1[jf] = __builtin_amdgcn_mfma_f32_16x16x32_bf16(qf[kk], kf[jf][kk], aT1[jf], 0, 0, 0);
        f32x4 aT2[3] = {};
        #pragma unroll
        for (int c = 0; c < 3; ++c)
        #pragma unroll
        for (int kk = 0; kk < 2; ++kk)
            aT2[c] = __builtin_amdgcn_mfma_f32_16x16x32_bf16(qf[kk], b2h[c][kk], aT2[c], 0, 0, 0);
        f32x4 aT3[2][2] = {};
        #pragma unroll
        for (int jf = 0; jf < 2; ++jf)
        #pragma unroll
        for (int ci = 0; ci < 2; ++ci) {
            int c = ci + (jf ^ 1);
            #pragma unroll
            for (int kk = 0; kk < 2; ++kk)
                aT3[jf][ci] = __builtin_amdgcn_mfma_f32_16x16x32_bf16(kf[jf][kk], b3h[c][kk], aT3[jf][ci], 0, 0, 0);
        }
        __builtin_amdgcn_s_setprio(0);
        #pragma unroll
        for (int c = 0; c < 3; ++c)
        #pragma unroll
        for (int r = 0; r < 4; ++r) {
            int i = g4 + r;
            int d = c * 16 + fr - i;
            if ((unsigned)d < 32u)
                T2c[i * 36 + d] = aT2[c][r];
        }
        #pragma unroll
        for (int jf = 0; jf < 2; ++jf)
        #pragma unroll
        for (int ci = 0; ci < 2; ++ci) {
            int c = ci + (jf ^ 1);
            #pragma unroll
            for (int r = 0; r < 4; ++r) {
                int j3 = jf * 16 + g4 + r;
                int d2 = c * 16 + fr + j3 - 31;
                if ((unsigned)d2 < 16u)
                    T3c[j3 * 20 + d2] = aT3[jf][ci][r];
            }
        }
        float sc0[4], sc1[4];
        #pragma unroll
        for (int r = 0; r < 4; ++r) {
            int i = g4 + r;
            {
                int j = fr;
                bool jv = (m0 + j) < 400;
                sc0[r] = !jv ? -INFINITY :
                    ((wlv_r[r] != 0.f && wm_c[0] != 0.f) ?
                     (aT1[0][r] + T2c[i * 36 + 31 - j] + T3c[j * 20 + i]) * scale : NEGMIN);
            }
            {
                int j = 16 + fr;
                bool jv = (m0 + j) < 400;
                sc1[r] = !jv ? -INFINITY :
                    ((wlv_r[r] != 0.f && wm_c[1] != 0.f) ?
                     (aT1[1][r] + T2c[i * 36 + 31 - j] + T3c[j * 20 + i]) * scale : NEGMIN);
            }
        }
        float corr[4];
        #pragma unroll
        for (int r = 0; r < 4; ++r) {
            float mx = fmaxf(sc0[r], sc1[r]);
            #pragma unroll
            for (int d = 1; d < 16; d <<= 1) mx = fmaxf(mx, __shfl_xor(mx, d, 64));
            float mn = fmaxf(ms[r], mx);
            corr[r] = __expf(ms[r] - mn);
            ms[r] = mn;
            float p0 = __expf(sc0[r] - mn), p1 = __expf(sc1[r] - mn);
            float rs = p0 + p1;
            #pragma unroll
            for (int d = 1; d < 16; d <<= 1) rs += __shfl_xor(rs, d, 64);
            ls[r] = ls[r] * corr[r] + rs;
            int i = g4 + r;
            Sth[i * 40 + fr] = f2bf(p0);
            Sth[i * 40 + 16 + fr] = f2bf(p1);
        }
        #pragma unroll
        for (int f = 0; f < 4; ++f)
        #pragma unroll
        for (int r = 0; r < 4; ++r) O[f][r] *= corr[r];
        bf16x8 Pha = *(const bf16x8*)&Sth[fr * 40 + kg8];
        __builtin_amdgcn_s_setprio(1);
        #pragma unroll
        for (int f = 0; f < 4; ++f)
            O[f] = __builtin_amdgcn_mfma_f32_16x16x32_bf16(Pha, vf[f], O[f], 0, 0, 0);
        __builtin_amdgcn_s_setprio(0);
    }
    #pragma unroll
    for (int f = 0; f < 4; ++f) {
        int colg = h * 64 + f * 16 + fr;
        #pragma unroll
        for (int r = 0; r < 4; ++r) {
            int lg = l0 + g4 + r;
            float val = O[f][r] / ls[r];
            long long idx = ((long long)(b * 400 + lg)) * 512 + colg;
            unsigned short hh = f2bf(val);
            ctxh[idx] = hh;
            ctxl[idx] = f2bf(val - bf2f(hh));
        }
    }
}

// ---------------------------------------------------------------------------
// Chunked pool / meanmax (full-chip), heads
// ---------------------------------------------------------------------------
__global__ __launch_bounds__(256) void pool_part(
    const float* __restrict__ in, long long inOStride,
    const float* __restrict__ mk, float* __restrict__ pp)
{
    int bi = blockIdx.x, c = blockIdx.y, t = threadIdx.x;
    int o = bi >> 3, b = bi & 7;
    int l0 = c * 31, l1 = min(400, l0 + 31);
    const float* ib = in + (long long)o * inOStride + (long long)(b * 400) * 256;
    const float* mkb = mk + o * 3200 + b * 400;
    float s = 0.f, mx = -INFINITY, sw = 0.f;
    for (int l = l0; l < l1; ++l) {
        float wv = mkb[l];
        float v = ib[(long long)l * 256 + t] * wv;
        s += v; mx = fmaxf(mx, v); sw += wv;
    }
    long long base = (long long)(c * gridDim.x + bi) * 514;
    pp[base + t] = s;
    pp[base + 256 + t] = mx;
    if (t == 0) pp[base + 512] = sw;
}

__global__ __launch_bounds__(256) void pool_merge(
    const float* __restrict__ pp, float* __restrict__ pooled, int nBI)
{
    int bi = blockIdx.x, t = threadIdx.x;
    float s = 0.f, mx = -INFINITY, sw = 0.f;
    for (int c = 0; c < 13; ++c) {
        long long base = (long long)(c * nBI + bi) * 514;
        s += pp[base + t];
        mx = fmaxf(mx, pp[base + 256 + t]);
        sw += pp[base + 512];
    }
    int o = bi >> 3, b = bi & 7;
    pooled[o * 4096 + b * 512 + t] = s / (sw + 1e-6f);
    pooled[o * 4096 + b * 512 + 256 + t] = mx;
}

__global__ __launch_bounds__(512) void mm_part(
    const unsigned short* __restrict__ fh, const unsigned short* __restrict__ fl,
    float* __restrict__ mmp)
{
    int b = blockIdx.x, c = blockIdx.y, t = threadIdx.x;
    int l0 = c * 31, l1 = min(400, l0 + 31);
    float s = 0.f, mx = -INFINITY;
    for (int l = l0; l < l1; ++l) {
        long long idx = ((long long)(b * 400 + l)) * 512 + t;
        float v = bf2f(fh[idx]) + bf2f(fl[idx]);
        s += v; mx = fmaxf(mx, v);
    }
    long long base = (long long)(c * 8 + b) * 1024;
    mmp[base + t] = s;
    mmp[base + 512 + t] = mx;
}

__global__ __launch_bounds__(512) void mm_merge(
    const float* __restrict__ mmp, float* __restrict__ mm)
{
    int b = blockIdx.x, t = threadIdx.x;
    float s = 0.f, mx = -INFINITY;
    for (int c = 0; c < 13; ++c) {
        long long base = (long long)(c * 8 + b) * 1024;
        s += mmp[base + t];
        mx = fmaxf(mx, mmp[base + 512 + t]);
    }
    mm[b * 1024 + t] = s / 400.f;
    mm[b * 1024 + 512 + t] = mx;
}

__global__ __launch_bounds__(256) void heads_kernel(
    const float* __restrict__ pooled, const float* __restrict__ mm,
    const float* __restrict__ w_bow1, const float* __restrict__ b_bow1,
    const float* __restrict__ w_bow2, const float* __restrict__ b_bow2,
    const float* __restrict__ w_ext1, const float* __restrict__ b_ext1,
    const float* __restrict__ w_ext2, const float* __restrict__ b_ext2,
    const float* __restrict__ w_org1, const float* __restrict__ b_org1,
    const float* __restrict__ w_org2, const float* __restrict__ b_org2,
    float* __restrict__ out)
{
    int b = blockIdx.x, role = blockIdx.y;
    int t = threadIdx.x;
    __shared__ float inb[1024];
    __shared__ float red[256];
    __shared__ float hid[256];
    if (role == 0) {
        inb[t] = pooled[b * 512 + t];
        inb[256 + t] = pooled[b * 512 + 256 + t];
        __syncthreads();
        float acc = b_bow1[t];
        for (int j = 0; j < 512; ++j) acc += inb[j] * w_bow1[j * 256 + t];
        red[t] = mishf(acc) * w_bow2[t];
        __syncthreads();
        for (int s = 128; s; s >>= 1) { if (t < s) red[t] += red[t + s]; __syncthreads(); }
        if (t == 0) out[b * 11 + 0] = red[0] + b_bow2[0];
    } else if (role == 1) {
        inb[t] = mm[b * 1024 + t];
        inb[256 + t] = mm[b * 1024 + 256 + t];
        inb[512 + t] = mm[b * 1024 + 512 + t];
        inb[768 + t] = mm[b * 1024 + 768 + t];
        __syncthreads();
        float acc = b_ext1[t];
        for (int j = 0; j < 1024; ++j) acc += inb[j] * w_ext1[j * 256 + t];
        red[t] = mishf(acc) * w_ext2[t];
        __syncthreads();
        for (int s = 128; s; s >>= 1) { if (t < s) red[t] += red[t + s]; __syncthreads(); }
        if (t == 0) { out[b * 11 + 1] = red[0] + b_ext2[0]; out[88 + b] = 0.f; }
    } else {
        int i = role - 2;
        inb[t] = pooled[((1 + i) * 8 + b) * 512 + t];
        inb[256 + t] = pooled[((1 + i) * 8 + b) * 512 + 256 + t];
        __syncthreads();
        float acc = b_org1[i * 256 + t];
        for (int j = 0; j < 512; ++j)
            acc += inb[j] * w_org1[((long long)i * 512 + j) * 256 + t];
        hid[t] = mishf(acc);
        __syncthreads();
        for (int c = 0; c < 3; ++c) {
            red[t] = hid[t] * w_org2[(i * 256 + t) * 3 + c];
            __syncthreads();
            for (int s = 128; s; s >>= 1) { if (t < s) red[t] += red[t + s]; __syncthreads(); }
            if (t == 0) out[b * 11 + 2 + i * 3 + c] = red[0] + b_org2[i * 3 + c];
            __syncthreads();
        }
    }
}

// ---------------------------------------------------------------------------
// Launch
// ---------------------------------------------------------------------------
extern "C" void kernel_launch(void* const* d_in, const int* in_sizes, int n_in,
                              void* d_out, int out_size, void* d_ws, size_t ws_size,
                              hipStream_t stream)
{
    const float* x      = (const float*)d_in[0];
    const float* w_mlp  = (const float*)d_in[1];
    const float* b_mlp  = (const float*)d_in[2];
    const float* w_cnn  = (const float*)d_in[3];
    const float* b_cnn  = (const float*)d_in[4];
    const float* rel_emb= (const float*)d_in[5];
    const float* rel_g  = (const float*)d_in[6];
    const float* rel_b  = (const float*)d_in[7];
    const float* wq     = (const float*)d_in[8];
    const float* wk     = (const float*)d_in[9];
    const float* wv     = (const float*)d_in[10];
    const float* wo     = (const float*)d_in[11];
    const float* wi     = (const float*)d_in[12];
    const float* bq     = (const float*)d_in[13];
    const float* bk     = (const float*)d_in[14];
    const float* bv     = (const float*)d_in[15];
    const float* bo     = (const float*)d_in[16];
    const float* bi     = (const float*)d_in[17];
    const float* wout   = (const float*)d_in[18];
    const float* bout   = (const float*)d_in[19];
    const float* ln1g   = (const float*)d_in[20];
    const float* ln1b   = (const float*)d_in[21];
    const float* ln2g   = (const float*)d_in[22];
    const float* ln2b   = (const float*)d_in[23];
    const float* w_bow1 = (const float*)d_in[24];
    const float* b_bow1 = (const float*)d_in[25];
    const float* w_bow2 = (const float*)d_in[26];
    const float* b_bow2 = (const float*)d_in[27];
    const float* w_ext1 = (const float*)d_in[28];
    const float* b_ext1 = (const float*)d_in[29];
    const float* w_ext2 = (const float*)d_in[30];
    const float* b_ext2 = (const float*)d_in[31];
    const float* w_org1 = (const float*)d_in[32];
    const float* b_org1 = (const float*)d_in[33];
    const float* w_org2 = (const float*)d_in[34];
    const float* b_org2 = (const float*)d_in[35];

    float* ws = (float*)d_ws;
    float* outf = (float*)d_out;
    const bool big = ws_size >= 143012736ull;

    if (big) {
        // ---------------- organ-batched path ----------------
        unsigned short* featsh = (unsigned short*)(ws + 0);        // 3200x512
        unsigned short* featsl = (unsigned short*)(ws + 819200);
        float* ctxR     = ws + 1638400;      // 6,553,600 fl
        float* f1pad    = ctxR;
        unsigned short* ctxh = (unsigned short*)ctxR;              // 4x3200x512
        unsigned short* ctxl = (unsigned short*)(ws + 4915200);
        float* qkA_f    = ws + 8192000;
        float* qkB_f    = ws + 14745600;
        unsigned short* qkA = (unsigned short*)qkA_f;
        unsigned short* qkB = (unsigned short*)qkB_f;
        unsigned short* rellnh = (unsigned short*)qkA_f;           // 4800x512
        unsigned short* rellnl = (unsigned short*)(ws + 8192000 + 1228800);
        unsigned short* vtA = (unsigned short*)(ws + 21299200);    // 4x4096x416
        unsigned short* vtB = (unsigned short*)(ws + 24707072);
        unsigned short* pkgA = (unsigned short*)(ws + 28114944);   // 4x799x1024
        unsigned short* pkgB = (unsigned short*)(ws + 29751296);
        unsigned short* whiA = (unsigned short*)(ws + 31387648);   // 4x786,432
        unsigned short* wloA = (unsigned short*)(ws + 32960512);
        unsigned short* wcnn_hi = (unsigned short*)(ws + 35188736);
        unsigned short* wcnn_lo = (unsigned short*)(ws + 35287040);
        float* bqkvb   = ws + 35385344;
        float* masksb  = ws + 35391488;
        float* pooledb = ws + 35404288;
        float* mmb     = ws + 35420672;
        int*   relidx  = (int*)(ws + 35428864);
        int*   convidx = (int*)(ws + 35429664);
        float* poolpart= ws + 35432864;
        float* mmpart  = ws + 35646688;
        float* tmp_all   = qkA_f;                                  // WO out (f32)
        unsigned short* h1h = (unsigned short*)qkB_f;              // LN1 out split
        unsigned short* h1l = (unsigned short*)(ws + 14745600 + 3276800);
        unsigned short* interh = (unsigned short*)qkA_f;           // WI out split
        unsigned short* interl = (unsigned short*)(ws + 8192000 + 3276800);
        float* outenc_all = (float*)vtA;                           // 4x819,200 f32
        float* outln_all  = ctxR;                                  // 4x819,200 f32
        unsigned short* whiB_all = whiA;
        unsigned short* wloB_all = wloA;

        gemm_bias<1><<<dim3(4, 50), 256, 0, stream>>>(
            x, w_mlp, b_mlp, f1pad, featsh, featsl, 3200, 256, 128, 512);
        setup_kernel<<<1080, 256, 0, stream>>>(x, bq, bk, bv, masksb, relidx, convidx,
                                               f1pad, bqkvb, vtA, vtB, 4);
        prep_wcnn<<<768, 256, 0, stream>>>(w_cnn, wcnn_hi, wcnn_lo);
        gemm_mfma<2, true, 0, true, 32, false, 3, true><<<dim3(2, 100), 256, 0, stream>>>(
            f1pad, nullptr, nullptr, wcnn_hi, wcnn_lo, b_cnn, nullptr,
            3200, 768, 256, 0, convidx, featsh + 256, featsl + 256, 512, 1 << 30,
            nullptr, nullptr, 0, 0, 0, 0, 0, 0);

        ln2_kernel<false, 512, 1><<<1200, 256, 0, stream>>>(
            rel_emb, nullptr, nullptr, rel_g, rel_b, nullptr, rellnh, rellnl, 4800, 1200);
        prep_wqkv<<<12288, 256, 0, stream>>>(wq, wk, wv, whiA, wloA, 0, 3145728, 0);
        // PQK (hi-only x1)
        gemm_mfma<0, true, 1, true, 64, true, 1, false><<<dim3(8, 13, 4), 256, 0, stream>>>(
            nullptr, rellnh, rellnl, whiA, wloA, bqkvb, nullptr, 799, 512, 512, 0, relidx,
            pkgA, pkgB, 1024, 1024, nullptr, nullptr,
            614400, 786432, 1536, 0, 818176, 0);
        // QKV (hi-only x1)
        gemm_mfma<0, false, 1, true, 64, true, 1, false><<<dim3(12, 50, 4), 256, 0, stream>>>(
            nullptr, featsh, featsl, whiA, wloA, bqkvb, nullptr, 3200, 512, 512, 0, nullptr,
            qkA, qkB, 1024, 1024, vtA, vtB,
            0, 786432, 1536, 0, 3276800, 1703936);
        prep_woiw<<<10240, 256, 0, stream>>>(wo, wi, wout, whiB_all, wloB_all,
                                             0, 2621440);
        attn_kernel<<<dim3(25, 8, 32), 64, 0, stream>>>(qkA, qkB, vtA, vtB,
            pkgA, pkgB, masksb, ctxh, ctxl);
        gemm_mfma<0, false, 1, false, 32, true, 3, true><<<dim3(4, 100, 4), 256, 0, stream>>>(
            nullptr, ctxh, ctxl, whiB_all, wloB_all, bo, tmp_all,
            3200, 512, 512, 512, nullptr, nullptr, nullptr, 0, 0, nullptr, nullptr,
            1638400, 655360, 512, 1638400, 0, 0);
        ln2_kernel<true, 512, 1><<<3200, 256, 0, stream>>>(
            tmp_all, featsh, featsl, ln1g, ln1b, nullptr, h1h, h1l, 12800, 3200);
        gemm_mfma<1, false, 1, true, 32, true, 3, true><<<dim3(4, 100, 4), 256, 0, stream>>>(
            nullptr, h1h, h1l, whiB_all + 262144, wloB_all + 262144, bi, nullptr,
            3200, 512, 512, 0, nullptr, interh, interl, 512, 1 << 30, nullptr, nullptr,
            1638400, 655360, 512, 0, 1638400, 0);
        gemm_mfma<0, false, 1, false, 32, true, 3, true><<<dim3(2, 100, 4), 256, 0, stream>>>(
            nullptr, interh, interl, whiB_all + 524288, wloB_all + 524288, bout, outenc_all,
            3200, 512, 512, 256, nullptr, nullptr, nullptr, 0, 0, nullptr, nullptr,
            1638400, 655360, 256, 819200, 0, 0);
        ln2_kernel<false, 256, 0><<<3200, 256, 0, stream>>>(
            outenc_all, nullptr, nullptr, ln2g, ln2b, outln_all, nullptr, nullptr,
            12800, 3200);

        pool_part<<<dim3(32, 13), 256, 0, stream>>>(outln_all, 819200, masksb, poolpart);
        pool_merge<<<32, 256, 0, stream>>>(poolpart, pooledb, 32);
        mm_part<<<dim3(8, 13), 512, 0, stream>>>(featsh, featsl, mmpart);
        mm_merge<<<8, 512, 0, stream>>>(mmpart, mmb);
        heads_kernel<<<dim3(8, 5), 256, 0, stream>>>(pooledb, mmb,
            w_bow1, b_bow1, w_bow2, b_bow2, w_ext1, b_ext1, w_ext2, b_ext2,
            w_org1, b_org1, w_org2, b_org2, outf);
        return;
    }

    // ---------------- per-organ fallback path ----------------
    unsigned short* featsh = (unsigned short*)(ws + 0);
    unsigned short* featsl = (unsigned short*)(ws + 819200);
    float* ctxR    = ws + 1638400;
    float* f1pad   = ctxR;
    unsigned short* ctxh = (unsigned short*)ctxR;
    unsigned short* ctxl = (unsigned short*)(ws + 1638400 + 819200);
    float* qkvA_f  = ws + 3276800;
    float* qkvB_f  = ws + 4915200;
    unsigned short* qkv_hi = (unsigned short*)qkvA_f;
    unsigned short* qkv_lo = (unsigned short*)qkvB_f;
    unsigned short* rellnh = (unsigned short*)qkvB_f;
    unsigned short* rellnl = (unsigned short*)(ws + 4915200 + 307200);
    unsigned short* pkg_hi = (unsigned short*)(ws + 6553600);
    unsigned short* pkg_lo = (unsigned short*)(ws + 6963200);
    unsigned short* vt_hi  = (unsigned short*)(ws + 7372800);
    unsigned short* vt_lo  = (unsigned short*)(ws + 8224768);
    unsigned short* whi    = (unsigned short*)(ws + 9076736);
    unsigned short* wlo    = (unsigned short*)(ws + 9469952);
    float* bqkvb   = ws + 9863168;
    float* masksb  = ws + 9869312;
    float* pooledb = ws + 9882112;
    float* mmb     = ws + 9898496;
    int*   relidx  = (int*)(ws + 9906688);
    unsigned short* wcnn_hi = (unsigned short*)(ws + 9907488);
    unsigned short* wcnn_lo = (unsigned short*)(ws + 10005792);
    int*   convidx = (int*)(ws + 10104096);
    float* poolpart= ws + 10107296;
    float* mmpart  = ws + 10160752;
    float* tmp     = qkvA_f;
    unsigned short* h1h = (unsigned short*)qkvB_f;
    unsigned short* h1l = (unsigned short*)(ws + 4915200 + 819200);
    unsigned short* interh = (unsigned short*)qkvA_f;
    unsigned short* interl = (unsigned short*)(ws + 3276800 + 819200);
    float* outenc  = (float*)vt_hi;
    float* outln   = ctxR;

    gemm_bias<1><<<dim3(4, 50), 256, 0, stream>>>(
        x, w_mlp, b_mlp, f1pad, featsh, featsl, 3200, 256, 128, 512);
    setup_kernel<<<312, 256, 0, stream>>>(x, bq, bk, bv, masksb, relidx, convidx,
                                          f1pad, bqkvb, vt_hi, vt_lo, 1);
    prep_wcnn<<<768, 256, 0, stream>>>(w_cnn, wcnn_hi, wcnn_lo);
    gemm_mfma<2, true, 0, true, 32, false, 3, true><<<dim3(2, 100), 256, 0, stream>>>(
        f1pad, nullptr, nullptr, wcnn_hi, wcnn_lo, b_cnn, nullptr,
        3200, 768, 256, 0, convidx, featsh + 256, featsl + 256, 512, 1 << 30,
        nullptr, nullptr, 0, 0, 0, 0, 0, 0);

    for (int o = 0; o < 4; ++o) {
        ln2_kernel<false, 512, 1><<<300, 256, 0, stream>>>(
            rel_emb + (long long)o * 614400, nullptr, nullptr,
            rel_g + o * 512, rel_b + o * 512, nullptr, rellnh, rellnl, 1200, 1200);
        prep_wqkv<<<3072, 256, 0, stream>>>(wq, wk, wv, whi, wlo, o, 786432, 0);
        gemm_mfma<0, true, 1, true, 64, true, 1, false><<<dim3(8, 13), 256, 0, stream>>>(
            nullptr, rellnh, rellnl, whi, wlo, bqkvb + o * 1536, nullptr,
            799, 512, 512, 0, relidx, pkg_hi, pkg_lo, 1024, 1024, nullptr, nullptr,
            0, 0, 0, 0, 0, 0);
        gemm_mfma<0, false, 1, true, 64, true, 1, false><<<dim3(12, 50), 256, 0, stream>>>(
            nullptr, featsh, featsl, whi, wlo, bqkvb + o * 1536, nullptr,
            3200, 512, 512, 0, nullptr, qkv_hi, qkv_lo, 1024, 1024, vt_hi, vt_lo,
            0, 0, 0, 0, 0, 0);
        prep_woiw<<<2560, 256, 0, stream>>>(wo, wi, wout, whi, wlo, o, 655360);
        attn_kernel<<<dim3(25, 8, 8), 64, 0, stream>>>(qkv_hi, qkv_lo, vt_hi, vt_lo,
            pkg_hi, pkg_lo, masksb + o * 3200, ctxh, ctxl);
        gemm_mfma<0, false, 1, false, 32, true, 3, true><<<dim3(4, 100), 256, 0, stream>>>(
            nullptr, ctxh, ctxl, whi, wlo, bo + o * 512, tmp,
            3200, 512, 512, 512, nullptr, nullptr, nullptr, 0, 0, nullptr, nullptr,
            0, 0, 0, 0, 0, 0);
        ln2_kernel<true, 512, 1><<<800, 256, 0, stream>>>(
            tmp, featsh, featsl, ln1g + o * 512, ln1b + o * 512, nullptr,
            h1h, h1l, 3200, 3200);
        gemm_mfma<1, false, 1, true, 32, true, 3, true><<<dim3(4, 100), 256, 0, stream>>>(
            nullptr, h1h, h1l, whi + 262144, wlo + 262144, bi + o * 512, nullptr,
            3200, 512, 512, 0, nullptr, interh, interl, 512, 1 << 30, nullptr, nullptr,
            0, 0, 0, 0, 0, 0);
        gemm_mfma<0, false, 1, false, 32, true, 3, true><<<dim3(2, 100), 256, 0, stream>>>(
            nullptr, interh, interl, whi + 524288, wlo + 524288, bout + o * 256, outenc,
            3200, 512, 512, 256, nullptr, nullptr, nullptr, 0, 0, nullptr, nullptr,
            0, 0, 0, 0, 0, 0);
        ln2_kernel<false, 256, 0><<<800, 256, 0, stream>>>(
            outenc, nullptr, nullptr, ln2g + o * 256, ln2b + o * 256, outln,
            nullptr, nullptr, 3200, 3200);
        pool_part<<<dim3(8, 13), 256, 0, stream>>>(outln, 0,
                                                   masksb + o * 3200, poolpart);
        pool_merge<<<8, 256, 0, stream>>>(poolpart, pooledb + o * 4096, 8);
    }

    mm_part<<<dim3(8, 13), 512, 0, stream>>>(featsh, featsl, mmpart);
    mm_merge<<<8, 512, 0, stream>>>(mmpart, mmb);
    heads_kernel<<<dim3(8, 5), 256, 0, stream>>>(pooledb, mmb,
        w_bow1, b_bow1, w_bow2, b_bow2, w_ext1, b_ext1, w_ext2, b_ext2,
        w_org1, b_org1, w_org2, b_org2, outf);
}

// Round 18
// 505.596 us; speedup vs baseline: 1.4302x; 1.0914x over previous
//
#include <hip/hip_runtime.h>
#include <math.h>

// ---------------------------------------------------------------------------
// Model dims (fixed): B=8 L=400 F=128 D=256 T=256 H=512 NH=8 HD=64 P=1200
// ---------------------------------------------------------------------------

typedef __attribute__((ext_vector_type(8))) short bf16x8;
typedef __attribute__((ext_vector_type(4))) float f32x4;
typedef __attribute__((ext_vector_type(4))) unsigned int u32x4;
typedef __attribute__((ext_vector_type(4))) unsigned short us4;

__device__ __forceinline__ float mishf(float x) {
    float sp = fmaxf(x, 0.f) + log1pf(expf(-fabsf(x)));   // stable softplus
    return x * tanhf(sp);
}

__device__ __forceinline__ unsigned short f2bf(float f) {
    unsigned int u = __float_as_uint(f);
    u = (u + 0x7fffu + ((u >> 16) & 1u)) >> 16;           // RNE
    return (unsigned short)u;
}
__device__ __forceinline__ float bf2f(unsigned short h) {
    return __uint_as_float(((unsigned int)h) << 16);
}

// async global->LDS 16B per lane; dst is wave-uniform base (+ lane*16 in HW)
__device__ __forceinline__ void gll16(const unsigned short* g, unsigned short* l) {
    __builtin_amdgcn_global_load_lds(
        (const __attribute__((address_space(1))) void*)g,
        (__attribute__((address_space(3))) void*)l, 16, 0, 0);
}

// ---------------------------------------------------------------------------
// fp32 GEMM (front MLP, K=128): writes f1pad (padded conv layout) + split
// bf16 hi/lo feats (cols 0..255 of 512-wide).
// ---------------------------------------------------------------------------
template<int EPI>
__global__ __launch_bounds__(256) void gemm_bias(
    const float* __restrict__ A, const float* __restrict__ Bm,
    const float* __restrict__ bias, float* __restrict__ C2,
    unsigned short* __restrict__ fhi, unsigned short* __restrict__ flo,
    int M, int N, int K, int ldc)
{
    __shared__ float As[16][68];
    __shared__ float Bs[16][68];
    int bm = blockIdx.y << 6, bn = blockIdx.x << 6;
    int tid = threadIdx.x;
    int tm = (tid >> 4) << 2, tn = (tid & 15) << 2;
    int ar = tid >> 2, ac4 = (tid & 3) << 2;
    int br = tid >> 4, bc4 = (tid & 15) << 2;
    float acc[4][4] = {};
    for (int k0 = 0; k0 < K; k0 += 16) {
        float4 av = make_float4(0.f, 0.f, 0.f, 0.f);
        if (bm + ar < M)
            av = *(const float4*)&A[(long long)(bm + ar) * K + k0 + ac4];
        As[ac4][ar] = av.x; As[ac4 + 1][ar] = av.y;
        As[ac4 + 2][ar] = av.z; As[ac4 + 3][ar] = av.w;
        *(float4*)&Bs[br][bc4] =
            *(const float4*)&Bm[(long long)(k0 + br) * N + bn + bc4];
        __syncthreads();
        #pragma unroll
        for (int kk = 0; kk < 16; ++kk) {
            float4 a4 = *(const float4*)&As[kk][tm];
            float4 b4 = *(const float4*)&Bs[kk][tn];
            acc[0][0] += a4.x * b4.x; acc[0][1] += a4.x * b4.y;
            acc[0][2] += a4.x * b4.z; acc[0][3] += a4.x * b4.w;
            acc[1][0] += a4.y * b4.x; acc[1][1] += a4.y * b4.y;
            acc[1][2] += a4.y * b4.z; acc[1][3] += a4.y * b4.w;
            acc[2][0] += a4.z * b4.x; acc[2][1] += a4.z * b4.y;
            acc[2][2] += a4.z * b4.z; acc[2][3] += a4.z * b4.w;
            acc[3][0] += a4.w * b4.x; acc[3][1] += a4.w * b4.y;
            acc[3][2] += a4.w * b4.z; acc[3][3] += a4.w * b4.w;
        }
        __syncthreads();
    }
    #pragma unroll
    for (int i = 0; i < 4; ++i) {
        int r = bm + tm + i;
        if (r < M) {
            float v[4];
            #pragma unroll
            for (int q = 0; q < 4; ++q) {
                v[q] = acc[i][q] + bias[bn + tn + q];
                if (EPI == 1) v[q] = mishf(v[q]);
            }
            float4 o; o.x = v[0]; o.y = v[1]; o.z = v[2]; o.w = v[3];
            int rr2 = (r / 400) * 402 + (r % 400) + 1;
            *(float4*)&C2[(long long)rr2 * 256 + bn + tn] = o;
            us4 ph, pl;
            #pragma unroll
            for (int q = 0; q < 4; ++q) {
                unsigned short hh = f2bf(v[q]);
                ph[q] = hh;
                pl[q] = f2bf(v[q] - bf2f(hh));
            }
            *(us4*)&fhi[(long long)r * ldc + bn + tn] = ph;
            *(us4*)&flo[(long long)r * ldc + bn + tn] = pl;
        }
    }
}

// ---------------------------------------------------------------------------
// MFMA bf16 GEMM. B pre-transposed+split [N][K] bf16 hi/lo.
// AMODE: 0 = A fp32 (split per tile), 1 = A pre-split hi/lo.
// XLV: 3 = x3-split (fp32-accurate), 1 = hi-only single MFMA.
// GLL: stage A/B via global_load_lds (async, unpadded stride-32 LDS).
// SPLIT out: cols<nhl -> Chi(/Clo if OUTLO); cols>=1024 -> V transposed (416).
// EPI: 0 none, 1 mish, 2 relu.
// ---------------------------------------------------------------------------
template<int EPI, bool GATHER, int AMODE, bool SPLIT, int MT, bool GLL,
         int XLV, bool OUTLO>
__global__ __launch_bounds__(256) void gemm_mfma(
    const float* __restrict__ A,
    const unsigned short* __restrict__ Ahi, const unsigned short* __restrict__ Alo,
    const unsigned short* __restrict__ Bth, const unsigned short* __restrict__ Btl,
    const float* __restrict__ bias, float* __restrict__ C,
    int M, int K, int lda, int ldc, const int* __restrict__ gidx,
    unsigned short* __restrict__ Chi, unsigned short* __restrict__ Clo,
    int ldhl, int nhl,
    unsigned short* __restrict__ vthi, unsigned short* __restrict__ vtlo,
    long long zA, int zB, int zBias, int zC, int zChi, int zVt)
{
    constexpr int AI = MT / 32;
    constexpr int STR = GLL ? 32 : 40;
    __shared__ unsigned short Ah[MT * STR];
    __shared__ unsigned short Al[(XLV == 3) ? MT * STR : 16];
    __shared__ unsigned short Bh[128 * STR];
    __shared__ unsigned short Bl[(XLV == 3) ? 128 * STR : 16];

    long long zz = blockIdx.z;
    if (AMODE == 0) A += zz * zA;
    else { Ahi += zz * zA; Alo += zz * zA; }
    Bth  += zz * (long long)zB;  Btl += zz * (long long)zB;
    bias += zz * (long long)zBias;
    C    += zz * (long long)zC;
    if (SPLIT) {
        Chi += zz * (long long)zChi; Clo += zz * (long long)zChi;
        vthi += zz * (long long)zVt; vtlo += zz * (long long)zVt;
    }

    int bm = blockIdx.y * MT, bn = blockIdx.x << 7;
    int tid = threadIdx.x;
    int lane = tid & 63, wid = tid >> 6;
    int wm = wid >> 1, wn = wid & 1;
    int fr = lane & 15, kg = (lane >> 4) << 3;

    // ---- GLL staging descriptors (wave-uniform dst, per-lane src) ----
    const unsigned short *aSrcH = nullptr, *aSrcL = nullptr;
    const unsigned short *bSrcH0 = nullptr, *bSrcL0 = nullptr;
    const unsigned short *bSrcH1 = nullptr, *bSrcL1 = nullptr;
    unsigned short *dstAh = nullptr, *dstAl = nullptr;
    unsigned short *dstBh0 = nullptr, *dstBl0 = nullptr;
    unsigned short *dstBh1 = nullptr, *dstBl1 = nullptr;
    bool doA = false;
    if (GLL) {
        int seg = (lane & 3) << 3;
        if (wid < MT / 16) {
            doA = true;
            int grow = bm + wid * 16 + (lane >> 2);
            grow = grow < M ? grow : (M - 1);
            long long arw = GATHER ? (long long)gidx[grow] : (long long)grow;
            aSrcH = Ahi + arw * lda + seg;
            aSrcL = Alo + arw * lda + seg;
            dstAh = &Ah[wid * 512];
            dstAl = &Al[(XLV == 3) ? wid * 512 : 0];
        }
        int br0 = bn + wid * 16 + (lane >> 2);
        int br1 = bn + (4 + wid) * 16 + (lane >> 2);
        bSrcH0 = Bth + (long long)br0 * K + seg;
        bSrcH1 = Bth + (long long)br1 * K + seg;
        bSrcL0 = Btl + (long long)br0 * K + seg;
        bSrcL1 = Btl + (long long)br1 * K + seg;
        dstBh0 = &Bh[wid * 512];       dstBh1 = &Bh[(4 + wid) * 512];
        dstBl0 = &Bl[(XLV == 3) ? wid * 512 : 0];
        dstBl1 = &Bl[(XLV == 3) ? (4 + wid) * 512 : 0];
    }

    // ---- legacy staging coords (non-GLL) ----
    int ar = tid >> 2, akc = (tid & 3) << 3;
    int bnr = tid >> 1, bkc = (tid & 1) << 4;
    bool astage = ar < MT;
    long long arow = 0; bool avalid = false;
    if (!GLL && astage) {
        int gr = bm + ar;
        avalid = gr < M;
        if (GATHER) arow = avalid ? (long long)gidx[gr] : 0;
        else        arow = avalid ? (long long)gr : 0;
    }

    f32x4 acc[AI][4] = {};

    for (int k0 = 0; k0 < K; k0 += 32) {
        if (GLL) {
            if (doA) {
                gll16(aSrcH + k0, dstAh);
                if (XLV == 3) gll16(aSrcL + k0, dstAl);
            }
            gll16(bSrcH0 + k0, dstBh0);
            gll16(bSrcH1 + k0, dstBh1);
            if (XLV == 3) {
                gll16(bSrcL0 + k0, dstBl0);
                gll16(bSrcL1 + k0, dstBl1);
            }
        } else {
            if (astage) {
                if (AMODE == 0) {
                    float vv[8];
                    if (avalid) {
                        float4 v0 = *(const float4*)&A[arow * lda + k0 + akc];
                        float4 v1 = *(const float4*)&A[arow * lda + k0 + akc + 4];
                        vv[0] = v0.x; vv[1] = v0.y; vv[2] = v0.z; vv[3] = v0.w;
                        vv[4] = v1.x; vv[5] = v1.y; vv[6] = v1.z; vv[7] = v1.w;
                    } else {
                        #pragma unroll
                        for (int e = 0; e < 8; ++e) vv[e] = 0.f;
                    }
                    union { unsigned short u[8]; u32x4 v; } ph, pl;
                    #pragma unroll
                    for (int e = 0; e < 8; ++e) {
                        unsigned short h = f2bf(vv[e]);
                        ph.u[e] = h;
                        pl.u[e] = f2bf(vv[e] - bf2f(h));
                    }
                    *(u32x4*)&Ah[ar * STR + akc] = ph.v;
                    if (XLV == 3) *(u32x4*)&Al[ar * STR + akc] = pl.v;
                } else {
                    u32x4 zv = {0u, 0u, 0u, 0u};
                    u32x4 vh = zv, vl = zv;
                    if (avalid) {
                        vh = *(const u32x4*)&Ahi[arow * lda + k0 + akc];
                        if (XLV == 3) vl = *(const u32x4*)&Alo[arow * lda + k0 + akc];
                    }
                    *(u32x4*)&Ah[ar * STR + akc] = vh;
                    if (XLV == 3) *(u32x4*)&Al[ar * STR + akc] = vl;
                }
            }
            long long boff = (long long)(bn + bnr) * K + k0 + bkc;
            *(u32x4*)&Bh[bnr * STR + bkc]     = *(const u32x4*)&Bth[boff];
            *(u32x4*)&Bh[bnr * STR + bkc + 8] = *(const u32x4*)&Bth[boff + 8];
            if (XLV == 3) {
                *(u32x4*)&Bl[bnr * STR + bkc]     = *(const u32x4*)&Btl[boff];
                *(u32x4*)&Bl[bnr * STR + bkc + 8] = *(const u32x4*)&Btl[boff + 8];
            }
        }
        __syncthreads();

        bf16x8 af[AI], alf[AI], bfj[4], blf[4];
        #pragma unroll
        for (int i = 0; i < AI; ++i) {
            int row = (MT == 64 ? wm * 32 + i * 16 : wm * 16) + fr;
            af[i]  = *(const bf16x8*)&Ah[row * STR + kg];
            if (XLV == 3) alf[i] = *(const bf16x8*)&Al[row * STR + kg];
        }
        #pragma unroll
        for (int j = 0; j < 4; ++j) {
            int row = wn * 64 + j * 16 + fr;
            bfj[j] = *(const bf16x8*)&Bh[row * STR + kg];
            if (XLV == 3) blf[j] = *(const bf16x8*)&Bl[row * STR + kg];
        }
        #pragma unroll
        for (int i = 0; i < AI; ++i)
        #pragma unroll
        for (int j = 0; j < 4; ++j) {
            acc[i][j] = __builtin_amdgcn_mfma_f32_16x16x32_bf16(af[i], bfj[j], acc[i][j], 0, 0, 0);
            if (XLV == 3) {
                acc[i][j] = __builtin_amdgcn_mfma_f32_16x16x32_bf16(af[i],  blf[j], acc[i][j], 0, 0, 0);
                acc[i][j] = __builtin_amdgcn_mfma_f32_16x16x32_bf16(alf[i], bfj[j], acc[i][j], 0, 0, 0);
            }
        }
        __syncthreads();
    }

    #pragma unroll
    for (int i = 0; i < AI; ++i) {
        int rbase = bm + (MT == 64 ? wm * 32 + i * 16 : wm * 16) + ((lane >> 4) << 2);
        #pragma unroll
        for (int j = 0; j < 4; ++j) {
            int ccol = bn + wn * 64 + j * 16 + fr;
            float bv = bias[ccol];
            #pragma unroll
            for (int r = 0; r < 4; ++r) {
                int row = rbase + r;
                if (row < M) {
                    float val = acc[i][j][r] + bv;
                    if (EPI == 1) val = mishf(val);
                    if (EPI == 2) val = fmaxf(val, 0.f);
                    if (SPLIT) {
                        unsigned short hh = f2bf(val);
                        if (ccol < nhl) {
                            Chi[(long long)row * ldhl + ccol] = hh;
                            if (OUTLO)
                                Clo[(long long)row * ldhl + ccol] = f2bf(val - bf2f(hh));
                        } else {
                            int bb = row / 400, m = row - bb * 400;
                            long long vi = ((long long)(bb * 512 + (ccol - 1024))) * 416 + m;
                            vthi[vi] = hh;
                            if (OUTLO)
                                vtlo[vi] = f2bf(val - bf2f(hh));
                        }
                    } else {
                        C[(long long)row * ldc + ccol] = val;
                    }
                }
            }
        }
    }
}

// ---------------------------------------------------------------------------
// Weight prep kernels (write-coalesced). wloEn: write lo half.
// ---------------------------------------------------------------------------
__global__ __launch_bounds__(256) void prep_wqkv(
    const float* __restrict__ wq, const float* __restrict__ wk,
    const float* __restrict__ wv,
    unsigned short* __restrict__ whi, unsigned short* __restrict__ wlo,
    int obase, int total, int wloEn)
{
    int idx = blockIdx.x * 256 + threadIdx.x;
    if (idx >= total) return;
    int o = obase + idx / 786432;
    int rem = idx % 786432;
    int n = rem >> 9, k = rem & 511;
    int sel = n >> 9, col = n & 511;
    const float* W = sel == 0 ? wq : (sel == 1 ? wk : wv);
    float v = W[(long long)o * 262144 + k * 512 + col];
    unsigned short h = f2bf(v);
    whi[idx] = h;
    if (wloEn) wlo[idx] = f2bf(v - bf2f(h));
}

__global__ __launch_bounds__(256) void prep_woiw(
    const float* __restrict__ wo, const float* __restrict__ wi,
    const float* __restrict__ wout,
    unsigned short* __restrict__ whi, unsigned short* __restrict__ wlo,
    int obase, int total, int wloEn)
{
    int idx = blockIdx.x * 256 + threadIdx.x;
    if (idx >= total) return;
    int o = obase + idx / 655360;
    int rem = idx % 655360;
    float v;
    if (rem < 262144) {
        int n = rem >> 9, k = rem & 511;
        v = wo[(long long)o * 262144 + k * 512 + n];
    } else if (rem < 524288) {
        int nk = rem - 262144;
        int n = nk >> 9, k = nk & 511;
        v = wi[(long long)o * 262144 + k * 512 + n];
    } else {
        int nk = rem - 524288;
        int n = nk >> 9, k = nk & 511;   // n < 256
        v = wout[(long long)o * 131072 + k * 256 + n];
    }
    unsigned short h = f2bf(v);
    whi[idx] = h;
    if (wloEn) wlo[idx] = f2bf(v - bf2f(h));
}

__global__ __launch_bounds__(256) void prep_wcnn(
    const float* __restrict__ w,
    unsigned short* __restrict__ whi, unsigned short* __restrict__ wlo)
{
    int idx = blockIdx.x * 256 + threadIdx.x;
    if (idx >= 256 * 768) return;
    int n = idx / 768, k = idx % 768;
    float v = w[k * 256 + n];
    unsigned short h = f2bf(v);
    whi[idx] = h;
    wlo[idx] = f2bf(v - bf2f(h));
}

// ---------------------------------------------------------------------------
// Fused setup
// ---------------------------------------------------------------------------
__global__ __launch_bounds__(256) void setup_kernel(
    const float* __restrict__ x,
    const float* __restrict__ bq, const float* __restrict__ bk,
    const float* __restrict__ bv,
    float* __restrict__ mk, int* __restrict__ relT, int* __restrict__ convidx,
    float* __restrict__ f1pad, float* __restrict__ bqkv,
    unsigned short* __restrict__ vt_hi, unsigned short* __restrict__ vt_lo,
    int nOrg)
{
    int i = blockIdx.x * 256 + threadIdx.x;
    if (i < 3200) {
        const float* xr = x + (long long)i * 128;
        mk[i] = xr[4];
        mk[3200 + i] = fmaxf(xr[2], xr[3]);
        mk[6400 + i] = xr[0];
        mk[9600 + i] = xr[1];
        convidx[i] = (i / 400) * 402 + (i % 400);
    }
    int j = i - 3200;
    if (j >= 0 && j < 799) {
        int rel = j - 399;
        int sgn = (rel > 0) - (rel < 0);
        int ab = (rel < 300 && rel > -300) ? 299 : (rel < 0 ? -rel : rel);
        long long bpos;
        if (ab <= 300) bpos = rel;
        else {
            double lp = ceil(log((double)ab / 300.0) / log(599.0 / 300.0) * 299.0) + 300.0;
            bpos = (long long)lp * sgn;
        }
        long long c2p = bpos + 600;
        c2p = c2p < 0 ? 0 : (c2p > 1199 ? 1199 : c2p);
        relT[j] = (int)c2p;
    }
    int k = i - 4000;
    if (k >= 0 && k < 4096) {
        int b = k >> 9, rem = k & 511;
        int row = b * 402 + (rem < 256 ? 0 : 401);
        f1pad[(long long)row * 256 + (rem & 255)] = 0.f;
    }
    int m = i - 8100;
    if (m >= 0 && m < 6144) {
        int o = m / 1536, n = m % 1536;
        float v;
        if (n < 512) v = bq[o * 512 + n];
        else if (n < 1024) v = bk[o * 512 + n - 512];
        else v = bv[o * 512 + n - 1024];
        bqkv[m] = v;
    }
    int v = i - 14244;
    if (v >= 0 && v < nOrg * 65536) {   // vt pad cols [400..416) zero, as u32
        int og = v >> 16, rem = v & 65535;
        int vb = rem & 32767;
        int row = vb >> 3, c = vb & 7;
        unsigned int* p = (unsigned int*)((rem < 32768) ? vt_hi : vt_lo);
        p[(long long)og * 851968 + row * 208 + 200 + c] = 0u;
    }
}

// ---------------------------------------------------------------------------
// LayerNorm, wave-per-row. Organ-batched (o = row/rpo). RES: split residual.
// OSPL: 0 -> f32 out, 1 -> split hi/lo, 2 -> hi only.
// ---------------------------------------------------------------------------
template<bool RES, int HD, int OSPL>
__global__ __launch_bounds__(256) void ln2_kernel(
    const float* __restrict__ X,
    const unsigned short* __restrict__ Rhi, const unsigned short* __restrict__ Rlo,
    const float* __restrict__ g, const float* __restrict__ be,
    float* __restrict__ Y,
    unsigned short* __restrict__ Yhi, unsigned short* __restrict__ Ylo,
    int rows, int rpo)
{
    constexpr int EPL = HD / 64;
    int wv = threadIdx.x >> 6, lane = threadIdx.x & 63;
    long long row = (long long)blockIdx.x * 4 + wv;
    if (row >= rows) return;
    int o = (int)(row / rpo);
    long long rrow = row % rpo;
    const float* x = X + row * HD;
    float v[EPL];
    #pragma unroll
    for (int q = 0; q < EPL / 4; ++q) {
        float4 a = *(const float4*)&x[lane * EPL + q * 4];
        v[q*4+0] = a.x; v[q*4+1] = a.y; v[q*4+2] = a.z; v[q*4+3] = a.w;
        if (RES) {
            us4 rh = *(const us4*)&Rhi[rrow * HD + lane * EPL + q * 4];
            us4 rl = *(const us4*)&Rlo[rrow * HD + lane * EPL + q * 4];
            #pragma unroll
            for (int e = 0; e < 4; ++e) v[q*4+e] += bf2f(rh[e]) + bf2f(rl[e]);
        }
    }
    float s = 0.f;
    #pragma unroll
    for (int e = 0; e < EPL; ++e) s += v[e];
    #pragma unroll
    for (int d = 1; d < 64; d <<= 1) s += __shfl_xor(s, d, 64);
    float mean = s * (1.f / HD);
    float s2 = 0.f;
    #pragma unroll
    for (int e = 0; e < EPL; ++e) { float d0 = v[e] - mean; s2 += d0 * d0; }
    #pragma unroll
    for (int d = 1; d < 64; d <<= 1) s2 += __shfl_xor(s2, d, 64);
    float inv = 1.f / sqrtf(s2 * (1.f / HD) + 1e-7f);
    #pragma unroll
    for (int q = 0; q < EPL / 4; ++q) {
        int c = lane * EPL + q * 4;
        float4 gg = *(const float4*)&g[o * HD + c];
        float4 bb = *(const float4*)&be[o * HD + c];
        float ov[4];
        ov[0] = (v[q*4+0] - mean) * inv * gg.x + bb.x;
        ov[1] = (v[q*4+1] - mean) * inv * gg.y + bb.y;
        ov[2] = (v[q*4+2] - mean) * inv * gg.z + bb.z;
        ov[3] = (v[q*4+3] - mean) * inv * gg.w + bb.w;
        if (OSPL == 1 || OSPL == 2) {
            us4 ph, pl;
            #pragma unroll
            for (int e = 0; e < 4; ++e) {
                unsigned short hh = f2bf(ov[e]);
                ph[e] = hh;
                pl[e] = f2bf(ov[e] - bf2f(hh));
            }
            *(us4*)&Yhi[row * HD + c] = ph;
            if (OSPL == 1) *(us4*)&Ylo[row * HD + c] = pl;
        } else {
            float4 of; of.x = ov[0]; of.y = ov[1]; of.z = ov[2]; of.w = ov[3];
            *(float4*)&Y[row * HD + c] = of;
        }
    }
}

// ---------------------------------------------------------------------------
// MFMA fused disentangled flash attention (R16 config): HI-ONLY operands,
// single-wave blocks, straight-line clamped loads, zero barriers.
// ctx written hi ONLY (WO runs x1 and never reads ctx-lo).
// Grid (25, 8, 8*nOrg), XCD-swizzled.
// ---------------------------------------------------------------------------
__global__ __launch_bounds__(64) void attn_kernel(
    const unsigned short* __restrict__ qk_hi, const unsigned short* __restrict__ qk_lo,
    const unsigned short* __restrict__ vt_hi, const unsigned short* __restrict__ vt_lo,
    const unsigned short* __restrict__ pkg_hi, const unsigned short* __restrict__ pkg_lo,
    const float* __restrict__ mask,
    unsigned short* __restrict__ ctxh, unsigned short* __restrict__ ctxl)
{
    const float scale = 0.07216878364870322f;       // 1/sqrt(64*3)
    const float NEGMIN = -3.402823466e38f;
    int lin = blockIdx.x + 25 * (blockIdx.y + 8 * blockIdx.z);
    int gz = gridDim.z;
    int xcd = lin & 7, within = lin >> 3;
    int g = within / 25, lt = within - g * 25;
    int combo = xcd * gz + g;
    int h = combo & 7, z = combo >> 3;
    int b = z & 7, o = z >> 3;
    qk_hi  += (long long)o * 3276800;
    vt_hi  += (long long)o * 1703936;
    pkg_hi += (long long)o * 818176;
    mask   += o * 3200;
    ctxh   += (long long)o * 1638400;

    int l0 = lt * 16;
    int lane = threadIdx.x;
    int fr = lane & 15, kg8 = (lane >> 4) << 3, g4 = (lane >> 4) << 2;

    __shared__ float T2c[16 * 36];
    __shared__ float T3c[32 * 20];
    __shared__ unsigned short Sth[16 * 40];

    bf16x8 qf[2];
    {
        long long base = ((long long)(b * 400 + l0 + fr)) * 1024 + h * 64 + kg8;
        #pragma unroll
        for (int kk = 0; kk < 2; ++kk)
            qf[kk] = *(const bf16x8*)(qk_hi + base + kk * 32);
    }
    float wlv_r[4], ms[4], ls[4];
    #pragma unroll
    for (int r = 0; r < 4; ++r) {
        wlv_r[r] = mask[b * 400 + l0 + g4 + r];
        ms[r] = -INFINITY;
        ls[r] = 0.f;
    }
    f32x4 O[4] = {};
    long long vtbase = ((long long)(b * 512 + h * 64)) * 416;

    for (int mt = 0; mt < 13; ++mt) {
        int m0 = mt * 32;
        int D0 = l0 - m0 + 368;
        bf16x8 kf[2][2];
        #pragma unroll
        for (int jf = 0; jf < 2; ++jf) {
            int kr = m0 + jf * 16 + fr;
            kr = kr < 400 ? kr : 399;
            long long base = ((long long)(b * 400 + kr)) * 1024 + 512 + h * 64 + kg8;
            #pragma unroll
            for (int kk = 0; kk < 2; ++kk)
                kf[jf][kk] = *(const bf16x8*)(qk_hi + base + kk * 32);
        }
        bf16x8 b2h[3][2], b3h[3][2];
        #pragma unroll
        for (int c = 0; c < 3; ++c) {
            int dd = D0 + c * 16 + fr;
            dd = dd < 0 ? 0 : (dd > 798 ? 798 : dd);
            long long base = (long long)dd * 1024 + h * 64 + kg8;
            #pragma unroll
            for (int kk = 0; kk < 2; ++kk) {
                b2h[c][kk] = *(const bf16x8*)(pkg_hi + base + 512 + kk * 32);
                b3h[c][kk] = *(const bf16x8*)(pkg_hi + base + kk * 32);
            }
        }
        bf16x8 vf[4];
        #pragma unroll
        for (int f = 0; f < 4; ++f) {
            long long a = vtbase + (long long)(f * 16 + fr) * 416 + m0 + kg8;
            vf[f] = *(const bf16x8*)&vt_hi[a];
        }
        float wm_c[2];
        #pragma unroll
        for (int cf = 0; cf < 2; ++cf) {
            int mg = m0 + cf * 16 + fr;
            mg = mg < 400 ? mg : 399;
            wm_c[cf] = mask[b * 400 + mg];
        }
        __builtin_amdgcn_s_setprio(1);
        f32x4 aT1[2] = {};
        #pragma unroll
        for (int jf = 0; jf < 2; ++jf)
        #pragma unroll
        for (int kk = 0; kk < 2; ++kk)
            aT1[jf] = __builtin_amdgcn_mfma_f32_16x16x32_bf16(qf[kk], kf[jf][kk], aT1[jf], 0, 0, 0);
        f32x4 aT2[3] = {};
        #pragma unroll
        for (int c = 0; c < 3; ++c)
        #pragma unroll
        for (int kk = 0; kk < 2; ++kk)
            aT2[c] = __builtin_amdgcn_mfma_f32_16x16x32_bf16(qf[kk], b2h[c][kk], aT2[c], 0, 0, 0);
        f32x4 aT3[2][2] = {};
        #pragma unroll
        for (int jf = 0; jf < 2; ++jf)
        #pragma unroll
        for (int ci = 0; ci < 2; ++ci) {
            int c = ci + (jf ^ 1);
            #pragma unroll
            for (int kk = 0; kk < 2; ++kk)
                aT3[jf][ci] = __builtin_amdgcn_mfma_f32_16x16x32_bf16(kf[jf][kk], b3h[c][kk], aT3[jf][ci], 0, 0, 0);
        }
        __builtin_amdgcn_s_setprio(0);
        #pragma unroll
        for (int c = 0; c < 3; ++c)
        #pragma unroll
        for (int r = 0; r < 4; ++r) {
            int i = g4 + r;
            int d = c * 16 + fr - i;
            if ((unsigned)d < 32u)
                T2c[i * 36 + d] = aT2[c][r];
        }
        #pragma unroll
        for (int jf = 0; jf < 2; ++jf)
        #pragma unroll
        for (int ci = 0; ci < 2; ++ci) {
            int c = ci + (jf ^ 1);
            #pragma unroll
            for (int r = 0; r < 4; ++r) {
                int j3 = jf * 16 + g4 + r;
                int d2 = c * 16 + fr + j3 - 31;
                if ((unsigned)d2 < 16u)
                    T3c[j3 * 20 + d2] = aT3[jf][ci][r];
            }
        }
        float sc0[4], sc1[4];
        #pragma unroll
        for (int r = 0; r < 4; ++r) {
            int i = g4 + r;
            {
                int j = fr;
                bool jv = (m0 + j) < 400;
                sc0[r] = !jv ? -INFINITY :
                    ((wlv_r[r] != 0.f && wm_c[0] != 0.f) ?
                     (aT1[0][r] + T2c[i * 36 + 31 - j] + T3c[j * 20 + i]) * scale : NEGMIN);
            }
            {
                int j = 16 + fr;
                bool jv = (m0 + j) < 400;
                sc1[r] = !jv ? -INFINITY :
                    ((wlv_r[r] != 0.f && wm_c[1] != 0.f) ?
                     (aT1[1][r] + T2c[i * 36 + 31 - j] + T3c[j * 20 + i]) * scale : NEGMIN);
            }
        }
        float corr[4];
        #pragma unroll
        for (int r = 0; r < 4; ++r) {
            float mx = fmaxf(sc0[r], sc1[r]);
            #pragma unroll
            for (int d = 1; d < 16; d <<= 1) mx = fmaxf(mx, __shfl_xor(mx, d, 64));
            float mn = fmaxf(ms[r], mx);
            corr[r] = __expf(ms[r] - mn);
            ms[r] = mn;
            float p0 = __expf(sc0[r] - mn), p1 = __expf(sc1[r] - mn);
            float rs = p0 + p1;
            #pragma unroll
            for (int d = 1; d < 16; d <<= 1) rs += __shfl_xor(rs, d, 64);
            ls[r] = ls[r] * corr[r] + rs;
            int i = g4 + r;
            Sth[i * 40 + fr] = f2bf(p0);
            Sth[i * 40 + 16 + fr] = f2bf(p1);
        }
        #pragma unroll
        for (int f = 0; f < 4; ++f)
        #pragma unroll
        for (int r = 0; r < 4; ++r) O[f][r] *= corr[r];
        bf16x8 Pha = *(const bf16x8*)&Sth[fr * 40 + kg8];
        __builtin_amdgcn_s_setprio(1);
        #pragma unroll
        for (int f = 0; f < 4; ++f)
            O[f] = __builtin_amdgcn_mfma_f32_16x16x32_bf16(Pha, vf[f], O[f], 0, 0, 0);
        __builtin_amdgcn_s_setprio(0);
    }
    #pragma unroll
    for (int f = 0; f < 4; ++f) {
        int colg = h * 64 + f * 16 + fr;
        #pragma unroll
        for (int r = 0; r < 4; ++r) {
            int lg = l0 + g4 + r;
            float val = O[f][r] / ls[r];
            long long idx = ((long long)(b * 400 + lg)) * 512 + colg;
            ctxh[idx] = f2bf(val);
        }
    }
}

// ---------------------------------------------------------------------------
// Chunked pool / meanmax (full-chip), heads
// ---------------------------------------------------------------------------
__global__ __launch_bounds__(256) void pool_part(
    const float* __restrict__ in, long long inOStride,
    const float* __restrict__ mk, float* __restrict__ pp)
{
    int bi = blockIdx.x, c = blockIdx.y, t = threadIdx.x;
    int o = bi >> 3, b = bi & 7;
    int l0 = c * 31, l1 = min(400, l0 + 31);
    const float* ib = in + (long long)o * inOStride + (long long)(b * 400) * 256;
    const float* mkb = mk + o * 3200 + b * 400;
    float s = 0.f, mx = -INFINITY, sw = 0.f;
    for (int l = l0; l < l1; ++l) {
        float wv = mkb[l];
        float v = ib[(long long)l * 256 + t] * wv;
        s += v; mx = fmaxf(mx, v); sw += wv;
    }
    long long base = (long long)(c * gridDim.x + bi) * 514;
    pp[base + t] = s;
    pp[base + 256 + t] = mx;
    if (t == 0) pp[base + 512] = sw;
}

__global__ __launch_bounds__(256) void pool_merge(
    const float* __restrict__ pp, float* __restrict__ pooled, int nBI)
{
    int bi = blockIdx.x, t = threadIdx.x;
    float s = 0.f, mx = -INFINITY, sw = 0.f;
    for (int c = 0; c < 13; ++c) {
        long long base = (long long)(c * nBI + bi) * 514;
        s += pp[base + t];
        mx = fmaxf(mx, pp[base + 256 + t]);
        sw += pp[base + 512];
    }
    int o = bi >> 3, b = bi & 7;
    pooled[o * 4096 + b * 512 + t] = s / (sw + 1e-6f);
    pooled[o * 4096 + b * 512 + 256 + t] = mx;
}

__global__ __launch_bounds__(512) void mm_part(
    const unsigned short* __restrict__ fh, const unsigned short* __restrict__ fl,
    float* __restrict__ mmp)
{
    int b = blockIdx.x, c = blockIdx.y, t = threadIdx.x;
    int l0 = c * 31, l1 = min(400, l0 + 31);
    float s = 0.f, mx = -INFINITY;
    for (int l = l0; l < l1; ++l) {
        long long idx = ((long long)(b * 400 + l)) * 512 + t;
        float v = bf2f(fh[idx]) + bf2f(fl[idx]);
        s += v; mx = fmaxf(mx, v);
    }
    long long base = (long long)(c * 8 + b) * 1024;
    mmp[base + t] = s;
    mmp[base + 512 + t] = mx;
}

__global__ __launch_bounds__(512) void mm_merge(
    const float* __restrict__ mmp, float* __restrict__ mm)
{
    int b = blockIdx.x, t = threadIdx.x;
    float s = 0.f, mx = -INFINITY;
    for (int c = 0; c < 13; ++c) {
        long long base = (long long)(c * 8 + b) * 1024;
        s += mmp[base + t];
        mx = fmaxf(mx, mmp[base + 512 + t]);
    }
    mm[b * 1024 + t] = s / 400.f;
    mm[b * 1024 + 512 + t] = mx;
}

__global__ __launch_bounds__(256) void heads_kernel(
    const float* __restrict__ pooled, const float* __restrict__ mm,
    const float* __restrict__ w_bow1, const float* __restrict__ b_bow1,
    const float* __restrict__ w_bow2, const float* __restrict__ b_bow2,
    const float* __restrict__ w_ext1, const float* __restrict__ b_ext1,
    const float* __restrict__ w_ext2, const float* __restrict__ b_ext2,
    const float* __restrict__ w_org1, const float* __restrict__ b_org1,
    const float* __restrict__ w_org2, const float* __restrict__ b_org2,
    float* __restrict__ out)
{
    int b = blockIdx.x, role = blockIdx.y;
    int t = threadIdx.x;
    __shared__ float inb[1024];
    __shared__ float red[256];
    __shared__ float hid[256];
    if (role == 0) {
        inb[t] = pooled[b * 512 + t];
        inb[256 + t] = pooled[b * 512 + 256 + t];
        __syncthreads();
        float acc = b_bow1[t];
        for (int j = 0; j < 512; ++j) acc += inb[j] * w_bow1[j * 256 + t];
        red[t] = mishf(acc) * w_bow2[t];
        __syncthreads();
        for (int s = 128; s; s >>= 1) { if (t < s) red[t] += red[t + s]; __syncthreads(); }
        if (t == 0) out[b * 11 + 0] = red[0] + b_bow2[0];
    } else if (role == 1) {
        inb[t] = mm[b * 1024 + t];
        inb[256 + t] = mm[b * 1024 + 256 + t];
        inb[512 + t] = mm[b * 1024 + 512 + t];
        inb[768 + t] = mm[b * 1024 + 768 + t];
        __syncthreads();
        float acc = b_ext1[t];
        for (int j = 0; j < 1024; ++j) acc += inb[j] * w_ext1[j * 256 + t];
        red[t] = mishf(acc) * w_ext2[t];
        __syncthreads();
        for (int s = 128; s; s >>= 1) { if (t < s) red[t] += red[t + s]; __syncthreads(); }
        if (t == 0) { out[b * 11 + 1] = red[0] + b_ext2[0]; out[88 + b] = 0.f; }
    } else {
        int i = role - 2;
        inb[t] = pooled[((1 + i) * 8 + b) * 512 + t];
        inb[256 + t] = pooled[((1 + i) * 8 + b) * 512 + 256 + t];
        __syncthreads();
        float acc = b_org1[i * 256 + t];
        for (int j = 0; j < 512; ++j)
            acc += inb[j] * w_org1[((long long)i * 512 + j) * 256 + t];
        hid[t] = mishf(acc);
        __syncthreads();
        for (int c = 0; c < 3; ++c) {
            red[t] = hid[t] * w_org2[(i * 256 + t) * 3 + c];
            __syncthreads();
            for (int s = 128; s; s >>= 1) { if (t < s) red[t] += red[t + s]; __syncthreads(); }
            if (t == 0) out[b * 11 + 2 + i * 3 + c] = red[0] + b_org2[i * 3 + c];
            __syncthreads();
        }
    }
}

// ---------------------------------------------------------------------------
// Launch
// ---------------------------------------------------------------------------
extern "C" void kernel_launch(void* const* d_in, const int* in_sizes, int n_in,
                              void* d_out, int out_size, void* d_ws, size_t ws_size,
                              hipStream_t stream)
{
    const float* x      = (const float*)d_in[0];
    const float* w_mlp  = (const float*)d_in[1];
    const float* b_mlp  = (const float*)d_in[2];
    const float* w_cnn  = (const float*)d_in[3];
    const float* b_cnn  = (const float*)d_in[4];
    const float* rel_emb= (const float*)d_in[5];
    const float* rel_g  = (const float*)d_in[6];
    const float* rel_b  = (const float*)d_in[7];
    const float* wq     = (const float*)d_in[8];
    const float* wk     = (const float*)d_in[9];
    const float* wv     = (const float*)d_in[10];
    const float* wo     = (const float*)d_in[11];
    const float* wi     = (const float*)d_in[12];
    const float* bq     = (const float*)d_in[13];
    const float* bk     = (const float*)d_in[14];
    const float* bv     = (const float*)d_in[15];
    const float* bo     = (const float*)d_in[16];
    const float* bi     = (const float*)d_in[17];
    const float* wout   = (const float*)d_in[18];
    const float* bout   = (const float*)d_in[19];
    const float* ln1g   = (const float*)d_in[20];
    const float* ln1b   = (const float*)d_in[21];
    const float* ln2g   = (const float*)d_in[22];
    const float* ln2b   = (const float*)d_in[23];
    const float* w_bow1 = (const float*)d_in[24];
    const float* b_bow1 = (const float*)d_in[25];
    const float* w_bow2 = (const float*)d_in[26];
    const float* b_bow2 = (const float*)d_in[27];
    const float* w_ext1 = (const float*)d_in[28];
    const float* b_ext1 = (const float*)d_in[29];
    const float* w_ext2 = (const float*)d_in[30];
    const float* b_ext2 = (const float*)d_in[31];
    const float* w_org1 = (const float*)d_in[32];
    const float* b_org1 = (const float*)d_in[33];
    const float* w_org2 = (const float*)d_in[34];
    const float* b_org2 = (const float*)d_in[35];

    float* ws = (float*)d_ws;
    float* outf = (float*)d_out;
    const bool big = ws_size >= 143012736ull;

    if (big) {
        // ---------------- organ-batched path ----------------
        unsigned short* featsh = (unsigned short*)(ws + 0);        // 3200x512
        unsigned short* featsl = (unsigned short*)(ws + 819200);
        float* ctxR     = ws + 1638400;      // 6,553,600 fl
        float* f1pad    = ctxR;
        unsigned short* ctxh = (unsigned short*)ctxR;              // 4x3200x512
        unsigned short* ctxl = (unsigned short*)(ws + 4915200);
        float* qkA_f    = ws + 8192000;
        float* qkB_f    = ws + 14745600;
        unsigned short* qkA = (unsigned short*)qkA_f;
        unsigned short* qkB = (unsigned short*)qkB_f;
        unsigned short* rellnh = (unsigned short*)qkA_f;           // 4800x512
        unsigned short* rellnl = (unsigned short*)(ws + 8192000 + 1228800);
        unsigned short* vtA = (unsigned short*)(ws + 21299200);    // 4x4096x416
        unsigned short* vtB = (unsigned short*)(ws + 24707072);
        unsigned short* pkgA = (unsigned short*)(ws + 28114944);   // 4x799x1024
        unsigned short* pkgB = (unsigned short*)(ws + 29751296);
        unsigned short* whiA = (unsigned short*)(ws + 31387648);   // 4x786,432
        unsigned short* wloA = (unsigned short*)(ws + 32960512);
        unsigned short* wcnn_hi = (unsigned short*)(ws + 35188736);
        unsigned short* wcnn_lo = (unsigned short*)(ws + 35287040);
        float* bqkvb   = ws + 35385344;
        float* masksb  = ws + 35391488;
        float* pooledb = ws + 35404288;
        float* mmb     = ws + 35420672;
        int*   relidx  = (int*)(ws + 35428864);
        int*   convidx = (int*)(ws + 35429664);
        float* poolpart= ws + 35432864;
        float* mmpart  = ws + 35646688;
        float* tmp_all   = qkA_f;                                  // WO out (f32)
        unsigned short* h1h = (unsigned short*)qkB_f;              // LN1 out hi
        unsigned short* interh = (unsigned short*)qkA_f;           // WI out hi
        float* outenc_all = (float*)vtA;                           // 4x819,200 f32
        float* outln_all  = ctxR;                                  // 4x819,200 f32
        unsigned short* whiB_all = whiA;
        unsigned short* wloB_all = wloA;

        gemm_bias<1><<<dim3(4, 50), 256, 0, stream>>>(
            x, w_mlp, b_mlp, f1pad, featsh, featsl, 3200, 256, 128, 512);
        setup_kernel<<<1080, 256, 0, stream>>>(x, bq, bk, bv, masksb, relidx, convidx,
                                               f1pad, bqkvb, vtA, vtB, 4);
        prep_wcnn<<<768, 256, 0, stream>>>(w_cnn, wcnn_hi, wcnn_lo);
        gemm_mfma<2, true, 0, true, 32, false, 3, true><<<dim3(2, 100), 256, 0, stream>>>(
            f1pad, nullptr, nullptr, wcnn_hi, wcnn_lo, b_cnn, nullptr,
            3200, 768, 256, 0, convidx, featsh + 256, featsl + 256, 512, 1 << 30,
            nullptr, nullptr, 0, 0, 0, 0, 0, 0);

        ln2_kernel<false, 512, 1><<<1200, 256, 0, stream>>>(
            rel_emb, nullptr, nullptr, rel_g, rel_b, nullptr, rellnh, rellnl, 4800, 1200);
        prep_wqkv<<<12288, 256, 0, stream>>>(wq, wk, wv, whiA, wloA, 0, 3145728, 0);
        gemm_mfma<0, true, 1, true, 64, true, 1, false><<<dim3(8, 13, 4), 256, 0, stream>>>(
            nullptr, rellnh, rellnl, whiA, wloA, bqkvb, nullptr, 799, 512, 512, 0, relidx,
            pkgA, pkgB, 1024, 1024, nullptr, nullptr,
            614400, 786432, 1536, 0, 818176, 0);
        gemm_mfma<0, false, 1, true, 64, true, 1, false><<<dim3(12, 50, 4), 256, 0, stream>>>(
            nullptr, featsh, featsl, whiA, wloA, bqkvb, nullptr, 3200, 512, 512, 0, nullptr,
            qkA, qkB, 1024, 1024, vtA, vtB,
            0, 786432, 1536, 0, 3276800, 1703936);
        prep_woiw<<<10240, 256, 0, stream>>>(wo, wi, wout, whiB_all, wloB_all,
                                             0, 2621440, 0);
        attn_kernel<<<dim3(25, 8, 32), 64, 0, stream>>>(qkA, qkB, vtA, vtB,
            pkgA, pkgB, masksb, ctxh, ctxl);
        // WO (x1) -> tmp f32
        gemm_mfma<0, false, 1, false, 32, true, 1, false><<<dim3(4, 100, 4), 256, 0, stream>>>(
            nullptr, ctxh, ctxl, whiB_all, wloB_all, bo, tmp_all,
            3200, 512, 512, 512, nullptr, nullptr, nullptr, 0, 0, nullptr, nullptr,
            1638400, 655360, 512, 1638400, 0, 0);
        // LN1 -> h1 hi only
        ln2_kernel<true, 512, 2><<<3200, 256, 0, stream>>>(
            tmp_all, featsh, featsl, ln1g, ln1b, nullptr, h1h, nullptr, 12800, 3200);
        // WI mish (x1) -> inter hi only
        gemm_mfma<1, false, 1, true, 32, true, 1, false><<<dim3(4, 100, 4), 256, 0, stream>>>(
            nullptr, h1h, nullptr, whiB_all + 262144, wloB_all + 262144, bi, nullptr,
            3200, 512, 512, 0, nullptr, interh, nullptr, 512, 1 << 30, nullptr, nullptr,
            1638400, 655360, 512, 0, 1638400, 0);
        // WOUT (x1) -> outenc f32
        gemm_mfma<0, false, 1, false, 32, true, 1, false><<<dim3(2, 100, 4), 256, 0, stream>>>(
            nullptr, interh, nullptr, whiB_all + 524288, wloB_all + 524288, bout, outenc_all,
            3200, 512, 512, 256, nullptr, nullptr, nullptr, 0, 0, nullptr, nullptr,
            1638400, 655360, 256, 819200, 0, 0);
        ln2_kernel<false, 256, 0><<<3200, 256, 0, stream>>>(
            outenc_all, nullptr, nullptr, ln2g, ln2b, outln_all, nullptr, nullptr,
            12800, 3200);

        pool_part<<<dim3(32, 13), 256, 0, stream>>>(outln_all, 819200, masksb, poolpart);
        pool_merge<<<32, 256, 0, stream>>>(poolpart, pooledb, 32);
        mm_part<<<dim3(8, 13), 512, 0, stream>>>(featsh, featsl, mmpart);
        mm_merge<<<8, 512, 0, stream>>>(mmpart, mmb);
        heads_kernel<<<dim3(8, 5), 256, 0, stream>>>(pooledb, mmb,
            w_bow1, b_bow1, w_bow2, b_bow2, w_ext1, b_ext1, w_ext2, b_ext2,
            w_org1, b_org1, w_org2, b_org2, outf);
        return;
    }

    // ---------------- per-organ fallback path ----------------
    unsigned short* featsh = (unsigned short*)(ws + 0);
    unsigned short* featsl = (unsigned short*)(ws + 819200);
    float* ctxR    = ws + 1638400;
    float* f1pad   = ctxR;
    unsigned short* ctxh = (unsigned short*)ctxR;
    unsigned short* ctxl = (unsigned short*)(ws + 1638400 + 819200);
    float* qkvA_f  = ws + 3276800;
    float* qkvB_f  = ws + 4915200;
    unsigned short* qkv_hi = (unsigned short*)qkvA_f;
    unsigned short* qkv_lo = (unsigned short*)qkvB_f;
    unsigned short* rellnh = (unsigned short*)qkvB_f;
    unsigned short* rellnl = (unsigned short*)(ws + 4915200 + 307200);
    unsigned short* pkg_hi = (unsigned short*)(ws + 6553600);
    unsigned short* pkg_lo = (unsigned short*)(ws + 6963200);
    unsigned short* vt_hi  = (unsigned short*)(ws + 7372800);
    unsigned short* vt_lo  = (unsigned short*)(ws + 8224768);
    unsigned short* whi    = (unsigned short*)(ws + 9076736);
    unsigned short* wlo    = (unsigned short*)(ws + 9469952);
    float* bqkvb   = ws + 9863168;
    float* masksb  = ws + 9869312;
    float* pooledb = ws + 9882112;
    float* mmb     = ws + 9898496;
    int*   relidx  = (int*)(ws + 9906688);
    unsigned short* wcnn_hi = (unsigned short*)(ws + 9907488);
    unsigned short* wcnn_lo = (unsigned short*)(ws + 10005792);
    int*   convidx = (int*)(ws + 10104096);
    float* poolpart= ws + 10107296;
    float* mmpart  = ws + 10160752;
    float* tmp     = qkvA_f;
    unsigned short* h1h = (unsigned short*)qkvB_f;
    unsigned short* interh = (unsigned short*)qkvA_f;
    float* outenc  = (float*)vt_hi;
    float* outln   = ctxR;

    gemm_bias<1><<<dim3(4, 50), 256, 0, stream>>>(
        x, w_mlp, b_mlp, f1pad, featsh, featsl, 3200, 256, 128, 512);
    setup_kernel<<<312, 256, 0, stream>>>(x, bq, bk, bv, masksb, relidx, convidx,
                                          f1pad, bqkvb, vt_hi, vt_lo, 1);
    prep_wcnn<<<768, 256, 0, stream>>>(w_cnn, wcnn_hi, wcnn_lo);
    gemm_mfma<2, true, 0, true, 32, false, 3, true><<<dim3(2, 100), 256, 0, stream>>>(
        f1pad, nullptr, nullptr, wcnn_hi, wcnn_lo, b_cnn, nullptr,
        3200, 768, 256, 0, convidx, featsh + 256, featsl + 256, 512, 1 << 30,
        nullptr, nullptr, 0, 0, 0, 0, 0, 0);

    for (int o = 0; o < 4; ++o) {
        ln2_kernel<false, 512, 1><<<300, 256, 0, stream>>>(
            rel_emb + (long long)o * 614400, nullptr, nullptr,
            rel_g + o * 512, rel_b + o * 512, nullptr, rellnh, rellnl, 1200, 1200);
        prep_wqkv<<<3072, 256, 0, stream>>>(wq, wk, wv, whi, wlo, o, 786432, 0);
        gemm_mfma<0, true, 1, true, 64, true, 1, false><<<dim3(8, 13), 256, 0, stream>>>(
            nullptr, rellnh, rellnl, whi, wlo, bqkvb + o * 1536, nullptr,
            799, 512, 512, 0, relidx, pkg_hi, pkg_lo, 1024, 1024, nullptr, nullptr,
            0, 0, 0, 0, 0, 0);
        gemm_mfma<0, false, 1, true, 64, true, 1, false><<<dim3(12, 50), 256, 0, stream>>>(
            nullptr, featsh, featsl, whi, wlo, bqkvb + o * 1536, nullptr,
            3200, 512, 512, 0, nullptr, qkv_hi, qkv_lo, 1024, 1024, vt_hi, vt_lo,
            0, 0, 0, 0, 0, 0);
        prep_woiw<<<2560, 256, 0, stream>>>(wo, wi, wout, whi, wlo, o, 655360, 0);
        attn_kernel<<<dim3(25, 8, 8), 64, 0, stream>>>(qkv_hi, qkv_lo, vt_hi, vt_lo,
            pkg_hi, pkg_lo, masksb + o * 3200, ctxh, ctxl);
        gemm_mfma<0, false, 1, false, 32, true, 1, false><<<dim3(4, 100), 256, 0, stream>>>(
            nullptr, ctxh, ctxl, whi, wlo, bo + o * 512, tmp,
            3200, 512, 512, 512, nullptr, nullptr, nullptr, 0, 0, nullptr, nullptr,
            0, 0, 0, 0, 0, 0);
        ln2_kernel<true, 512, 2><<<800, 256, 0, stream>>>(
            tmp, featsh, featsl, ln1g + o * 512, ln1b + o * 512, nullptr,
            h1h, nullptr, 3200, 3200);
        gemm_mfma<1, false, 1, true, 32, true, 1, false><<<dim3(4, 100), 256, 0, stream>>>(
            nullptr, h1h, nullptr, whi + 262144, wlo + 262144, bi + o * 512, nullptr,
            3200, 512, 512, 0, nullptr, interh, nullptr, 512, 1 << 30, nullptr, nullptr,
            0, 0, 0, 0, 0, 0);
        gemm_mfma<0, false, 1, false, 32, true, 1, false><<<dim3(2, 100), 256, 0, stream>>>(
            nullptr, interh, nullptr, whi + 524288, wlo + 524288, bout + o * 256, outenc,
            3200, 512, 512, 256, nullptr, nullptr, nullptr, 0, 0, nullptr, nullptr,
            0, 0, 0, 0, 0, 0);
        ln2_kernel<false, 256, 0><<<800, 256, 0, stream>>>(
            outenc, nullptr, nullptr, ln2g + o * 256, ln2b + o * 256, outln,
            nullptr, nullptr, 3200, 3200);
        pool_part<<<dim3(8, 13), 256, 0, stream>>>(outln, 0,
                                                   masksb + o * 3200, poolpart);
        pool_merge<<<8, 256, 0, stream>>>(poolpart, pooledb + o * 4096, 8);
    }

    mm_part<<<dim3(8, 13), 512, 0, stream>>>(featsh, featsl, mmpart);
    mm_merge<<<8, 512, 0, stream>>>(mmpart, mmb);
    heads_kernel<<<dim3(8, 5), 256, 0, stream>>>(pooledb, mmb,
        w_bow1, b_bow1, w_bow2, b_bow2, w_ext1, b_ext1, w_ext2, b_ext2,
        w_org1, b_org1, w_org2, b_org2, outf);
}

// Round 19
// 464.545 us; speedup vs baseline: 1.5566x; 1.0884x over previous
//
#include <hip/hip_runtime.h>
#include <math.h>

// ---------------------------------------------------------------------------
// Model dims (fixed): B=8 L=400 F=128 D=256 T=256 H=512 NH=8 HD=64 P=1200
// ---------------------------------------------------------------------------

typedef __attribute__((ext_vector_type(8))) short bf16x8;
typedef __attribute__((ext_vector_type(4))) float f32x4;
typedef __attribute__((ext_vector_type(4))) unsigned int u32x4;
typedef __attribute__((ext_vector_type(4))) unsigned short us4;

__device__ __forceinline__ float mishf(float x) {
    float sp = fmaxf(x, 0.f) + log1pf(expf(-fabsf(x)));   // stable softplus
    return x * tanhf(sp);
}

__device__ __forceinline__ unsigned short f2bf(float f) {
    unsigned int u = __float_as_uint(f);
    u = (u + 0x7fffu + ((u >> 16) & 1u)) >> 16;           // RNE
    return (unsigned short)u;
}
__device__ __forceinline__ float bf2f(unsigned short h) {
    return __uint_as_float(((unsigned int)h) << 16);
}

// async global->LDS 16B per lane; dst is wave-uniform base (+ lane*16 in HW)
__device__ __forceinline__ void gll16(const unsigned short* g, unsigned short* l) {
    __builtin_amdgcn_global_load_lds(
        (const __attribute__((address_space(1))) void*)g,
        (__attribute__((address_space(3))) void*)l, 16, 0, 0);
}

// ---------------------------------------------------------------------------
// fp32 GEMM (front MLP, K=128): writes f1pad (padded conv layout) + split
// bf16 hi/lo feats (cols 0..255 of 512-wide).
// ---------------------------------------------------------------------------
template<int EPI>
__global__ __launch_bounds__(256) void gemm_bias(
    const float* __restrict__ A, const float* __restrict__ Bm,
    const float* __restrict__ bias, float* __restrict__ C2,
    unsigned short* __restrict__ fhi, unsigned short* __restrict__ flo,
    int M, int N, int K, int ldc)
{
    __shared__ float As[16][68];
    __shared__ float Bs[16][68];
    int bm = blockIdx.y << 6, bn = blockIdx.x << 6;
    int tid = threadIdx.x;
    int tm = (tid >> 4) << 2, tn = (tid & 15) << 2;
    int ar = tid >> 2, ac4 = (tid & 3) << 2;
    int br = tid >> 4, bc4 = (tid & 15) << 2;
    float acc[4][4] = {};
    for (int k0 = 0; k0 < K; k0 += 16) {
        float4 av = make_float4(0.f, 0.f, 0.f, 0.f);
        if (bm + ar < M)
            av = *(const float4*)&A[(long long)(bm + ar) * K + k0 + ac4];
        As[ac4][ar] = av.x; As[ac4 + 1][ar] = av.y;
        As[ac4 + 2][ar] = av.z; As[ac4 + 3][ar] = av.w;
        *(float4*)&Bs[br][bc4] =
            *(const float4*)&Bm[(long long)(k0 + br) * N + bn + bc4];
        __syncthreads();
        #pragma unroll
        for (int kk = 0; kk < 16; ++kk) {
            float4 a4 = *(const float4*)&As[kk][tm];
            float4 b4 = *(const float4*)&Bs[kk][tn];
            acc[0][0] += a4.x * b4.x; acc[0][1] += a4.x * b4.y;
            acc[0][2] += a4.x * b4.z; acc[0][3] += a4.x * b4.w;
            acc[1][0] += a4.y * b4.x; acc[1][1] += a4.y * b4.y;
            acc[1][2] += a4.y * b4.z; acc[1][3] += a4.y * b4.w;
            acc[2][0] += a4.z * b4.x; acc[2][1] += a4.z * b4.y;
            acc[2][2] += a4.z * b4.z; acc[2][3] += a4.z * b4.w;
            acc[3][0] += a4.w * b4.x; acc[3][1] += a4.w * b4.y;
            acc[3][2] += a4.w * b4.z; acc[3][3] += a4.w * b4.w;
        }
        __syncthreads();
    }
    #pragma unroll
    for (int i = 0; i < 4; ++i) {
        int r = bm + tm + i;
        if (r < M) {
            float v[4];
            #pragma unroll
            for (int q = 0; q < 4; ++q) {
                v[q] = acc[i][q] + bias[bn + tn + q];
                if (EPI == 1) v[q] = mishf(v[q]);
            }
            float4 o; o.x = v[0]; o.y = v[1]; o.z = v[2]; o.w = v[3];
            int rr2 = (r / 400) * 402 + (r % 400) + 1;
            *(float4*)&C2[(long long)rr2 * 256 + bn + tn] = o;
            us4 ph, pl;
            #pragma unroll
            for (int q = 0; q < 4; ++q) {
                unsigned short hh = f2bf(v[q]);
                ph[q] = hh;
                pl[q] = f2bf(v[q] - bf2f(hh));
            }
            *(us4*)&fhi[(long long)r * ldc + bn + tn] = ph;
            *(us4*)&flo[(long long)r * ldc + bn + tn] = pl;
        }
    }
}

// ---------------------------------------------------------------------------
// MFMA bf16 GEMM. B pre-transposed+split [N][K] bf16 hi/lo.
// AMODE: 0 = A fp32 (split per tile), 1 = A pre-split hi/lo.
// XLV: 3 = x3-split (fp32-accurate), 1 = hi-only single MFMA.
// GLL: stage A/B via global_load_lds (async, unpadded stride-32 LDS).
// SPLIT out: cols<nhl -> Chi(/Clo if OUTLO); cols>=1024 -> V transposed (416).
// EPI: 0 none, 1 mish, 2 relu.
// ---------------------------------------------------------------------------
template<int EPI, bool GATHER, int AMODE, bool SPLIT, int MT, bool GLL,
         int XLV, bool OUTLO>
__global__ __launch_bounds__(256) void gemm_mfma(
    const float* __restrict__ A,
    const unsigned short* __restrict__ Ahi, const unsigned short* __restrict__ Alo,
    const unsigned short* __restrict__ Bth, const unsigned short* __restrict__ Btl,
    const float* __restrict__ bias, float* __restrict__ C,
    int M, int K, int lda, int ldc, const int* __restrict__ gidx,
    unsigned short* __restrict__ Chi, unsigned short* __restrict__ Clo,
    int ldhl, int nhl,
    unsigned short* __restrict__ vthi, unsigned short* __restrict__ vtlo,
    long long zA, int zB, int zBias, int zC, int zChi, int zVt)
{
    constexpr int AI = MT / 32;
    constexpr int STR = GLL ? 32 : 40;
    __shared__ unsigned short Ah[MT * STR];
    __shared__ unsigned short Al[(XLV == 3) ? MT * STR : 16];
    __shared__ unsigned short Bh[128 * STR];
    __shared__ unsigned short Bl[(XLV == 3) ? 128 * STR : 16];

    long long zz = blockIdx.z;
    if (AMODE == 0) A += zz * zA;
    else { Ahi += zz * zA; Alo += zz * zA; }
    Bth  += zz * (long long)zB;  Btl += zz * (long long)zB;
    bias += zz * (long long)zBias;
    C    += zz * (long long)zC;
    if (SPLIT) {
        Chi += zz * (long long)zChi; Clo += zz * (long long)zChi;
        vthi += zz * (long long)zVt; vtlo += zz * (long long)zVt;
    }

    int bm = blockIdx.y * MT, bn = blockIdx.x << 7;
    int tid = threadIdx.x;
    int lane = tid & 63, wid = tid >> 6;
    int wm = wid >> 1, wn = wid & 1;
    int fr = lane & 15, kg = (lane >> 4) << 3;

    // ---- GLL staging descriptors (wave-uniform dst, per-lane src) ----
    const unsigned short *aSrcH = nullptr, *aSrcL = nullptr;
    const unsigned short *bSrcH0 = nullptr, *bSrcL0 = nullptr;
    const unsigned short *bSrcH1 = nullptr, *bSrcL1 = nullptr;
    unsigned short *dstAh = nullptr, *dstAl = nullptr;
    unsigned short *dstBh0 = nullptr, *dstBl0 = nullptr;
    unsigned short *dstBh1 = nullptr, *dstBl1 = nullptr;
    bool doA = false;
    if (GLL) {
        int seg = (lane & 3) << 3;
        if (wid < MT / 16) {
            doA = true;
            int grow = bm + wid * 16 + (lane >> 2);
            grow = grow < M ? grow : (M - 1);
            long long arw = GATHER ? (long long)gidx[grow] : (long long)grow;
            aSrcH = Ahi + arw * lda + seg;
            aSrcL = Alo + arw * lda + seg;
            dstAh = &Ah[wid * 512];
            dstAl = &Al[(XLV == 3) ? wid * 512 : 0];
        }
        int br0 = bn + wid * 16 + (lane >> 2);
        int br1 = bn + (4 + wid) * 16 + (lane >> 2);
        bSrcH0 = Bth + (long long)br0 * K + seg;
        bSrcH1 = Bth + (long long)br1 * K + seg;
        bSrcL0 = Btl + (long long)br0 * K + seg;
        bSrcL1 = Btl + (long long)br1 * K + seg;
        dstBh0 = &Bh[wid * 512];       dstBh1 = &Bh[(4 + wid) * 512];
        dstBl0 = &Bl[(XLV == 3) ? wid * 512 : 0];
        dstBl1 = &Bl[(XLV == 3) ? (4 + wid) * 512 : 0];
    }

    // ---- legacy staging coords (non-GLL) ----
    int ar = tid >> 2, akc = (tid & 3) << 3;
    int bnr = tid >> 1, bkc = (tid & 1) << 4;
    bool astage = ar < MT;
    long long arow = 0; bool avalid = false;
    if (!GLL && astage) {
        int gr = bm + ar;
        avalid = gr < M;
        if (GATHER) arow = avalid ? (long long)gidx[gr] : 0;
        else        arow = avalid ? (long long)gr : 0;
    }

    f32x4 acc[AI][4] = {};

    for (int k0 = 0; k0 < K; k0 += 32) {
        if (GLL) {
            if (doA) {
                gll16(aSrcH + k0, dstAh);
                if (XLV == 3) gll16(aSrcL + k0, dstAl);
            }
            gll16(bSrcH0 + k0, dstBh0);
            gll16(bSrcH1 + k0, dstBh1);
            if (XLV == 3) {
                gll16(bSrcL0 + k0, dstBl0);
                gll16(bSrcL1 + k0, dstBl1);
            }
        } else {
            if (astage) {
                if (AMODE == 0) {
                    float vv[8];
                    if (avalid) {
                        float4 v0 = *(const float4*)&A[arow * lda + k0 + akc];
                        float4 v1 = *(const float4*)&A[arow * lda + k0 + akc + 4];
                        vv[0] = v0.x; vv[1] = v0.y; vv[2] = v0.z; vv[3] = v0.w;
                        vv[4] = v1.x; vv[5] = v1.y; vv[6] = v1.z; vv[7] = v1.w;
                    } else {
                        #pragma unroll
                        for (int e = 0; e < 8; ++e) vv[e] = 0.f;
                    }
                    union { unsigned short u[8]; u32x4 v; } ph, pl;
                    #pragma unroll
                    for (int e = 0; e < 8; ++e) {
                        unsigned short h = f2bf(vv[e]);
                        ph.u[e] = h;
                        pl.u[e] = f2bf(vv[e] - bf2f(h));
                    }
                    *(u32x4*)&Ah[ar * STR + akc] = ph.v;
                    if (XLV == 3) *(u32x4*)&Al[ar * STR + akc] = pl.v;
                } else {
                    u32x4 zv = {0u, 0u, 0u, 0u};
                    u32x4 vh = zv, vl = zv;
                    if (avalid) {
                        vh = *(const u32x4*)&Ahi[arow * lda + k0 + akc];
                        if (XLV == 3) vl = *(const u32x4*)&Alo[arow * lda + k0 + akc];
                    }
                    *(u32x4*)&Ah[ar * STR + akc] = vh;
                    if (XLV == 3) *(u32x4*)&Al[ar * STR + akc] = vl;
                }
            }
            long long boff = (long long)(bn + bnr) * K + k0 + bkc;
            *(u32x4*)&Bh[bnr * STR + bkc]     = *(const u32x4*)&Bth[boff];
            *(u32x4*)&Bh[bnr * STR + bkc + 8] = *(const u32x4*)&Bth[boff + 8];
            if (XLV == 3) {
                *(u32x4*)&Bl[bnr * STR + bkc]     = *(const u32x4*)&Btl[boff];
                *(u32x4*)&Bl[bnr * STR + bkc + 8] = *(const u32x4*)&Btl[boff + 8];
            }
        }
        __syncthreads();

        bf16x8 af[AI], alf[AI], bfj[4], blf[4];
        #pragma unroll
        for (int i = 0; i < AI; ++i) {
            int row = (MT == 64 ? wm * 32 + i * 16 : wm * 16) + fr;
            af[i]  = *(const bf16x8*)&Ah[row * STR + kg];
            if (XLV == 3) alf[i] = *(const bf16x8*)&Al[row * STR + kg];
        }
        #pragma unroll
        for (int j = 0; j < 4; ++j) {
            int row = wn * 64 + j * 16 + fr;
            bfj[j] = *(const bf16x8*)&Bh[row * STR + kg];
            if (XLV == 3) blf[j] = *(const bf16x8*)&Bl[row * STR + kg];
        }
        #pragma unroll
        for (int i = 0; i < AI; ++i)
        #pragma unroll
        for (int j = 0; j < 4; ++j) {
            acc[i][j] = __builtin_amdgcn_mfma_f32_16x16x32_bf16(af[i], bfj[j], acc[i][j], 0, 0, 0);
            if (XLV == 3) {
                acc[i][j] = __builtin_amdgcn_mfma_f32_16x16x32_bf16(af[i],  blf[j], acc[i][j], 0, 0, 0);
                acc[i][j] = __builtin_amdgcn_mfma_f32_16x16x32_bf16(alf[i], bfj[j], acc[i][j], 0, 0, 0);
            }
        }
        __syncthreads();
    }

    #pragma unroll
    for (int i = 0; i < AI; ++i) {
        int rbase = bm + (MT == 64 ? wm * 32 + i * 16 : wm * 16) + ((lane >> 4) << 2);
        #pragma unroll
        for (int j = 0; j < 4; ++j) {
            int ccol = bn + wn * 64 + j * 16 + fr;
            float bv = bias[ccol];
            #pragma unroll
            for (int r = 0; r < 4; ++r) {
                int row = rbase + r;
                if (row < M) {
                    float val = acc[i][j][r] + bv;
                    if (EPI == 1) val = mishf(val);
                    if (EPI == 2) val = fmaxf(val, 0.f);
                    if (SPLIT) {
                        unsigned short hh = f2bf(val);
                        if (ccol < nhl) {
                            Chi[(long long)row * ldhl + ccol] = hh;
                            if (OUTLO)
                                Clo[(long long)row * ldhl + ccol] = f2bf(val - bf2f(hh));
                        } else {
                            int bb = row / 400, m = row - bb * 400;
                            long long vi = ((long long)(bb * 512 + (ccol - 1024))) * 416 + m;
                            vthi[vi] = hh;
                            if (OUTLO)
                                vtlo[vi] = f2bf(val - bf2f(hh));
                        }
                    } else {
                        C[(long long)row * ldc + ccol] = val;
                    }
                }
            }
        }
    }
}

// ---------------------------------------------------------------------------
// Weight prep kernels (write-coalesced). wloEn: write lo half.
// ---------------------------------------------------------------------------
__global__ __launch_bounds__(256) void prep_wqkv(
    const float* __restrict__ wq, const float* __restrict__ wk,
    const float* __restrict__ wv,
    unsigned short* __restrict__ whi, unsigned short* __restrict__ wlo,
    int obase, int total, int wloEn)
{
    int idx = blockIdx.x * 256 + threadIdx.x;
    if (idx >= total) return;
    int o = obase + idx / 786432;
    int rem = idx % 786432;
    int n = rem >> 9, k = rem & 511;
    int sel = n >> 9, col = n & 511;
    const float* W = sel == 0 ? wq : (sel == 1 ? wk : wv);
    float v = W[(long long)o * 262144 + k * 512 + col];
    unsigned short h = f2bf(v);
    whi[idx] = h;
    if (wloEn) wlo[idx] = f2bf(v - bf2f(h));
}

__global__ __launch_bounds__(256) void prep_woiw(
    const float* __restrict__ wo, const float* __restrict__ wi,
    const float* __restrict__ wout,
    unsigned short* __restrict__ whi, unsigned short* __restrict__ wlo,
    int obase, int total, int wloEn)
{
    int idx = blockIdx.x * 256 + threadIdx.x;
    if (idx >= total) return;
    int o = obase + idx / 655360;
    int rem = idx % 655360;
    float v;
    if (rem < 262144) {
        int n = rem >> 9, k = rem & 511;
        v = wo[(long long)o * 262144 + k * 512 + n];
    } else if (rem < 524288) {
        int nk = rem - 262144;
        int n = nk >> 9, k = nk & 511;
        v = wi[(long long)o * 262144 + k * 512 + n];
    } else {
        int nk = rem - 524288;
        int n = nk >> 9, k = nk & 511;   // n < 256
        v = wout[(long long)o * 131072 + k * 256 + n];
    }
    unsigned short h = f2bf(v);
    whi[idx] = h;
    if (wloEn) wlo[idx] = f2bf(v - bf2f(h));
}

__global__ __launch_bounds__(256) void prep_wcnn(
    const float* __restrict__ w,
    unsigned short* __restrict__ whi, unsigned short* __restrict__ wlo)
{
    int idx = blockIdx.x * 256 + threadIdx.x;
    if (idx >= 256 * 768) return;
    int n = idx / 768, k = idx % 768;
    float v = w[k * 256 + n];
    unsigned short h = f2bf(v);
    whi[idx] = h;
    wlo[idx] = f2bf(v - bf2f(h));
}

// ---------------------------------------------------------------------------
// Fused setup
// ---------------------------------------------------------------------------
__global__ __launch_bounds__(256) void setup_kernel(
    const float* __restrict__ x,
    const float* __restrict__ bq, const float* __restrict__ bk,
    const float* __restrict__ bv,
    float* __restrict__ mk, int* __restrict__ relT, int* __restrict__ convidx,
    float* __restrict__ f1pad, float* __restrict__ bqkv,
    unsigned short* __restrict__ vt_hi, unsigned short* __restrict__ vt_lo,
    int nOrg)
{
    int i = blockIdx.x * 256 + threadIdx.x;
    if (i < 3200) {
        const float* xr = x + (long long)i * 128;
        mk[i] = xr[4];
        mk[3200 + i] = fmaxf(xr[2], xr[3]);
        mk[6400 + i] = xr[0];
        mk[9600 + i] = xr[1];
        convidx[i] = (i / 400) * 402 + (i % 400);
    }
    int j = i - 3200;
    if (j >= 0 && j < 799) {
        int rel = j - 399;
        int sgn = (rel > 0) - (rel < 0);
        int ab = (rel < 300 && rel > -300) ? 299 : (rel < 0 ? -rel : rel);
        long long bpos;
        if (ab <= 300) bpos = rel;
        else {
            double lp = ceil(log((double)ab / 300.0) / log(599.0 / 300.0) * 299.0) + 300.0;
            bpos = (long long)lp * sgn;
        }
        long long c2p = bpos + 600;
        c2p = c2p < 0 ? 0 : (c2p > 1199 ? 1199 : c2p);
        relT[j] = (int)c2p;
    }
    int k = i - 4000;
    if (k >= 0 && k < 4096) {
        int b = k >> 9, rem = k & 511;
        int row = b * 402 + (rem < 256 ? 0 : 401);
        f1pad[(long long)row * 256 + (rem & 255)] = 0.f;
    }
    int m = i - 8100;
    if (m >= 0 && m < 6144) {
        int o = m / 1536, n = m % 1536;
        float v;
        if (n < 512) v = bq[o * 512 + n];
        else if (n < 1024) v = bk[o * 512 + n - 512];
        else v = bv[o * 512 + n - 1024];
        bqkv[m] = v;
    }
    int v = i - 14244;
    if (v >= 0 && v < nOrg * 65536) {   // vt pad cols [400..416) zero, as u32
        int og = v >> 16, rem = v & 65535;
        int vb = rem & 32767;
        int row = vb >> 3, c = vb & 7;
        unsigned int* p = (unsigned int*)((rem < 32768) ? vt_hi : vt_lo);
        p[(long long)og * 851968 + row * 208 + 200 + c] = 0u;
    }
}

// ---------------------------------------------------------------------------
// LayerNorm, wave-per-row. Organ-batched (o = row/rpo). RES: split residual.
// OSPL: 0 -> f32 out, 1 -> split hi/lo, 2 -> hi only.
// ---------------------------------------------------------------------------
template<bool RES, int HD, int OSPL>
__global__ __launch_bounds__(256) void ln2_kernel(
    const float* __restrict__ X,
    const unsigned short* __restrict__ Rhi, const unsigned short* __restrict__ Rlo,
    const float* __restrict__ g, const float* __restrict__ be,
    float* __restrict__ Y,
    unsigned short* __restrict__ Yhi, unsigned short* __restrict__ Ylo,
    int rows, int rpo)
{
    constexpr int EPL = HD / 64;
    int wv = threadIdx.x >> 6, lane = threadIdx.x & 63;
    long long row = (long long)blockIdx.x * 4 + wv;
    if (row >= rows) return;
    int o = (int)(row / rpo);
    long long rrow = row % rpo;
    const float* x = X + row * HD;
    float v[EPL];
    #pragma unroll
    for (int q = 0; q < EPL / 4; ++q) {
        float4 a = *(const float4*)&x[lane * EPL + q * 4];
        v[q*4+0] = a.x; v[q*4+1] = a.y; v[q*4+2] = a.z; v[q*4+3] = a.w;
        if (RES) {
            us4 rh = *(const us4*)&Rhi[rrow * HD + lane * EPL + q * 4];
            us4 rl = *(const us4*)&Rlo[rrow * HD + lane * EPL + q * 4];
            #pragma unroll
            for (int e = 0; e < 4; ++e) v[q*4+e] += bf2f(rh[e]) + bf2f(rl[e]);
        }
    }
    float s = 0.f;
    #pragma unroll
    for (int e = 0; e < EPL; ++e) s += v[e];
    #pragma unroll
    for (int d = 1; d < 64; d <<= 1) s += __shfl_xor(s, d, 64);
    float mean = s * (1.f / HD);
    float s2 = 0.f;
    #pragma unroll
    for (int e = 0; e < EPL; ++e) { float d0 = v[e] - mean; s2 += d0 * d0; }
    #pragma unroll
    for (int d = 1; d < 64; d <<= 1) s2 += __shfl_xor(s2, d, 64);
    float inv = 1.f / sqrtf(s2 * (1.f / HD) + 1e-7f);
    #pragma unroll
    for (int q = 0; q < EPL / 4; ++q) {
        int c = lane * EPL + q * 4;
        float4 gg = *(const float4*)&g[o * HD + c];
        float4 bb = *(const float4*)&be[o * HD + c];
        float ov[4];
        ov[0] = (v[q*4+0] - mean) * inv * gg.x + bb.x;
        ov[1] = (v[q*4+1] - mean) * inv * gg.y + bb.y;
        ov[2] = (v[q*4+2] - mean) * inv * gg.z + bb.z;
        ov[3] = (v[q*4+3] - mean) * inv * gg.w + bb.w;
        if (OSPL == 1 || OSPL == 2) {
            us4 ph, pl;
            #pragma unroll
            for (int e = 0; e < 4; ++e) {
                unsigned short hh = f2bf(ov[e]);
                ph[e] = hh;
                pl[e] = f2bf(ov[e] - bf2f(hh));
            }
            *(us4*)&Yhi[row * HD + c] = ph;
            if (OSPL == 1) *(us4*)&Ylo[row * HD + c] = pl;
        } else {
            float4 of; of.x = ov[0]; of.y = ov[1]; of.z = ov[2]; of.w = ov[3];
            *(float4*)&Y[row * HD + c] = of;
        }
    }
}

// ---------------------------------------------------------------------------
// MFMA fused disentangled flash attention (round 19): HI-ONLY operands,
// single-wave blocks, zero-VGPR band staging via global_load_lds.
// Per tile: [barrier; 12x gll(pq/pk bands)->LDS; barrier; reg-load K/V/mask;
// compute with LDS frag reads]. Removes register-pressure-serialized load
// rounds (prev: 80 VGPRs of in-flight band operands forced multiple
// vmcnt waits per tile). Bit-identical math to R18.
// Grid (25, 8, 8*nOrg), XCD-swizzled.
// ---------------------------------------------------------------------------
__global__ __launch_bounds__(64) void attn_kernel(
    const unsigned short* __restrict__ qk_hi, const unsigned short* __restrict__ qk_lo,
    const unsigned short* __restrict__ vt_hi, const unsigned short* __restrict__ vt_lo,
    const unsigned short* __restrict__ pkg_hi, const unsigned short* __restrict__ pkg_lo,
    const float* __restrict__ mask,
    unsigned short* __restrict__ ctxh, unsigned short* __restrict__ ctxl)
{
    const float scale = 0.07216878364870322f;       // 1/sqrt(64*3)
    const float NEGMIN = -3.402823466e38f;
    int lin = blockIdx.x + 25 * (blockIdx.y + 8 * blockIdx.z);
    int gz = gridDim.z;
    int xcd = lin & 7, within = lin >> 3;
    int g = within / 25, lt = within - g * 25;
    int combo = xcd * gz + g;
    int h = combo & 7, z = combo >> 3;
    int b = z & 7, o = z >> 3;
    qk_hi  += (long long)o * 3276800;
    vt_hi  += (long long)o * 1703936;
    pkg_hi += (long long)o * 818176;
    mask   += o * 3200;
    ctxh   += (long long)o * 1638400;

    int l0 = lt * 16;
    int lane = threadIdx.x;
    int fr = lane & 15, kg8 = (lane >> 4) << 3, g4 = (lane >> 4) << 2;
    int rowS = lane >> 2, segS = (lane & 3) << 3;   // staging: 16 rows x 4x16B

    // band staging: blocks 0..5 = pq (c*2+kk), 6..11 = pk. 1KB each:
    // [16 rows][32 shorts], row r of block c holds pkg row dd=D0+c*16+r,
    // elements kk*32 .. kk*32+31. Frag (c,kk) read at [fr*32 + kg8].
    __shared__ unsigned short PB[12 * 512];
    __shared__ float T2c[16 * 36];
    __shared__ float T3c[32 * 20];
    __shared__ unsigned short Sth[16 * 40];

    bf16x8 qf[2];
    {
        long long base = ((long long)(b * 400 + l0 + fr)) * 1024 + h * 64 + kg8;
        #pragma unroll
        for (int kk = 0; kk < 2; ++kk)
            qf[kk] = *(const bf16x8*)(qk_hi + base + kk * 32);
    }
    float wlv_r[4], ms[4], ls[4];
    #pragma unroll
    for (int r = 0; r < 4; ++r) {
        wlv_r[r] = mask[b * 400 + l0 + g4 + r];
        ms[r] = -INFINITY;
        ls[r] = 0.f;
    }
    f32x4 O[4] = {};
    long long vtbase = ((long long)(b * 512 + h * 64)) * 416;

    for (int mt = 0; mt < 13; ++mt) {
        int m0 = mt * 32;
        int D0 = l0 - m0 + 368;
        // ---- protect LDS blocks from prior-tile reads, then async-stage ----
        __syncthreads();
        #pragma unroll
        for (int c = 0; c < 3; ++c) {
            int dd = D0 + c * 16 + rowS;
            dd = dd < 0 ? 0 : (dd > 798 ? 798 : dd);    // clamp; unread
            const unsigned short* gb = pkg_hi + (long long)dd * 1024 + h * 64 + segS;
            #pragma unroll
            for (int kk = 0; kk < 2; ++kk) {
                gll16(gb + kk * 32,       &PB[(c * 2 + kk) * 512]);        // pq
                gll16(gb + 512 + kk * 32, &PB[(6 + c * 2 + kk) * 512]);    // pk
            }
        }
        __syncthreads();   // vmcnt drain: bands resident in LDS
        // ---- register loads (K first-use, V last-use, masks) ----
        bf16x8 kf[2][2];
        #pragma unroll
        for (int jf = 0; jf < 2; ++jf) {
            int kr = m0 + jf * 16 + fr;
            kr = kr < 400 ? kr : 399;
            long long base = ((long long)(b * 400 + kr)) * 1024 + 512 + h * 64 + kg8;
            #pragma unroll
            for (int kk = 0; kk < 2; ++kk)
                kf[jf][kk] = *(const bf16x8*)(qk_hi + base + kk * 32);
        }
        bf16x8 vf[4];
        #pragma unroll
        for (int f = 0; f < 4; ++f) {
            long long a = vtbase + (long long)(f * 16 + fr) * 416 + m0 + kg8;
            vf[f] = *(const bf16x8*)&vt_hi[a];
        }
        float wm_c[2];
        #pragma unroll
        for (int cf = 0; cf < 2; ++cf) {
            int mg = m0 + cf * 16 + fr;
            mg = mg < 400 ? mg : 399;
            wm_c[cf] = mask[b * 400 + mg];
        }
        // ---- T1 = Q@K^T ----
        __builtin_amdgcn_s_setprio(1);
        f32x4 aT1[2] = {};
        #pragma unroll
        for (int jf = 0; jf < 2; ++jf)
        #pragma unroll
        for (int kk = 0; kk < 2; ++kk)
            aT1[jf] = __builtin_amdgcn_mfma_f32_16x16x32_bf16(qf[kk], kf[jf][kk], aT1[jf], 0, 0, 0);
        // ---- T2 = Q@pk (band frags from LDS) ----
        f32x4 aT2[3] = {};
        #pragma unroll
        for (int c = 0; c < 3; ++c)
        #pragma unroll
        for (int kk = 0; kk < 2; ++kk) {
            bf16x8 bf = *(const bf16x8*)&PB[(6 + c * 2 + kk) * 512 + fr * 32 + kg8];
            aT2[c] = __builtin_amdgcn_mfma_f32_16x16x32_bf16(qf[kk], bf, aT2[c], 0, 0, 0);
        }
        // ---- T3 = K@pq (band frags from LDS) ----
        f32x4 aT3[2][2] = {};
        #pragma unroll
        for (int jf = 0; jf < 2; ++jf)
        #pragma unroll
        for (int ci = 0; ci < 2; ++ci) {
            int c = ci + (jf ^ 1);
            #pragma unroll
            for (int kk = 0; kk < 2; ++kk) {
                bf16x8 bf = *(const bf16x8*)&PB[(c * 2 + kk) * 512 + fr * 32 + kg8];
                aT3[jf][ci] = __builtin_amdgcn_mfma_f32_16x16x32_bf16(kf[jf][kk], bf, aT3[jf][ci], 0, 0, 0);
            }
        }
        __builtin_amdgcn_s_setprio(0);
        // ---- banded scatter (in-wave LDS ordering, no barrier) ----
        #pragma unroll
        for (int c = 0; c < 3; ++c)
        #pragma unroll
        for (int r = 0; r < 4; ++r) {
            int i = g4 + r;
            int d = c * 16 + fr - i;
            if ((unsigned)d < 32u)
                T2c[i * 36 + d] = aT2[c][r];
        }
        #pragma unroll
        for (int jf = 0; jf < 2; ++jf)
        #pragma unroll
        for (int ci = 0; ci < 2; ++ci) {
            int c = ci + (jf ^ 1);
            #pragma unroll
            for (int r = 0; r < 4; ++r) {
                int j3 = jf * 16 + g4 + r;
                int d2 = c * 16 + fr + j3 - 31;
                if ((unsigned)d2 < 16u)
                    T3c[j3 * 20 + d2] = aT3[jf][ci][r];
            }
        }
        // ---- assemble scores ----
        float sc0[4], sc1[4];
        #pragma unroll
        for (int r = 0; r < 4; ++r) {
            int i = g4 + r;
            {
                int j = fr;
                bool jv = (m0 + j) < 400;
                sc0[r] = !jv ? -INFINITY :
                    ((wlv_r[r] != 0.f && wm_c[0] != 0.f) ?
                     (aT1[0][r] + T2c[i * 36 + 31 - j] + T3c[j * 20 + i]) * scale : NEGMIN);
            }
            {
                int j = 16 + fr;
                bool jv = (m0 + j) < 400;
                sc1[r] = !jv ? -INFINITY :
                    ((wlv_r[r] != 0.f && wm_c[1] != 0.f) ?
                     (aT1[1][r] + T2c[i * 36 + 31 - j] + T3c[j * 20 + i]) * scale : NEGMIN);
            }
        }
        // ---- wave-local flash softmax ----
        float corr[4];
        #pragma unroll
        for (int r = 0; r < 4; ++r) {
            float mx = fmaxf(sc0[r], sc1[r]);
            #pragma unroll
            for (int d = 1; d < 16; d <<= 1) mx = fmaxf(mx, __shfl_xor(mx, d, 64));
            float mn = fmaxf(ms[r], mx);
            corr[r] = __expf(ms[r] - mn);
            ms[r] = mn;
            float p0 = __expf(sc0[r] - mn), p1 = __expf(sc1[r] - mn);
            float rs = p0 + p1;
            #pragma unroll
            for (int d = 1; d < 16; d <<= 1) rs += __shfl_xor(rs, d, 64);
            ls[r] = ls[r] * corr[r] + rs;
            int i = g4 + r;
            Sth[i * 40 + fr] = f2bf(p0);
            Sth[i * 40 + 16 + fr] = f2bf(p1);
        }
        // ---- PV (P transposed via in-wave LDS, hi-only) ----
        #pragma unroll
        for (int f = 0; f < 4; ++f)
        #pragma unroll
        for (int r = 0; r < 4; ++r) O[f][r] *= corr[r];
        bf16x8 Pha = *(const bf16x8*)&Sth[fr * 40 + kg8];
        __builtin_amdgcn_s_setprio(1);
        #pragma unroll
        for (int f = 0; f < 4; ++f)
            O[f] = __builtin_amdgcn_mfma_f32_16x16x32_bf16(Pha, vf[f], O[f], 0, 0, 0);
        __builtin_amdgcn_s_setprio(0);
    }
    #pragma unroll
    for (int f = 0; f < 4; ++f) {
        int colg = h * 64 + f * 16 + fr;
        #pragma unroll
        for (int r = 0; r < 4; ++r) {
            int lg = l0 + g4 + r;
            float val = O[f][r] / ls[r];
            long long idx = ((long long)(b * 400 + lg)) * 512 + colg;
            ctxh[idx] = f2bf(val);
        }
    }
}

// ---------------------------------------------------------------------------
// Chunked pool / meanmax (full-chip), heads
// ---------------------------------------------------------------------------
__global__ __launch_bounds__(256) void pool_part(
    const float* __restrict__ in, long long inOStride,
    const float* __restrict__ mk, float* __restrict__ pp)
{
    int bi = blockIdx.x, c = blockIdx.y, t = threadIdx.x;
    int o = bi >> 3, b = bi & 7;
    int l0 = c * 31, l1 = min(400, l0 + 31);
    const float* ib = in + (long long)o * inOStride + (long long)(b * 400) * 256;
    const float* mkb = mk + o * 3200 + b * 400;
    float s = 0.f, mx = -INFINITY, sw = 0.f;
    for (int l = l0; l < l1; ++l) {
        float wv = mkb[l];
        float v = ib[(long long)l * 256 + t] * wv;
        s += v; mx = fmaxf(mx, v); sw += wv;
    }
    long long base = (long long)(c * gridDim.x + bi) * 514;
    pp[base + t] = s;
    pp[base + 256 + t] = mx;
    if (t == 0) pp[base + 512] = sw;
}

__global__ __launch_bounds__(256) void pool_merge(
    const float* __restrict__ pp, float* __restrict__ pooled, int nBI)
{
    int bi = blockIdx.x, t = threadIdx.x;
    float s = 0.f, mx = -INFINITY, sw = 0.f;
    for (int c = 0; c < 13; ++c) {
        long long base = (long long)(c * nBI + bi) * 514;
        s += pp[base + t];
        mx = fmaxf(mx, pp[base + 256 + t]);
        sw += pp[base + 512];
    }
    int o = bi >> 3, b = bi & 7;
    pooled[o * 4096 + b * 512 + t] = s / (sw + 1e-6f);
    pooled[o * 4096 + b * 512 + 256 + t] = mx;
}

__global__ __launch_bounds__(512) void mm_part(
    const unsigned short* __restrict__ fh, const unsigned short* __restrict__ fl,
    float* __restrict__ mmp)
{
    int b = blockIdx.x, c = blockIdx.y, t = threadIdx.x;
    int l0 = c * 31, l1 = min(400, l0 + 31);
    float s = 0.f, mx = -INFINITY;
    for (int l = l0; l < l1; ++l) {
        long long idx = ((long long)(b * 400 + l)) * 512 + t;
        float v = bf2f(fh[idx]) + bf2f(fl[idx]);
        s += v; mx = fmaxf(mx, v);
    }
    long long base = (long long)(c * 8 + b) * 1024;
    mmp[base + t] = s;
    mmp[base + 512 + t] = mx;
}

__global__ __launch_bounds__(512) void mm_merge(
    const float* __restrict__ mmp, float* __restrict__ mm)
{
    int b = blockIdx.x, t = threadIdx.x;
    float s = 0.f, mx = -INFINITY;
    for (int c = 0; c < 13; ++c) {
        long long base = (long long)(c * 8 + b) * 1024;
        s += mmp[base + t];
        mx = fmaxf(mx, mmp[base + 512 + t]);
    }
    mm[b * 1024 + t] = s / 400.f;
    mm[b * 1024 + 512 + t] = mx;
}

__global__ __launch_bounds__(256) void heads_kernel(
    const float* __restrict__ pooled, const float* __restrict__ mm,
    const float* __restrict__ w_bow1, const float* __restrict__ b_bow1,
    const float* __restrict__ w_bow2, const float* __restrict__ b_bow2,
    const float* __restrict__ w_ext1, const float* __restrict__ b_ext1,
    const float* __restrict__ w_ext2, const float* __restrict__ b_ext2,
    const float* __restrict__ w_org1, const float* __restrict__ b_org1,
    const float* __restrict__ w_org2, const float* __restrict__ b_org2,
    float* __restrict__ out)
{
    int b = blockIdx.x, role = blockIdx.y;
    int t = threadIdx.x;
    __shared__ float inb[1024];
    __shared__ float red[256];
    __shared__ float hid[256];
    if (role == 0) {
        inb[t] = pooled[b * 512 + t];
        inb[256 + t] = pooled[b * 512 + 256 + t];
        __syncthreads();
        float acc = b_bow1[t];
        for (int j = 0; j < 512; ++j) acc += inb[j] * w_bow1[j * 256 + t];
        red[t] = mishf(acc) * w_bow2[t];
        __syncthreads();
        for (int s = 128; s; s >>= 1) { if (t < s) red[t] += red[t + s]; __syncthreads(); }
        if (t == 0) out[b * 11 + 0] = red[0] + b_bow2[0];
    } else if (role == 1) {
        inb[t] = mm[b * 1024 + t];
        inb[256 + t] = mm[b * 1024 + 256 + t];
        inb[512 + t] = mm[b * 1024 + 512 + t];
        inb[768 + t] = mm[b * 1024 + 768 + t];
        __syncthreads();
        float acc = b_ext1[t];
        for (int j = 0; j < 1024; ++j) acc += inb[j] * w_ext1[j * 256 + t];
        red[t] = mishf(acc) * w_ext2[t];
        __syncthreads();
        for (int s = 128; s; s >>= 1) { if (t < s) red[t] += red[t + s]; __syncthreads(); }
        if (t == 0) { out[b * 11 + 1] = red[0] + b_ext2[0]; out[88 + b] = 0.f; }
    } else {
        int i = role - 2;
        inb[t] = pooled[((1 + i) * 8 + b) * 512 + t];
        inb[256 + t] = pooled[((1 + i) * 8 + b) * 512 + 256 + t];
        __syncthreads();
        float acc = b_org1[i * 256 + t];
        for (int j = 0; j < 512; ++j)
            acc += inb[j] * w_org1[((long long)i * 512 + j) * 256 + t];
        hid[t] = mishf(acc);
        __syncthreads();
        for (int c = 0; c < 3; ++c) {
            red[t] = hid[t] * w_org2[(i * 256 + t) * 3 + c];
            __syncthreads();
            for (int s = 128; s; s >>= 1) { if (t < s) red[t] += red[t + s]; __syncthreads(); }
            if (t == 0) out[b * 11 + 2 + i * 3 + c] = red[0] + b_org2[i * 3 + c];
            __syncthreads();
        }
    }
}

// ---------------------------------------------------------------------------
// Launch
// ---------------------------------------------------------------------------
extern "C" void kernel_launch(void* const* d_in, const int* in_sizes, int n_in,
                              void* d_out, int out_size, void* d_ws, size_t ws_size,
                              hipStream_t stream)
{
    const float* x      = (const float*)d_in[0];
    const float* w_mlp  = (const float*)d_in[1];
    const float* b_mlp  = (const float*)d_in[2];
    const float* w_cnn  = (const float*)d_in[3];
    const float* b_cnn  = (const float*)d_in[4];
    const float* rel_emb= (const float*)d_in[5];
    const float* rel_g  = (const float*)d_in[6];
    const float* rel_b  = (const float*)d_in[7];
    const float* wq     = (const float*)d_in[8];
    const float* wk     = (const float*)d_in[9];
    const float* wv     = (const float*)d_in[10];
    const float* wo     = (const float*)d_in[11];
    const float* wi     = (const float*)d_in[12];
    const float* bq     = (const float*)d_in[13];
    const float* bk     = (const float*)d_in[14];
    const float* bv     = (const float*)d_in[15];
    const float* bo     = (const float*)d_in[16];
    const float* bi     = (const float*)d_in[17];
    const float* wout   = (const float*)d_in[18];
    const float* bout   = (const float*)d_in[19];
    const float* ln1g   = (const float*)d_in[20];
    const float* ln1b   = (const float*)d_in[21];
    const float* ln2g   = (const float*)d_in[22];
    const float* ln2b   = (const float*)d_in[23];
    const float* w_bow1 = (const float*)d_in[24];
    const float* b_bow1 = (const float*)d_in[25];
    const float* w_bow2 = (const float*)d_in[26];
    const float* b_bow2 = (const float*)d_in[27];
    const float* w_ext1 = (const float*)d_in[28];
    const float* b_ext1 = (const float*)d_in[29];
    const float* w_ext2 = (const float*)d_in[30];
    const float* b_ext2 = (const float*)d_in[31];
    const float* w_org1 = (const float*)d_in[32];
    const float* b_org1 = (const float*)d_in[33];
    const float* w_org2 = (const float*)d_in[34];
    const float* b_org2 = (const float*)d_in[35];

    float* ws = (float*)d_ws;
    float* outf = (float*)d_out;
    const bool big = ws_size >= 143012736ull;

    if (big) {
        // ---------------- organ-batched path ----------------
        unsigned short* featsh = (unsigned short*)(ws + 0);        // 3200x512
        unsigned short* featsl = (unsigned short*)(ws + 819200);
        float* ctxR     = ws + 1638400;      // 6,553,600 fl
        float* f1pad    = ctxR;
        unsigned short* ctxh = (unsigned short*)ctxR;              // 4x3200x512
        unsigned short* ctxl = (unsigned short*)(ws + 4915200);
        float* qkA_f    = ws + 8192000;
        float* qkB_f    = ws + 14745600;
        unsigned short* qkA = (unsigned short*)qkA_f;
        unsigned short* qkB = (unsigned short*)qkB_f;
        unsigned short* rellnh = (unsigned short*)qkA_f;           // 4800x512
        unsigned short* rellnl = (unsigned short*)(ws + 8192000 + 1228800);
        unsigned short* vtA = (unsigned short*)(ws + 21299200);    // 4x4096x416
        unsigned short* vtB = (unsigned short*)(ws + 24707072);
        unsigned short* pkgA = (unsigned short*)(ws + 28114944);   // 4x799x1024
        unsigned short* pkgB = (unsigned short*)(ws + 29751296);
        unsigned short* whiA = (unsigned short*)(ws + 31387648);   // 4x786,432
        unsigned short* wloA = (unsigned short*)(ws + 32960512);
        unsigned short* wcnn_hi = (unsigned short*)(ws + 35188736);
        unsigned short* wcnn_lo = (unsigned short*)(ws + 35287040);
        float* bqkvb   = ws + 35385344;
        float* masksb  = ws + 35391488;
        float* pooledb = ws + 35404288;
        float* mmb     = ws + 35420672;
        int*   relidx  = (int*)(ws + 35428864);
        int*   convidx = (int*)(ws + 35429664);
        float* poolpart= ws + 35432864;
        float* mmpart  = ws + 35646688;
        float* tmp_all   = qkA_f;                                  // WO out (f32)
        unsigned short* h1h = (unsigned short*)qkB_f;              // LN1 out hi
        unsigned short* interh = (unsigned short*)qkA_f;           // WI out hi
        float* outenc_all = (float*)vtA;                           // 4x819,200 f32
        float* outln_all  = ctxR;                                  // 4x819,200 f32
        unsigned short* whiB_all = whiA;
        unsigned short* wloB_all = wloA;

        gemm_bias<1><<<dim3(4, 50), 256, 0, stream>>>(
            x, w_mlp, b_mlp, f1pad, featsh, featsl, 3200, 256, 128, 512);
        setup_kernel<<<1080, 256, 0, stream>>>(x, bq, bk, bv, masksb, relidx, convidx,
                                               f1pad, bqkvb, vtA, vtB, 4);
        prep_wcnn<<<768, 256, 0, stream>>>(w_cnn, wcnn_hi, wcnn_lo);
        gemm_mfma<2, true, 0, true, 32, false, 3, true><<<dim3(2, 100), 256, 0, stream>>>(
            f1pad, nullptr, nullptr, wcnn_hi, wcnn_lo, b_cnn, nullptr,
            3200, 768, 256, 0, convidx, featsh + 256, featsl + 256, 512, 1 << 30,
            nullptr, nullptr, 0, 0, 0, 0, 0, 0);

        ln2_kernel<false, 512, 1><<<1200, 256, 0, stream>>>(
            rel_emb, nullptr, nullptr, rel_g, rel_b, nullptr, rellnh, rellnl, 4800, 1200);
        prep_wqkv<<<12288, 256, 0, stream>>>(wq, wk, wv, whiA, wloA, 0, 3145728, 0);
        gemm_mfma<0, true, 1, true, 64, true, 1, false><<<dim3(8, 13, 4), 256, 0, stream>>>(
            nullptr, rellnh, rellnl, whiA, wloA, bqkvb, nullptr, 799, 512, 512, 0, relidx,
            pkgA, pkgB, 1024, 1024, nullptr, nullptr,
            614400, 786432, 1536, 0, 818176, 0);
        gemm_mfma<0, false, 1, true, 64, true, 1, false><<<dim3(12, 50, 4), 256, 0, stream>>>(
            nullptr, featsh, featsl, whiA, wloA, bqkvb, nullptr, 3200, 512, 512, 0, nullptr,
            qkA, qkB, 1024, 1024, vtA, vtB,
            0, 786432, 1536, 0, 3276800, 1703936);
        prep_woiw<<<10240, 256, 0, stream>>>(wo, wi, wout, whiB_all, wloB_all,
                                             0, 2621440, 0);
        attn_kernel<<<dim3(25, 8, 32), 64, 0, stream>>>(qkA, qkB, vtA, vtB,
            pkgA, pkgB, masksb, ctxh, ctxl);
        // WO (x1) -> tmp f32
        gemm_mfma<0, false, 1, false, 32, true, 1, false><<<dim3(4, 100, 4), 256, 0, stream>>>(
            nullptr, ctxh, ctxl, whiB_all, wloB_all, bo, tmp_all,
            3200, 512, 512, 512, nullptr, nullptr, nullptr, 0, 0, nullptr, nullptr,
            1638400, 655360, 512, 1638400, 0, 0);
        // LN1 -> h1 hi only
        ln2_kernel<true, 512, 2><<<3200, 256, 0, stream>>>(
            tmp_all, featsh, featsl, ln1g, ln1b, nullptr, h1h, nullptr, 12800, 3200);
        // WI mish (x1) -> inter hi only
        gemm_mfma<1, false, 1, true, 32, true, 1, false><<<dim3(4, 100, 4), 256, 0, stream>>>(
            nullptr, h1h, nullptr, whiB_all + 262144, wloB_all + 262144, bi, nullptr,
            3200, 512, 512, 0, nullptr, interh, nullptr, 512, 1 << 30, nullptr, nullptr,
            1638400, 655360, 512, 0, 1638400, 0);
        // WOUT (x1) -> outenc f32
        gemm_mfma<0, false, 1, false, 32, true, 1, false><<<dim3(2, 100, 4), 256, 0, stream>>>(
            nullptr, interh, nullptr, whiB_all + 524288, wloB_all + 524288, bout, outenc_all,
            3200, 512, 512, 256, nullptr, nullptr, nullptr, 0, 0, nullptr, nullptr,
            1638400, 655360, 256, 819200, 0, 0);
        ln2_kernel<false, 256, 0><<<3200, 256, 0, stream>>>(
            outenc_all, nullptr, nullptr, ln2g, ln2b, outln_all, nullptr, nullptr,
            12800, 3200);

        pool_part<<<dim3(32, 13), 256, 0, stream>>>(outln_all, 819200, masksb, poolpart);
        pool_merge<<<32, 256, 0, stream>>>(poolpart, pooledb, 32);
        mm_part<<<dim3(8, 13), 512, 0, stream>>>(featsh, featsl, mmpart);
        mm_merge<<<8, 512, 0, stream>>>(mmpart, mmb);
        heads_kernel<<<dim3(8, 5), 256, 0, stream>>>(pooledb, mmb,
            w_bow1, b_bow1, w_bow2, b_bow2, w_ext1, b_ext1, w_ext2, b_ext2,
            w_org1, b_org1, w_org2, b_org2, outf);
        return;
    }

    // ---------------- per-organ fallback path ----------------
    unsigned short* featsh = (unsigned short*)(ws + 0);
    unsigned short* featsl = (unsigned short*)(ws + 819200);
    float* ctxR    = ws + 1638400;
    float* f1pad   = ctxR;
    unsigned short* ctxh = (unsigned short*)ctxR;
    unsigned short* ctxl = (unsigned short*)(ws + 1638400 + 819200);
    float* qkvA_f  = ws + 3276800;
    float* qkvB_f  = ws + 4915200;
    unsigned short* qkv_hi = (unsigned short*)qkvA_f;
    unsigned short* qkv_lo = (unsigned short*)qkvB_f;
    unsigned short* rellnh = (unsigned short*)qkvB_f;
    unsigned short* rellnl = (unsigned short*)(ws + 4915200 + 307200);
    unsigned short* pkg_hi = (unsigned short*)(ws + 6553600);
    unsigned short* pkg_lo = (unsigned short*)(ws + 6963200);
    unsigned short* vt_hi  = (unsigned short*)(ws + 7372800);
    unsigned short* vt_lo  = (unsigned short*)(ws + 8224768);
    unsigned short* whi    = (unsigned short*)(ws + 9076736);
    unsigned short* wlo    = (unsigned short*)(ws + 9469952);
    float* bqkvb   = ws + 9863168;
    float* masksb  = ws + 9869312;
    float* pooledb = ws + 9882112;
    float* mmb     = ws + 9898496;
    int*   relidx  = (int*)(ws + 9906688);
    unsigned short* wcnn_hi = (unsigned short*)(ws + 9907488);
    unsigned short* wcnn_lo = (unsigned short*)(ws + 10005792);
    int*   convidx = (int*)(ws + 10104096);
    float* poolpart= ws + 10107296;
    float* mmpart  = ws + 10160752;
    float* tmp     = qkvA_f;
    unsigned short* h1h = (unsigned short*)qkvB_f;
    unsigned short* interh = (unsigned short*)qkvA_f;
    float* outenc  = (float*)vt_hi;
    float* outln   = ctxR;

    gemm_bias<1><<<dim3(4, 50), 256, 0, stream>>>(
        x, w_mlp, b_mlp, f1pad, featsh, featsl, 3200, 256, 128, 512);
    setup_kernel<<<312, 256, 0, stream>>>(x, bq, bk, bv, masksb, relidx, convidx,
                                          f1pad, bqkvb, vt_hi, vt_lo, 1);
    prep_wcnn<<<768, 256, 0, stream>>>(w_cnn, wcnn_hi, wcnn_lo);
    gemm_mfma<2, true, 0, true, 32, false, 3, true><<<dim3(2, 100), 256, 0, stream>>>(
        f1pad, nullptr, nullptr, wcnn_hi, wcnn_lo, b_cnn, nullptr,
        3200, 768, 256, 0, convidx, featsh + 256, featsl + 256, 512, 1 << 30,
        nullptr, nullptr, 0, 0, 0, 0, 0, 0);

    for (int o = 0; o < 4; ++o) {
        ln2_kernel<false, 512, 1><<<300, 256, 0, stream>>>(
            rel_emb + (long long)o * 614400, nullptr, nullptr,
            rel_g + o * 512, rel_b + o * 512, nullptr, rellnh, rellnl, 1200, 1200);
        prep_wqkv<<<3072, 256, 0, stream>>>(wq, wk, wv, whi, wlo, o, 786432, 0);
        gemm_mfma<0, true, 1, true, 64, true, 1, false><<<dim3(8, 13), 256, 0, stream>>>(
            nullptr, rellnh, rellnl, whi, wlo, bqkvb + o * 1536, nullptr,
            799, 512, 512, 0, relidx, pkg_hi, pkg_lo, 1024, 1024, nullptr, nullptr,
            0, 0, 0, 0, 0, 0);
        gemm_mfma<0, false, 1, true, 64, true, 1, false><<<dim3(12, 50), 256, 0, stream>>>(
            nullptr, featsh, featsl, whi, wlo, bqkvb + o * 1536, nullptr,
            3200, 512, 512, 0, nullptr, qkv_hi, qkv_lo, 1024, 1024, vt_hi, vt_lo,
            0, 0, 0, 0, 0, 0);
        prep_woiw<<<2560, 256, 0, stream>>>(wo, wi, wout, whi, wlo, o, 655360, 0);
        attn_kernel<<<dim3(25, 8, 8), 64, 0, stream>>>(qkv_hi, qkv_lo, vt_hi, vt_lo,
            pkg_hi, pkg_lo, masksb + o * 3200, ctxh, ctxl);
        gemm_mfma<0, false, 1, false, 32, true, 1, false><<<dim3(4, 100), 256, 0, stream>>>(
            nullptr, ctxh, ctxl, whi, wlo, bo + o * 512, tmp,
            3200, 512, 512, 512, nullptr, nullptr, nullptr, 0, 0, nullptr, nullptr,
            0, 0, 0, 0, 0, 0);
        ln2_kernel<true, 512, 2><<<800, 256, 0, stream>>>(
            tmp, featsh, featsl, ln1g + o * 512, ln1b + o * 512, nullptr,
            h1h, nullptr, 3200, 3200);
        gemm_mfma<1, false, 1, true, 32, true, 1, false><<<dim3(4, 100), 256, 0, stream>>>(
            nullptr, h1h, nullptr, whi + 262144, wlo + 262144, bi + o * 512, nullptr,
            3200, 512, 512, 0, nullptr, interh, nullptr, 512, 1 << 30, nullptr, nullptr,
            0, 0, 0, 0, 0, 0);
        gemm_mfma<0, false, 1, false, 32, true, 1, false><<<dim3(2, 100), 256, 0, stream>>>(
            nullptr, interh, nullptr, whi + 524288, wlo + 524288, bout + o * 256, outenc,
            3200, 512, 512, 256, nullptr, nullptr, nullptr, 0, 0, nullptr, nullptr,
            0, 0, 0, 0, 0, 0);
        ln2_kernel<false, 256, 0><<<800, 256, 0, stream>>>(
            outenc, nullptr, nullptr, ln2g + o * 256, ln2b + o * 256, outln,
            nullptr, nullptr, 3200, 3200);
        pool_part<<<dim3(8, 13), 256, 0, stream>>>(outln, 0,
                                                   masksb + o * 3200, poolpart);
        pool_merge<<<8, 256, 0, stream>>>(poolpart, pooledb + o * 4096, 8);
    }

    mm_part<<<dim3(8, 13), 512, 0, stream>>>(featsh, featsl, mmpart);
    mm_merge<<<8, 512, 0, stream>>>(mmpart, mmb);
    heads_kernel<<<dim3(8, 5), 256, 0, stream>>>(pooledb, mmb,
        w_bow1, b_bow1, w_bow2, b_bow2, w_ext1, b_ext1, w_ext2, b_ext2,
        w_org1, b_org1, w_org2, b_org2, outf);
}